// Round 2
// baseline (551.384 us; speedup 1.0000x reference)
//
#include <hip/hip_runtime.h>
#include <math.h>

#define B_ 2
#define N_ 8192          // points per batch
#define G_ 64
#define NG 4096          // G*G latent grid points
#define WID_ 64
#define K_ 16
#define CIN_ 6
#define COUT_ 3
#define PI_ 3.14159265358979323846

typedef unsigned long long u64k;
typedef __attribute__((ext_vector_type(8))) short bf16x8;   // 8 bf16 bit-patterns (4 VGPR)
typedef __attribute__((ext_vector_type(16))) float f32x16;  // 32x32 MFMA acc

// ---------------------------------------------------------------- helpers
__device__ __forceinline__ float gelu_f(float x) {
    return 0.5f * x * (1.0f + erff(x * 0.70710678118654752440f));
}
__device__ __forceinline__ int cellof(float v) {
    int c = (int)floorf((v + 1.0f) * 32.0f);
    return min(63, max(0, c));
}
__device__ __forceinline__ u64k umin64(u64k a, u64k b) { return a < b ? a : b; }
__device__ __forceinline__ u64k umax64(u64k a, u64k b) { return a < b ? b : a; }
__device__ __forceinline__ u64k shflxor64(u64k v, int m) {
    return (u64k)__shfl_xor((long long)v, m, 64);
}
__device__ __forceinline__ void bsort64(u64k& key, int lane) {
#pragma unroll
    for (int sz = 2; sz <= 64; sz <<= 1) {
#pragma unroll
        for (int j = sz >> 1; j >= 1; j >>= 1) {
            u64k o = shflxor64(key, j);
            bool keep_min = ((lane & j) == 0) == ((lane & sz) == 0);
            key = keep_min ? umin64(key, o) : umax64(key, o);
        }
    }
}
__device__ __forceinline__ void bmerge_into(u64k& R, u64k key, int lane) {
    u64k o = shflxor64(key, 63);
    u64k L = umin64(R, o);
#pragma unroll
    for (int j = 32; j >= 1; j >>= 1) {
        u64k t = shflxor64(L, j);
        L = ((lane & j) == 0) ? umin64(L, t) : umax64(L, t);
    }
    R = L;
}
// split fp32 -> bf16 hi (RNE) + bf16 lo (truncated residual); err ~2^-17 rel
__device__ __forceinline__ void cvt8v(float4 a, float4 b, bf16x8& hv, bf16x8& lv) {
    float v[8] = {a.x, a.y, a.z, a.w, b.x, b.y, b.z, b.w};
#pragma unroll
    for (int i = 0; i < 8; i++) {
        unsigned u = __float_as_uint(v[i]);
        unsigned r = u + 0x7fffu + ((u >> 16) & 1u);
        hv[i] = (short)(r >> 16);
        float lo = v[i] - __uint_as_float(r & 0xffff0000u);
        lv[i] = (short)(__float_as_uint(lo) >> 16);
    }
}
__device__ __forceinline__ bf16x8 ldfrag(const short* __restrict__ WB, int f, int lane) {
    return *(const bf16x8*)(WB + ((long)f * 64 + lane) * 8);
}
struct Frag4 { bf16x8 h0, l0, h1, l1; };
// base/nk select layer: L1 base=0 nk=5, L2 base=20 nk=4, L3 base=36 nk=4
__device__ __forceinline__ Frag4 ldfrag4(const short* __restrict__ WB, int base, int nk,
                                         int kc, int lane) {
    Frag4 f;
    f.h0 = ldfrag(WB, base + (0 * nk + kc) * 2 + 0, lane);
    f.l0 = ldfrag(WB, base + (0 * nk + kc) * 2 + 1, lane);
    f.h1 = ldfrag(WB, base + (1 * nk + kc) * 2 + 0, lane);
    f.l1 = ldfrag(WB, base + (1 * nk + kc) * 2 + 1, lane);
    return f;
}

// ---------------------------------------------------------------- binning (+ grid gen fused)
__global__ void k_bincount(const float2* __restrict__ coords, int* __restrict__ cnt,
                           float4* __restrict__ gp) {
    int t = blockIdx.x * blockDim.x + threadIdx.x;
    if (t < NG) {        // numpy linspace semantics grid gen
        int i = t >> 6, j = t & 63;
        double st = 2.0 / 63.0;
        float gx = (i == 63) ? 1.0f : (float)(-1.0 + st * (double)i);
        float gy = (j == 63) ? 1.0f : (float)(-1.0 + st * (double)j);
        float s2 = __fadd_rn(__fmul_rn(gx, gx), __fmul_rn(gy, gy));
        gp[t] = make_float4(gx, gy, s2, 0.f);
    }
    if (t >= B_ * N_) return;
    float2 c = coords[t];
    int b = t >> 13;
    int cell = cellof(c.x) * 64 + cellof(c.y);
    atomicAdd(&cnt[b * 4096 + cell], 1);
}
__global__ void k_binscan(const int* __restrict__ cnt, int* __restrict__ offs) {
    int b = blockIdx.x, t = threadIdx.x;    // 1024 threads
    __shared__ int s[1024];
    int4 v = ((const int4*)(cnt + b * 4096))[t];
    int sum = v.x + v.y + v.z + v.w;
    s[t] = sum;
    __syncthreads();
    for (int d = 1; d < 1024; d <<= 1) {
        int x = (t >= d) ? s[t - d] : 0;
        __syncthreads();
        s[t] += x;
        __syncthreads();
    }
    int incl = s[t], excl = incl - sum;
    int* ob = offs + b * 4097;
    ob[4 * t] = excl; ob[4 * t + 1] = excl + v.x;
    ob[4 * t + 2] = excl + v.x + v.y; ob[4 * t + 3] = excl + v.x + v.y + v.z;
    if (t == 1023) ob[4096] = incl;
}
__global__ void k_binscatter(const float2* __restrict__ coords, const int* __restrict__ offs,
                             int* __restrict__ fill, float4* __restrict__ srt) {
    int t = blockIdx.x * blockDim.x + threadIdx.x;
    if (t >= B_ * N_) return;
    float2 c = coords[t];
    int b = t >> 13, n = t & 8191;
    int cell = cellof(c.x) * 64 + cellof(c.y);
    int pos = offs[b * 4097 + cell] + atomicAdd(&fill[b * 4096 + cell], 1);
    float s2 = __fadd_rn(__fmul_rn(c.x, c.x), __fmul_rn(c.y, c.y));
    srt[b * N_ + pos] = make_float4(c.x, c.y, s2, __int_as_float(n));
}

// ---------------------------------------------------------------- lift MLP
__global__ void __launch_bounds__(256) k_lift(
    const float* __restrict__ fin, const float* __restrict__ W1,
    const float* __restrict__ b1, const float* __restrict__ W2,
    const float* __restrict__ b2, float* __restrict__ fout) {
    __shared__ float xr[4][8];
    __shared__ __align__(16) float h[4][64];
    int ql = threadIdx.x >> 6, j = threadIdx.x & 63;
    int node = blockIdx.x * 4 + ql;
    if (j < CIN_) xr[ql][j] = fin[node * CIN_ + j];
    __syncthreads();
    float a = b1[j];
#pragma unroll
    for (int i = 0; i < CIN_; i++) a = fmaf(xr[ql][i], W1[i * 64 + j], a);
    h[ql][j] = gelu_f(a);
    __syncthreads();
    float a2 = b2[j];
    for (int k = 0; k < 64; k += 4) {
        float w0 = W2[(k + 0) * 64 + j], w1 = W2[(k + 1) * 64 + j];
        float w2 = W2[(k + 2) * 64 + j], w3 = W2[(k + 3) * 64 + j];
        const float4 hv = *(const float4*)&h[ql][k];
        a2 = fmaf(hv.x, w0, fmaf(hv.y, w1, fmaf(hv.z, w2, fmaf(hv.w, w3, a2))));
    }
    fout[node * 64 + j] = a2;
}

// ---------------------------------------------------------------- kNN grid->points: one wave per query
__global__ void __launch_bounds__(256) k_knn_in(
    const float4* __restrict__ gp, const float4* __restrict__ srt,
    const int* __restrict__ offs, int* __restrict__ oidx,
    float* __restrict__ odist, float* __restrict__ lastd) {
    int lane = threadIdx.x & 63;
    int w = (blockIdx.x * blockDim.x + threadIdx.x) >> 6;
    int b = w >> 12, p = w & 4095;
    float4 q = gp[p];
    float qx = q.x, qy = q.y, q2 = q.z;
    int cqx = cellof(qx), cqy = cellof(qy);
    const float4* S = srt + b * N_;
    const int* OF = offs + b * 4097;

    u64k R = ~0ull;
    u64k pend = ~0ull;
    int fill = 0;

    auto flush = [&]() {
        bsort64(pend, lane);
        bmerge_into(R, pend, lane);
        pend = ~0ull;
        fill = 0;
    };
    auto feed = [&](int s0, int s1) {
        int cnt = s1 - s0;
        while (cnt > 0) {
            int take = min(cnt, 64 - fill);
            int t = lane - fill;
            if (t >= 0 && t < take) {
                float4 sp = S[s0 + t];
                float dot = __fadd_rn(__fmul_rn(qx, sp.x), __fmul_rn(qy, sp.y));
                float d2 = __fsub_rn(__fadd_rn(q2, sp.z), 2.0f * dot);
                d2 = fmaxf(d2, 0.0f);
                pend = ((u64k)__float_as_uint(d2) << 32) | (unsigned)__float_as_int(sp.w);
            }
            fill += take; s0 += take; cnt -= take;
            if (fill == 64) flush();
        }
    };

    {
        int xa = max(cqx - 2, 0), xb = min(cqx + 2, 63);
        int ya = max(cqy - 2, 0), yb = min(cqy + 2, 63);
        for (int cx = xa; cx <= xb; cx++) feed(OF[cx * 64 + ya], OF[cx * 64 + yb + 1]);
    }
    int r = 2;
    while (true) {
        if (fill) flush();
        u64k T = (u64k)__shfl((long long)R, 15, 64);
        float d16 = __uint_as_float((unsigned)(T >> 32));
        float bm = (float)r * 0.03125f;
        if (d16 < bm * bm - 1e-5f) break;
        if (cqx - r <= 0 && cqx + r >= 63 && cqy - r <= 0 && cqy + r >= 63) break;
        r++;
        int ya = max(cqy - r, 0), yb = min(cqy + r, 63);
        if (cqx - r >= 0)  { int c0 = (cqx - r) * 64; feed(OF[c0 + ya], OF[c0 + yb + 1]); }
        if (cqx + r <= 63) { int c0 = (cqx + r) * 64; feed(OF[c0 + ya], OF[c0 + yb + 1]); }
        int xa2 = max(cqx - r + 1, 0), xb2 = min(cqx + r - 1, 63);
        for (int cx = xa2; cx <= xb2; cx++) {
            if (cqy - r >= 0)  { int cc = cx * 64 + cqy - r; feed(OF[cc], OF[cc + 1]); }
            if (cqy + r <= 63) { int cc = cx * 64 + cqy + r; feed(OF[cc], OF[cc + 1]); }
        }
    }
    if (lane < 16) {
        float d2 = __uint_as_float((unsigned)(R >> 32));
        float d = sqrtf(d2);
        oidx[w * 16 + lane] = (int)(unsigned)(R & 0xffffffffu);
        odist[w * 16 + lane] = d;
        if (lane == 15) lastd[w] = d;
    }
}

// ---------------------------------------------------------------- kNN points->grid: one wave per query
__global__ void __launch_bounds__(256) k_knn_out(
    const float2* __restrict__ coords, const float4* __restrict__ gp,
    int* __restrict__ oidx, float* __restrict__ odist, float* __restrict__ lastd) {
    int lane = threadIdx.x & 63;
    int w = (blockIdx.x * blockDim.x + threadIdx.x) >> 6;
    float2 c = coords[w];
    float qx = c.x, qy = c.y;
    float q2 = __fadd_rn(__fmul_rn(qx, qx), __fmul_rn(qy, qy));
    int i0 = (int)floorf((qx + 1.0f) * 31.5f);
    int j0 = (int)floorf((qy + 1.0f) * 31.5f);
    int li = min(max(i0 - 3, 0), 56);
    int lj = min(max(j0 - 3, 0), 56);
    int p = (li + (lane >> 3)) * 64 + (lj + (lane & 7));
    float4 sp = gp[p];
    float dot = __fadd_rn(__fmul_rn(qx, sp.x), __fmul_rn(qy, sp.y));
    float d2 = fmaxf(__fsub_rn(__fadd_rn(q2, sp.z), 2.0f * dot), 0.0f);
    u64k key = ((u64k)__float_as_uint(d2) << 32) | (unsigned)p;
    bsort64(key, lane);
    if (lane < 16) {
        float dd = sqrtf(__uint_as_float((unsigned)(key >> 32)));
        oidx[w * 16 + lane] = (int)(unsigned)(key & 0xffffffffu);
        odist[w * 16 + lane] = dd;
        if (lane == 15) lastd[w] = dd;
    }
}

// ---------------------------------------------------------------- exact lower-median via 32-step bisection
__global__ void __launch_bounds__(1024) k_median_bis(
    const float* __restrict__ vals, int n, float* __restrict__ sig) {
    __shared__ int wred[2][16];
    int tid = threadIdx.x;
    int lane = tid & 63, wv = tid >> 6;
    int cnt_per = n >> 10;           // 8 or 16
    unsigned v[16];
    for (int i = 0; i < cnt_per; i++) v[i] = __float_as_uint(vals[tid + (i << 10)]);
    int r = (n - 1) >> 1;
    unsigned prefix = 0;
    for (int bit = 31; bit >= 0; bit--) {
        unsigned cand = prefix | (1u << bit);
        int c = 0;
        for (int i = 0; i < cnt_per; i++) c += (v[i] < cand) ? 1 : 0;
        for (int o = 32; o >= 1; o >>= 1) c += __shfl_down(c, o, 64);
        int buf = bit & 1;
        if (lane == 0) wred[buf][wv] = c;
        __syncthreads();
        int tot = 0;
#pragma unroll
        for (int k = 0; k < 16; k++) tot += wred[buf][k];
        prefix = (tot <= r) ? cand : prefix;
    }
    if (tid == 0) *sig = fmaxf(__uint_as_float(prefix), 1e-6f);
}

// ---------------------------------------------------------------- weight split/pack for MFMA edge MLP
// WB layout: 52 fragments of 64 lanes x 8 bf16 (1 KB each):
//   W1: f = (nt*5 + kc)*2 + h          (nt<2, kc<5, h: 0=hi 1=lo)   frags 0..19
//   W2: f = 20 + (nt*4 + kc)*2 + h                                  frags 20..35
//   W3: f = 36 + (nt*4 + kc)*2 + h                                  frags 36..51
// B-frag element (lane,i): k = kc*16 + (lane>>5)*8 + i, col = nt*32 + (lane&31).
// W1 row map (x slots): k<7 -> W1[k]; k==7 -> 0 (pad); 8<=k<72 -> W1[k-1]; k>=72 -> 0.
__global__ void k_wcvt(const float* __restrict__ W1s, const float* __restrict__ W2s,
                       const float* __restrict__ W3s, short* __restrict__ WB) {
    int t = blockIdx.x * blockDim.x + threadIdx.x;   // 52*64 = 3328 threads
    if (t >= 3328) return;
    int f = t >> 6, lane = t & 63;
    const float* W; int h, nt, kc, l1 = 0;
    if (f < 20)      { W = W1s; int r = f;      h = r & 1; r >>= 1; nt = r / 5; kc = r % 5; l1 = 1; }
    else if (f < 36) { W = W2s; int r = f - 20; h = r & 1; r >>= 1; nt = r / 4; kc = r % 4; }
    else             { W = W3s; int r = f - 36; h = r & 1; r >>= 1; nt = r / 4; kc = r % 4; }
    int col = nt * 32 + (lane & 31);
    bf16x8 out;
#pragma unroll
    for (int i = 0; i < 8; i++) {
        int k = kc * 16 + (lane >> 5) * 8 + i;
        float w = 0.f;
        if (l1) {
            if (k < 7) w = W[k * 64 + col];
            else if (k >= 8 && k < 72) w = W[(k - 1) * 64 + col];
        } else {
            w = W[k * 64 + col];
        }
        unsigned u = __float_as_uint(w);
        unsigned hi = (u + 0x7fffu + ((u >> 16) & 1u)) & 0xffff0000u;
        float lo = w - __uint_as_float(hi);
        unsigned ul = __float_as_uint(lo);
        unsigned lr = ul + 0x7fffu + ((ul >> 16) & 1u);
        out[i] = h ? (short)(lr >> 16) : (short)(hi >> 16);
    }
    *(bf16x8*)(WB + ((long)f * 64 + lane) * 8) = out;
}

// ---------------------------------------------------------------- edge MLP via split-bf16 MFMA (v2)
// One wave = 2 queries (32 edge rows = M of a 32x32x16 MFMA). N=64 -> 2 tiles.
// 3-term split: D = Ah*Bh + Al*Bh + Ah*Bl (fp32 acc), err ~2^-17 per product.
// v2 vs v1 (v1: 70us, MfmaUtil 11%, VALUBusy 35%, VGPR 56 -> latency-bound):
//  - split-K dual accumulators (even/odd kc): 4 independent MFMA dep chains,
//    max serial chain 15 -> 9 (L1), 12 -> 6 (L2/L3)
//  - explicit one-kc-ahead B-fragment prefetch (+ cross-layer, + first frag
//    issued before staging): v1's VGPR=56 showed the compiler wasn't hoisting
//  - s_setprio(1) around MFMA clusters (barrier-free independent waves)
// C/D layout (HW-verified): col = lane&31, row = (reg&3) + 8*(reg>>2) + 4*(lane>>5).
template <int MODE>
__global__ void __launch_bounds__(256, 4) k_edge_mfma(
    const int* __restrict__ idxb, const float* __restrict__ distb,
    const float* __restrict__ sigp,
    const float2* __restrict__ coords, const float4* __restrict__ gp,
    const float* __restrict__ feats, const short* __restrict__ WB,
    const float* __restrict__ b1, const float* __restrict__ b2,
    const float* __restrict__ b3,
    float* __restrict__ outb, int Nq, int srcRows) {
    __shared__ float X[4][2432];           // per wave: 32 rows x 76 floats
    const int tid = threadIdx.x, wv = tid >> 6, lane = tid & 63;
    const int r31 = lane & 31, g = lane >> 5;
    const int qbase = (blockIdx.x * 4 + wv) * 2;
    const float sig = *sigp;
    float* X_ = X[wv];

    // issue first B-fragment load immediately: in flight during staging
    Frag4 cur = ldfrag4(WB, 0, 5, 0, lane);

    // ---- staging: 32 (query,edge) rows by lanes 0..31
    int si = 0; float wt = 0.f;
    if (lane < 32) {
        int q = lane >> 4, e = lane & 15;
        int gq = qbase + q;
        int b = gq / Nq, p = gq - b * Nq;
        si = idxb[gq * 16 + e];
        float d = distb[gq * 16 + e];
        wt = expf(-d / sig);
        float qx, qy, sx, sy;
        if (MODE == 0) {
            float4 gv = gp[p]; qx = gv.x; qy = gv.y;
            float2 cc = coords[(long)b * srcRows + si]; sx = cc.x; sy = cc.y;
        } else {
            float2 cc = coords[(long)b * Nq + p]; qx = cc.x; qy = cc.y;
            float4 gv = gp[si]; sx = gv.x; sy = gv.y;
        }
        float* row = X_ + lane * 76;
        *(float4*)row       = make_float4(qx, qy, sx, sy);
        *(float4*)(row + 4) = make_float4(qx - sx, qy - sy, d, 0.f);
    }
    // per-query weight sums (within each 16-lane group)
    float swt = wt;
#pragma unroll
    for (int m = 1; m < 16; m <<= 1) swt += __shfl_xor(swt, m, 64);
    // ---- feats gather: 32 rows x 16 float4
#pragma unroll
    for (int it = 0; it < 8; it++) {
        int slot = it * 64 + lane;
        int row = slot >> 4, f4 = slot & 15;
        int gq = qbase + (row >> 4);
        int b = gq / Nq;
        int sr = __shfl(si, row, 64);
        float4 v = *(const float4*)&feats[((long)b * srcRows + sr) * 64 + f4 * 4];
        *(float4*)&X_[row * 76 + 8 + f4 * 4] = v;
    }

    f32x16 aE0, aE1, aO0, aO1;     // even-kc / odd-kc accumulator pairs
    // ---------- layer 1: K = 71 (+pad), kc 0..4; kc=4 upper half is A=0
    {
        float bb0 = b1[r31], bb1 = b1[32 + r31];
#pragma unroll
        for (int i = 0; i < 16; i++) {
            aE0[i] = bb0; aE1[i] = bb1; aO0[i] = 0.f; aO1[i] = 0.f;
        }
#pragma unroll
        for (int kc = 0; kc < 5; kc++) {
            Frag4 nxt = (kc < 4) ? ldfrag4(WB, 0, 5, kc + 1, lane)
                                 : ldfrag4(WB, 20, 4, 0, lane);   // layer-2 kc0
            bf16x8 ah, al;
            if (kc == 4 && g) {
#pragma unroll
                for (int i = 0; i < 8; i++) { ah[i] = 0; al[i] = 0; }
            } else {
                const float* xp = &X_[r31 * 76 + kc * 16 + g * 8];
                cvt8v(*(const float4*)xp, *(const float4*)(xp + 4), ah, al);
            }
            __builtin_amdgcn_s_setprio(1);
            if (kc & 1) {
                aO0 = __builtin_amdgcn_mfma_f32_32x32x16_bf16(ah, cur.h0, aO0, 0, 0, 0);
                aO1 = __builtin_amdgcn_mfma_f32_32x32x16_bf16(ah, cur.h1, aO1, 0, 0, 0);
                aO0 = __builtin_amdgcn_mfma_f32_32x32x16_bf16(al, cur.h0, aO0, 0, 0, 0);
                aO1 = __builtin_amdgcn_mfma_f32_32x32x16_bf16(al, cur.h1, aO1, 0, 0, 0);
                aO0 = __builtin_amdgcn_mfma_f32_32x32x16_bf16(ah, cur.l0, aO0, 0, 0, 0);
                aO1 = __builtin_amdgcn_mfma_f32_32x32x16_bf16(ah, cur.l1, aO1, 0, 0, 0);
            } else {
                aE0 = __builtin_amdgcn_mfma_f32_32x32x16_bf16(ah, cur.h0, aE0, 0, 0, 0);
                aE1 = __builtin_amdgcn_mfma_f32_32x32x16_bf16(ah, cur.h1, aE1, 0, 0, 0);
                aE0 = __builtin_amdgcn_mfma_f32_32x32x16_bf16(al, cur.h0, aE0, 0, 0, 0);
                aE1 = __builtin_amdgcn_mfma_f32_32x32x16_bf16(al, cur.h1, aE1, 0, 0, 0);
                aE0 = __builtin_amdgcn_mfma_f32_32x32x16_bf16(ah, cur.l0, aE0, 0, 0, 0);
                aE1 = __builtin_amdgcn_mfma_f32_32x32x16_bf16(ah, cur.l1, aE1, 0, 0, 0);
            }
            __builtin_amdgcn_s_setprio(0);
            cur = nxt;
        }
    }
    // h = gelu(accE + accO) -> LDS (overwrites x slots 0..63; all layer-1 reads done)
#pragma unroll
    for (int reg = 0; reg < 16; reg++) {
        int row = (reg & 3) + 8 * (reg >> 2) + 4 * g;
        X_[row * 76 + r31]      = gelu_f(aE0[reg] + aO0[reg]);
        X_[row * 76 + 32 + r31] = gelu_f(aE1[reg] + aO1[reg]);
    }
    // ---------- layer 2
    {
        float bb0 = b2[r31], bb1 = b2[32 + r31];
#pragma unroll
        for (int i = 0; i < 16; i++) {
            aE0[i] = bb0; aE1[i] = bb1; aO0[i] = 0.f; aO1[i] = 0.f;
        }
#pragma unroll
        for (int kc = 0; kc < 4; kc++) {
            Frag4 nxt = (kc < 3) ? ldfrag4(WB, 20, 4, kc + 1, lane)
                                 : ldfrag4(WB, 36, 4, 0, lane);   // layer-3 kc0
            const float* xp = &X_[r31 * 76 + kc * 16 + g * 8];
            bf16x8 ah, al;
            cvt8v(*(const float4*)xp, *(const float4*)(xp + 4), ah, al);
            __builtin_amdgcn_s_setprio(1);
            if (kc & 1) {
                aO0 = __builtin_amdgcn_mfma_f32_32x32x16_bf16(ah, cur.h0, aO0, 0, 0, 0);
                aO1 = __builtin_amdgcn_mfma_f32_32x32x16_bf16(ah, cur.h1, aO1, 0, 0, 0);
                aO0 = __builtin_amdgcn_mfma_f32_32x32x16_bf16(al, cur.h0, aO0, 0, 0, 0);
                aO1 = __builtin_amdgcn_mfma_f32_32x32x16_bf16(al, cur.h1, aO1, 0, 0, 0);
                aO0 = __builtin_amdgcn_mfma_f32_32x32x16_bf16(ah, cur.l0, aO0, 0, 0, 0);
                aO1 = __builtin_amdgcn_mfma_f32_32x32x16_bf16(ah, cur.l1, aO1, 0, 0, 0);
            } else {
                aE0 = __builtin_amdgcn_mfma_f32_32x32x16_bf16(ah, cur.h0, aE0, 0, 0, 0);
                aE1 = __builtin_amdgcn_mfma_f32_32x32x16_bf16(ah, cur.h1, aE1, 0, 0, 0);
                aE0 = __builtin_amdgcn_mfma_f32_32x32x16_bf16(al, cur.h0, aE0, 0, 0, 0);
                aE1 = __builtin_amdgcn_mfma_f32_32x32x16_bf16(al, cur.h1, aE1, 0, 0, 0);
                aE0 = __builtin_amdgcn_mfma_f32_32x32x16_bf16(ah, cur.l0, aE0, 0, 0, 0);
                aE1 = __builtin_amdgcn_mfma_f32_32x32x16_bf16(ah, cur.l1, aE1, 0, 0, 0);
            }
            __builtin_amdgcn_s_setprio(0);
            cur = nxt;
        }
    }
#pragma unroll
    for (int reg = 0; reg < 16; reg++) {
        int row = (reg & 3) + 8 * (reg >> 2) + 4 * g;
        X_[row * 76 + r31]      = gelu_f(aE0[reg] + aO0[reg]);
        X_[row * 76 + 32 + r31] = gelu_f(aE1[reg] + aO1[reg]);
    }
    // ---------- layer 3 (no activation)
    {
        float bb0 = b3[r31], bb1 = b3[32 + r31];
#pragma unroll
        for (int i = 0; i < 16; i++) {
            aE0[i] = bb0; aE1[i] = bb1; aO0[i] = 0.f; aO1[i] = 0.f;
        }
#pragma unroll
        for (int kc = 0; kc < 4; kc++) {
            Frag4 nxt = cur;
            if (kc < 3) nxt = ldfrag4(WB, 36, 4, kc + 1, lane);
            const float* xp = &X_[r31 * 76 + kc * 16 + g * 8];
            bf16x8 ah, al;
            cvt8v(*(const float4*)xp, *(const float4*)(xp + 4), ah, al);
            __builtin_amdgcn_s_setprio(1);
            if (kc & 1) {
                aO0 = __builtin_amdgcn_mfma_f32_32x32x16_bf16(ah, cur.h0, aO0, 0, 0, 0);
                aO1 = __builtin_amdgcn_mfma_f32_32x32x16_bf16(ah, cur.h1, aO1, 0, 0, 0);
                aO0 = __builtin_amdgcn_mfma_f32_32x32x16_bf16(al, cur.h0, aO0, 0, 0, 0);
                aO1 = __builtin_amdgcn_mfma_f32_32x32x16_bf16(al, cur.h1, aO1, 0, 0, 0);
                aO0 = __builtin_amdgcn_mfma_f32_32x32x16_bf16(ah, cur.l0, aO0, 0, 0, 0);
                aO1 = __builtin_amdgcn_mfma_f32_32x32x16_bf16(ah, cur.l1, aO1, 0, 0, 0);
            } else {
                aE0 = __builtin_amdgcn_mfma_f32_32x32x16_bf16(ah, cur.h0, aE0, 0, 0, 0);
                aE1 = __builtin_amdgcn_mfma_f32_32x32x16_bf16(ah, cur.h1, aE1, 0, 0, 0);
                aE0 = __builtin_amdgcn_mfma_f32_32x32x16_bf16(al, cur.h0, aE0, 0, 0, 0);
                aE1 = __builtin_amdgcn_mfma_f32_32x32x16_bf16(al, cur.h1, aE1, 0, 0, 0);
                aE0 = __builtin_amdgcn_mfma_f32_32x32x16_bf16(ah, cur.l0, aE0, 0, 0, 0);
                aE1 = __builtin_amdgcn_mfma_f32_32x32x16_bf16(ah, cur.l1, aE1, 0, 0, 0);
            }
            __builtin_amdgcn_s_setprio(0);
            cur = nxt;
        }
    }
    // ---------- weighted aggregation over edges (rows) + output
    float wtv[16];
#pragma unroll
    for (int reg = 0; reg < 16; reg++)
        wtv[reg] = __shfl(wt, (reg & 3) + 8 * (reg >> 2) + 4 * g, 64);
    float s00 = 0.f, s01 = 0.f, s10 = 0.f, s11 = 0.f;   // s<query><ntile>
#pragma unroll
    for (int reg = 0; reg < 16; reg++) {
        float v0 = aE0[reg] + aO0[reg];
        float v1 = aE1[reg] + aO1[reg];
        if (reg < 8) { s00 = fmaf(wtv[reg], v0, s00); s01 = fmaf(wtv[reg], v1, s01); }
        else         { s10 = fmaf(wtv[reg], v0, s10); s11 = fmaf(wtv[reg], v1, s11); }
    }
    s00 += __shfl_xor(s00, 32, 64);
    s01 += __shfl_xor(s01, 32, 64);
    s10 += __shfl_xor(s10, 32, 64);
    s11 += __shfl_xor(s11, 32, 64);
    float sw0 = __shfl(swt, 0, 64), sw1 = __shfl(swt, 16, 64);
    if (g == 0) {
        float i0 = 1.0f / fmaxf(sw0, 1e-6f), i1 = 1.0f / fmaxf(sw1, 1e-6f);
        int gq0 = qbase, gq1 = qbase + 1;
        if (MODE == 0) {
            int b0 = gq0 / Nq, p0 = gq0 - b0 * Nq;
            int b1i = gq1 / Nq, p1 = gq1 - b1i * Nq;
            outb[((long)b0 * 64 + r31) * 4096 + p0]        = s00 * i0;   // transposed (b, col, p)
            outb[((long)b0 * 64 + 32 + r31) * 4096 + p0]   = s01 * i0;
            outb[((long)b1i * 64 + r31) * 4096 + p1]       = s10 * i1;
            outb[((long)b1i * 64 + 32 + r31) * 4096 + p1]  = s11 * i1;
        } else {
            outb[(long)gq0 * 64 + r31]      = s00 * i0;
            outb[(long)gq0 * 64 + 32 + r31] = s01 * i0;
            outb[(long)gq1 * 64 + r31]      = s10 * i1;
            outb[(long)gq1 * 64 + 32 + r31] = s11 * i1;
        }
    }
}

// ---------------------------------------------------------------- transpose (B,R,C) -> (B,C,R)
__global__ void k_transp(const float* __restrict__ src, float* __restrict__ dst, int R, int C) {
    __shared__ float t[32][33];
    int b = blockIdx.z;
    int c0 = blockIdx.x * 32, r0 = blockIdx.y * 32;
    int tx = threadIdx.x, ty0 = threadIdx.y;    // (32,8)
    for (int yy = ty0; yy < 32; yy += 8) {
        int r = r0 + yy, c = c0 + tx;
        if (r < R && c < C) t[yy][tx] = src[((long)b * R + r) * C + c];
    }
    __syncthreads();
    for (int yy = ty0; yy < 32; yy += 8) {
        int c = c0 + yy, r = r0 + tx;
        if (r < R && c < C) dst[((long)b * C + c) * R + r] = t[tx][yy];
    }
}

// ---------------------------------------------------------------- FNO: truncated forward DFT
__global__ void __launch_bounds__(1024) k_f1(const float* __restrict__ x, float* __restrict__ Xh) {
    int blk = blockIdx.x;    // b*64 + ch
    int tid = threadIdx.x;   // 1024
    __shared__ __align__(16) float img[4096];
    __shared__ float Tre[64][12], Tim[64][12];
    __shared__ float cs[64], sn[64];
    if (tid < 64) {
        double a = (2.0 * PI_ / 64.0) * (double)tid;
        cs[tid] = (float)cos(a);
        sn[tid] = (float)sin(a);
    }
    ((float4*)img)[tid] = ((const float4*)(x + (long)blk * 4096))[tid];
    __syncthreads();
    if (tid < 768) {                             // (h, c)
        int h = tid / 12, c = tid - 12 * h;
        float re = 0.f, im = 0.f;
        for (int w = 0; w < 64; w++) {
            float v = img[h * 64 + w];
            int k = (c * w) & 63;
            re = fmaf(v, cs[k], re);
            im = fmaf(-v, sn[k], im);
        }
        Tre[h][c] = re; Tim[h][c] = im;
    }
    __syncthreads();
    if (tid < 288) {                             // (x24, c12)
        int xx = tid / 12, c = tid - 12 * xx;
        int r = (xx < 12) ? xx : (xx + 40);
        float re = 0.f, im = 0.f;
        for (int h = 0; h < 64; h++) {
            int k = (r * h) & 63;
            float cr = cs[k], si = sn[k];
            float a = Tre[h][c], bb = Tim[h][c];
            re += a * cr + bb * si;
            im += bb * cr - a * si;
        }
        Xh[((long)blk * 288 + tid) * 2] = re;
        Xh[((long)blk * 288 + tid) * 2 + 1] = im;
    }
}

// mode-mix: Yhat[b,o,m] = sum_i Wc[i,o,m] * Xhat[b,i,m]
__global__ void __launch_bounds__(256) k_f2(const float* __restrict__ Xh, const float* __restrict__ s1,
                                            const float* __restrict__ s2, float* __restrict__ Yh) {
    int m = blockIdx.x;                  // 0..287
    int xx = m / 12, y = m - 12 * xx;
    const float* W; int xw;
    if (xx < 12) { W = s1; xw = xx; } else { W = s2; xw = xx - 12; }
    __shared__ float xr[128], xi[128];
    __shared__ float pr[256], pi[256];
    int tid = threadIdx.x;               // 256
    if (tid < 128) {
        int bb = tid >> 6, i = tid & 63;
        xr[tid] = Xh[(((long)bb * 64 + i) * 288 + m) * 2];
        xi[tid] = Xh[(((long)bb * 64 + i) * 288 + m) * 2 + 1];
    }
    __syncthreads();
    int half = tid >> 7;
    int t2 = tid & 127;
    int bb = t2 >> 6, o = t2 & 63;
    float re = 0.f, im = 0.f;
    for (int i = half * 32; i < half * 32 + 32; i++) {
        long wb = (long)i * 18432 + (long)o * 288 + xw * 24 + y * 2;
        float wr = W[wb], wi = W[wb + 1];
        float a = xr[bb * 64 + i], cc = xi[bb * 64 + i];
        re += a * wr - cc * wi;
        im += a * wi + cc * wr;
    }
    pr[tid] = re; pi[tid] = im;
    __syncthreads();
    if (tid < 128) {
        float re2 = pr[tid] + pr[tid + 128];
        float im2 = pi[tid] + pi[tid + 128];
        Yh[(((long)bb * 64 + o) * 288 + m) * 2] = re2;
        Yh[(((long)bb * 64 + o) * 288 + m) * 2 + 1] = im2;
    }
}

// inverse DFT + pointwise conv + bias + InstanceNorm + GELU, fused per (b, out-channel)
__global__ void __launch_bounds__(1024) k_f3(const float* __restrict__ Yh, const float* __restrict__ x,
                                             const float* __restrict__ pwW, const float* __restrict__ pwb,
                                             float* __restrict__ xo) {
    int blk = blockIdx.x;
    int b = blk >> 6, o = blk & 63;
    int tid = threadIdx.x;   // 1024; each thread owns 4 consecutive pixels
    __shared__ float yre[288], yim[288];
    __shared__ float Qre[64][12], Qim[64][12];
    __shared__ float cs[64], sn[64];
    __shared__ float red[1024];
    if (tid < 64) {
        double a = (2.0 * PI_ / 64.0) * (double)tid;
        cs[tid] = (float)cos(a);
        sn[tid] = (float)sin(a);
    }
    if (tid < 288) {
        yre[tid] = Yh[((long)blk * 288 + tid) * 2];
        yim[tid] = Yh[((long)blk * 288 + tid) * 2 + 1];
    }
    __syncthreads();
    if (tid < 768) {    // (h, c): complex ifft along rows (1/64 scale)
        int h = tid / 12, c = tid - 12 * h;
        float re = 0.f, im = 0.f;
#pragma unroll
        for (int xx = 0; xx < 24; xx++) {
            int r = (xx < 12) ? xx : (xx + 40);
            int k = (r * h) & 63;
            float wr = cs[k], wi = sn[k];
            float a = yre[xx * 12 + c], bb = yim[xx * 12 + c];
            re += a * wr - bb * wi;
            im += a * wi + bb * wr;
        }
        Qre[h][c] = re * (1.0f / 64.0f);
        Qim[h][c] = im * (1.0f / 64.0f);
    }
    __syncthreads();
    float bias = pwb[o];
    int h = tid >> 4;
    int w0 = (tid & 15) * 4;
    float sp0, sp1, sp2, sp3;
    {
        float base = Qre[h][0];
        sp0 = sp1 = sp2 = sp3 = base;
#pragma unroll
        for (int c = 1; c < 12; c++) {
            float qr = Qre[h][c], qi = Qim[h][c];
            int k0 = (c * w0) & 63, k1 = (c * (w0 + 1)) & 63;
            int k2 = (c * (w0 + 2)) & 63, k3 = (c * (w0 + 3)) & 63;
            sp0 += 2.0f * (qr * cs[k0] - qi * sn[k0]);
            sp1 += 2.0f * (qr * cs[k1] - qi * sn[k1]);
            sp2 += 2.0f * (qr * cs[k2] - qi * sn[k2]);
            sp3 += 2.0f * (qr * cs[k3] - qi * sn[k3]);
        }
    }
    float a0 = sp0 * (1.0f / 64.0f) + bias;
    float a1 = sp1 * (1.0f / 64.0f) + bias;
    float a2 = sp2 * (1.0f / 64.0f) + bias;
    float a3 = sp3 * (1.0f / 64.0f) + bias;
    const float* xb = x + ((long)b * 64) * 4096 + tid * 4;
    for (int i = 0; i < 64; i++) {
        float wv = pwW[o * 64 + i];
        const float4 xv = *(const float4*)(xb + (long)i * 4096);
        a0 = fmaf(xv.x, wv, a0);
        a1 = fmaf(xv.y, wv, a1);
        a2 = fmaf(xv.z, wv, a2);
        a3 = fmaf(xv.w, wv, a3);
    }
    red[tid] = a0 + a1 + a2 + a3;
    __syncthreads();
    for (int d = 512; d > 0; d >>= 1) { if (tid < d) red[tid] += red[tid + d]; __syncthreads(); }
    float mu = red[0] * (1.0f / 4096.0f);
    __syncthreads();
    float d0 = a0 - mu, d1 = a1 - mu, d2 = a2 - mu, d3 = a3 - mu;
    red[tid] = d0 * d0 + d1 * d1 + d2 * d2 + d3 * d3;
    __syncthreads();
    for (int d = 512; d > 0; d >>= 1) { if (tid < d) red[tid] += red[tid + d]; __syncthreads(); }
    float var = red[0] * (1.0f / 4096.0f);
    float inv = 1.0f / sqrtf(var + 1e-5f);
    float4 ov = make_float4(gelu_f(d0 * inv), gelu_f(d1 * inv), gelu_f(d2 * inv), gelu_f(d3 * inv));
    *(float4*)&xo[(long)blk * 4096 + tid * 4] = ov;
}

// ---------------------------------------------------------------- projection MLP (64 -> 64 -> 3)
__global__ void __launch_bounds__(256) k_proj(
    const float* __restrict__ y, const float* __restrict__ W1, const float* __restrict__ b1,
    const float* __restrict__ W2, const float* __restrict__ b2, float* __restrict__ out) {
    __shared__ __align__(16) float yr[4][64];
    __shared__ float h[4][64];
    int ql = threadIdx.x >> 6, j = threadIdx.x & 63;
    long node = (long)blockIdx.x * 4 + ql;
    yr[ql][j] = y[node * 64 + j];
    __syncthreads();
    float a = b1[j];
    for (int k = 0; k < 64; k += 4) {
        float w0 = W1[(k + 0) * 64 + j], w1 = W1[(k + 1) * 64 + j];
        float w2 = W1[(k + 2) * 64 + j], w3 = W1[(k + 3) * 64 + j];
        const float4 hv = *(const float4*)&yr[ql][k];
        a = fmaf(hv.x, w0, fmaf(hv.y, w1, fmaf(hv.z, w2, fmaf(hv.w, w3, a))));
    }
    h[ql][j] = gelu_f(a);
    __syncthreads();
    if (j < 3) {
        float a2 = b2[j];
        for (int k = 0; k < 64; k++) a2 = fmaf(h[ql][k], W2[k * 3 + j], a2);
        out[node * 3 + j] = a2;
    }
}

// ---------------------------------------------------------------- launch
extern "C" void kernel_launch(void* const* d_in, const int* in_sizes, int n_in,
                              void* d_out, int out_size, void* d_ws, size_t ws_size,
                              hipStream_t stream) {
    (void)in_sizes; (void)n_in; (void)out_size; (void)ws_size;
    const float* coords   = (const float*)d_in[0];
    const float* features = (const float*)d_in[1];
    const float* lift_W1 = (const float*)d_in[2];
    const float* lift_b1 = (const float*)d_in[3];
    const float* lift_W2 = (const float*)d_in[4];
    const float* lift_b2 = (const float*)d_in[5];
    const float* gin_W1 = (const float*)d_in[6];
    const float* gin_b1 = (const float*)d_in[7];
    const float* gin_W2 = (const float*)d_in[8];
    const float* gin_b2 = (const float*)d_in[9];
    const float* gin_W3 = (const float*)d_in[10];
    const float* gin_b3 = (const float*)d_in[11];
    const float* spec1 = (const float*)d_in[12];
    const float* spec2 = (const float*)d_in[13];
    const float* pw_W  = (const float*)d_in[14];
    const float* pw_b  = (const float*)d_in[15];
    const float* gout_W1 = (const float*)d_in[16];
    const float* gout_b1 = (const float*)d_in[17];
    const float* gout_W2 = (const float*)d_in[18];
    const float* gout_b2 = (const float*)d_in[19];
    const float* gout_W3 = (const float*)d_in[20];
    const float* gout_b3 = (const float*)d_in[21];
    const float* proj_W1 = (const float*)d_in[22];
    const float* proj_b1 = (const float*)d_in[23];
    const float* proj_W2 = (const float*)d_in[24];
    const float* proj_b2 = (const float*)d_in[25];

    char* ws = (char*)d_ws;
    size_t off = 0;
    auto alloc = [&](size_t bytes) -> char* {
        char* p = ws + off;
        off = (off + bytes + 255) & ~(size_t)255;
        return p;
    };
    float4* grid_pack = (float4*)alloc((size_t)NG * 16);
    float*  feat      = (float*)alloc((size_t)B_ * N_ * 64 * 4);
    int*    bin_cnt   = (int*)alloc((size_t)B_ * 4096 * 4);
    int*    bin_fill  = (int*)alloc((size_t)B_ * 4096 * 4);
    int*    bin_off   = (int*)alloc((size_t)B_ * 4097 * 4);
    float4* srt       = (float4*)alloc((size_t)B_ * N_ * 16);
    int*    idx_in    = (int*)alloc((size_t)B_ * NG * 16 * 4);
    float*  dist_in   = (float*)alloc((size_t)B_ * NG * 16 * 4);
    float*  lastd_in  = (float*)alloc((size_t)B_ * NG * 4);
    float*  sig_in    = (float*)alloc(256);
    float*  xb0       = (float*)alloc((size_t)B_ * 64 * NG * 4);
    float*  xb1       = (float*)alloc((size_t)B_ * 64 * NG * 4);
    float*  Xh        = (float*)alloc((size_t)B_ * 64 * 288 * 2 * 4);
    float*  Yh        = (float*)alloc((size_t)B_ * 64 * 288 * 2 * 4);
    float*  g2        = (float*)alloc((size_t)B_ * NG * 64 * 4);
    int*    idx_out   = (int*)alloc((size_t)B_ * N_ * 16 * 4);
    float*  dist_out  = (float*)alloc((size_t)B_ * N_ * 16 * 4);
    float*  lastd_out = (float*)alloc((size_t)B_ * N_ * 4);
    float*  sig_out   = (float*)alloc(256);
    float*  ybuf      = (float*)alloc((size_t)B_ * N_ * 64 * 4);
    short*  wb_in     = (short*)alloc((size_t)52 * 1024);   // 52 x 1KB bf16 hi/lo fragments
    short*  wb_out    = (short*)alloc((size_t)52 * 1024);

    hipMemsetAsync(bin_cnt, 0, (size_t)B_ * 4096 * 4, stream);
    hipMemsetAsync(bin_fill, 0, (size_t)B_ * 4096 * 4, stream);

    k_wcvt<<<13, 256, 0, stream>>>(gin_W1, gin_W2, gin_W3, wb_in);
    k_wcvt<<<13, 256, 0, stream>>>(gout_W1, gout_W2, gout_W3, wb_out);
    k_lift<<<(B_ * N_) / 4, 256, 0, stream>>>(features, lift_W1, lift_b1, lift_W2, lift_b2, feat);
    k_bincount<<<(B_ * N_) / 256, 256, 0, stream>>>((const float2*)coords, bin_cnt, grid_pack);
    k_binscan<<<B_, 1024, 0, stream>>>(bin_cnt, bin_off);
    k_binscatter<<<(B_ * N_) / 256, 256, 0, stream>>>((const float2*)coords, bin_off, bin_fill, srt);
    k_knn_in<<<(B_ * NG * 64) / 256, 256, 0, stream>>>(grid_pack, srt, bin_off, idx_in, dist_in, lastd_in);
    k_median_bis<<<1, 1024, 0, stream>>>(lastd_in, B_ * NG, sig_in);
    k_edge_mfma<0><<<(B_ * NG) / 8, 256, 0, stream>>>(idx_in, dist_in, sig_in,
        (const float2*)coords, grid_pack, feat, wb_in,
        gin_b1, gin_b2, gin_b3, xb0, NG, N_);
    float* xc = xb0; float* xn = xb1;
    for (int d = 0; d < 3; d++) {
        k_f1<<<B_ * 64, 1024, 0, stream>>>(xc, Xh);
        k_f2<<<288, 256, 0, stream>>>(Xh, spec1 + (size_t)d * 1179648, spec2 + (size_t)d * 1179648, Yh);
        k_f3<<<B_ * 64, 1024, 0, stream>>>(Yh, xc, pw_W + (size_t)d * 4096, pw_b + (size_t)d * 64, xn);
        float* tmp = xc; xc = xn; xn = tmp;
    }
    {
        dim3 g(NG / 32, 64 / 32, B_); dim3 t(32, 8);
        k_transp<<<g, t, 0, stream>>>(xc, g2, 64, NG);
    }
    k_knn_out<<<(B_ * N_ * 64) / 256, 256, 0, stream>>>((const float2*)coords, grid_pack, idx_out, dist_out, lastd_out);
    k_median_bis<<<1, 1024, 0, stream>>>(lastd_out, B_ * N_, sig_out);
    k_edge_mfma<1><<<(B_ * N_) / 8, 256, 0, stream>>>(idx_out, dist_out, sig_out,
        (const float2*)coords, grid_pack, g2, wb_out,
        gout_b1, gout_b2, gout_b3, ybuf, N_, NG);
    k_proj<<<(B_ * N_) / 4, 256, 0, stream>>>(ybuf, proj_W1, proj_b1, proj_W2, proj_b2, (float*)d_out);
}

// Round 3
// 451.736 us; speedup vs baseline: 1.2206x; 1.2206x over previous
//
#include <hip/hip_runtime.h>
#include <math.h>

#define B_ 2
#define N_ 8192          // points per batch
#define G_ 64
#define NG 4096          // G*G latent grid points
#define WID_ 64
#define K_ 16
#define CIN_ 6
#define COUT_ 3
#define PI_ 3.14159265358979323846

typedef unsigned long long u64k;
typedef __attribute__((ext_vector_type(8))) short bf16x8;   // 8 bf16 bit-patterns (4 VGPR)
typedef __attribute__((ext_vector_type(16))) float f32x16;  // 32x32 MFMA acc

// ---------------------------------------------------------------- helpers
__device__ __forceinline__ float gelu_f(float x) {
    return 0.5f * x * (1.0f + erff(x * 0.70710678118654752440f));
}
__device__ __forceinline__ int cellof(float v) {
    int c = (int)floorf((v + 1.0f) * 32.0f);
    return min(63, max(0, c));
}
__device__ __forceinline__ u64k umin64(u64k a, u64k b) { return a < b ? a : b; }
__device__ __forceinline__ u64k umax64(u64k a, u64k b) { return a < b ? b : a; }
__device__ __forceinline__ u64k shflxor64(u64k v, int m) {
    return (u64k)__shfl_xor((long long)v, m, 64);
}
__device__ __forceinline__ void bsort64(u64k& key, int lane) {
#pragma unroll
    for (int sz = 2; sz <= 64; sz <<= 1) {
#pragma unroll
        for (int j = sz >> 1; j >= 1; j >>= 1) {
            u64k o = shflxor64(key, j);
            bool keep_min = ((lane & j) == 0) == ((lane & sz) == 0);
            key = keep_min ? umin64(key, o) : umax64(key, o);
        }
    }
}
__device__ __forceinline__ void bmerge_into(u64k& R, u64k key, int lane) {
    u64k o = shflxor64(key, 63);
    u64k L = umin64(R, o);
#pragma unroll
    for (int j = 32; j >= 1; j >>= 1) {
        u64k t = shflxor64(L, j);
        L = ((lane & j) == 0) ? umin64(L, t) : umax64(L, t);
    }
    R = L;
}
// split fp32 -> bf16 hi (RNE) + bf16 lo (truncated residual); err ~2^-17 rel
__device__ __forceinline__ void cvt8v(float4 a, float4 b, bf16x8& hv, bf16x8& lv) {
    float v[8] = {a.x, a.y, a.z, a.w, b.x, b.y, b.z, b.w};
#pragma unroll
    for (int i = 0; i < 8; i++) {
        unsigned u = __float_as_uint(v[i]);
        unsigned r = u + 0x7fffu + ((u >> 16) & 1u);
        hv[i] = (short)(r >> 16);
        float lo = v[i] - __uint_as_float(r & 0xffff0000u);
        lv[i] = (short)(__float_as_uint(lo) >> 16);
    }
}
__device__ __forceinline__ bf16x8 ldfrag(const short* __restrict__ WB, int f, int lane) {
    return *(const bf16x8*)(WB + ((long)f * 64 + lane) * 8);
}
struct Frag4 { bf16x8 h0, l0, h1, l1; };
// base/nk select layer: L1 base=0 nk=5, L2 base=20 nk=4, L3 base=36 nk=4
__device__ __forceinline__ Frag4 ldfrag4(const short* __restrict__ WB, int base, int nk,
                                         int kc, int lane) {
    Frag4 f;
    f.h0 = ldfrag(WB, base + (0 * nk + kc) * 2 + 0, lane);
    f.l0 = ldfrag(WB, base + (0 * nk + kc) * 2 + 1, lane);
    f.h1 = ldfrag(WB, base + (1 * nk + kc) * 2 + 0, lane);
    f.l1 = ldfrag(WB, base + (1 * nk + kc) * 2 + 1, lane);
    return f;
}

// ---------------------------------------------------------------- binning (+ grid gen fused)
__global__ void k_bincount(const float2* __restrict__ coords, int* __restrict__ cnt,
                           float4* __restrict__ gp) {
    int t = blockIdx.x * blockDim.x + threadIdx.x;
    if (t < NG) {        // numpy linspace semantics grid gen
        int i = t >> 6, j = t & 63;
        double st = 2.0 / 63.0;
        float gx = (i == 63) ? 1.0f : (float)(-1.0 + st * (double)i);
        float gy = (j == 63) ? 1.0f : (float)(-1.0 + st * (double)j);
        float s2 = __fadd_rn(__fmul_rn(gx, gx), __fmul_rn(gy, gy));
        gp[t] = make_float4(gx, gy, s2, 0.f);
    }
    if (t >= B_ * N_) return;
    float2 c = coords[t];
    int b = t >> 13;
    int cell = cellof(c.x) * 64 + cellof(c.y);
    atomicAdd(&cnt[b * 4096 + cell], 1);
}
__global__ void k_binscan(const int* __restrict__ cnt, int* __restrict__ offs) {
    int b = blockIdx.x, t = threadIdx.x;    // 1024 threads
    __shared__ int s[1024];
    int4 v = ((const int4*)(cnt + b * 4096))[t];
    int sum = v.x + v.y + v.z + v.w;
    s[t] = sum;
    __syncthreads();
    for (int d = 1; d < 1024; d <<= 1) {
        int x = (t >= d) ? s[t - d] : 0;
        __syncthreads();
        s[t] += x;
        __syncthreads();
    }
    int incl = s[t], excl = incl - sum;
    int* ob = offs + b * 4097;
    ob[4 * t] = excl; ob[4 * t + 1] = excl + v.x;
    ob[4 * t + 2] = excl + v.x + v.y; ob[4 * t + 3] = excl + v.x + v.y + v.z;
    if (t == 1023) ob[4096] = incl;
}
__global__ void k_binscatter(const float2* __restrict__ coords, const int* __restrict__ offs,
                             int* __restrict__ fill, float4* __restrict__ srt) {
    int t = blockIdx.x * blockDim.x + threadIdx.x;
    if (t >= B_ * N_) return;
    float2 c = coords[t];
    int b = t >> 13, n = t & 8191;
    int cell = cellof(c.x) * 64 + cellof(c.y);
    int pos = offs[b * 4097 + cell] + atomicAdd(&fill[b * 4096 + cell], 1);
    float s2 = __fadd_rn(__fmul_rn(c.x, c.x), __fmul_rn(c.y, c.y));
    srt[b * N_ + pos] = make_float4(c.x, c.y, s2, __int_as_float(n));
}

// ---------------------------------------------------------------- lift MLP
__global__ void __launch_bounds__(256) k_lift(
    const float* __restrict__ fin, const float* __restrict__ W1,
    const float* __restrict__ b1, const float* __restrict__ W2,
    const float* __restrict__ b2, float* __restrict__ fout) {
    __shared__ float xr[4][8];
    __shared__ __align__(16) float h[4][64];
    int ql = threadIdx.x >> 6, j = threadIdx.x & 63;
    int node = blockIdx.x * 4 + ql;
    if (j < CIN_) xr[ql][j] = fin[node * CIN_ + j];
    __syncthreads();
    float a = b1[j];
#pragma unroll
    for (int i = 0; i < CIN_; i++) a = fmaf(xr[ql][i], W1[i * 64 + j], a);
    h[ql][j] = gelu_f(a);
    __syncthreads();
    float a2 = b2[j];
    for (int k = 0; k < 64; k += 4) {
        float w0 = W2[(k + 0) * 64 + j], w1 = W2[(k + 1) * 64 + j];
        float w2 = W2[(k + 2) * 64 + j], w3 = W2[(k + 3) * 64 + j];
        const float4 hv = *(const float4*)&h[ql][k];
        a2 = fmaf(hv.x, w0, fmaf(hv.y, w1, fmaf(hv.z, w2, fmaf(hv.w, w3, a2))));
    }
    fout[node * 64 + j] = a2;
}

// ---------------------------------------------------------------- kNN grid->points: one wave per query
__global__ void __launch_bounds__(256) k_knn_in(
    const float4* __restrict__ gp, const float4* __restrict__ srt,
    const int* __restrict__ offs, int* __restrict__ oidx,
    float* __restrict__ odist, float* __restrict__ lastd) {
    int lane = threadIdx.x & 63;
    int w = (blockIdx.x * blockDim.x + threadIdx.x) >> 6;
    int b = w >> 12, p = w & 4095;
    float4 q = gp[p];
    float qx = q.x, qy = q.y, q2 = q.z;
    int cqx = cellof(qx), cqy = cellof(qy);
    const float4* S = srt + b * N_;
    const int* OF = offs + b * 4097;

    u64k R = ~0ull;
    u64k pend = ~0ull;
    int fill = 0;

    auto flush = [&]() {
        bsort64(pend, lane);
        bmerge_into(R, pend, lane);
        pend = ~0ull;
        fill = 0;
    };
    auto feed = [&](int s0, int s1) {
        int cnt = s1 - s0;
        while (cnt > 0) {
            int take = min(cnt, 64 - fill);
            int t = lane - fill;
            if (t >= 0 && t < take) {
                float4 sp = S[s0 + t];
                float dot = __fadd_rn(__fmul_rn(qx, sp.x), __fmul_rn(qy, sp.y));
                float d2 = __fsub_rn(__fadd_rn(q2, sp.z), 2.0f * dot);
                d2 = fmaxf(d2, 0.0f);
                pend = ((u64k)__float_as_uint(d2) << 32) | (unsigned)__float_as_int(sp.w);
            }
            fill += take; s0 += take; cnt -= take;
            if (fill == 64) flush();
        }
    };

    {
        int xa = max(cqx - 2, 0), xb = min(cqx + 2, 63);
        int ya = max(cqy - 2, 0), yb = min(cqy + 2, 63);
        for (int cx = xa; cx <= xb; cx++) feed(OF[cx * 64 + ya], OF[cx * 64 + yb + 1]);
    }
    int r = 2;
    while (true) {
        if (fill) flush();
        u64k T = (u64k)__shfl((long long)R, 15, 64);
        float d16 = __uint_as_float((unsigned)(T >> 32));
        float bm = (float)r * 0.03125f;
        if (d16 < bm * bm - 1e-5f) break;
        if (cqx - r <= 0 && cqx + r >= 63 && cqy - r <= 0 && cqy + r >= 63) break;
        r++;
        int ya = max(cqy - r, 0), yb = min(cqy + r, 63);
        if (cqx - r >= 0)  { int c0 = (cqx - r) * 64; feed(OF[c0 + ya], OF[c0 + yb + 1]); }
        if (cqx + r <= 63) { int c0 = (cqx + r) * 64; feed(OF[c0 + ya], OF[c0 + yb + 1]); }
        int xa2 = max(cqx - r + 1, 0), xb2 = min(cqx + r - 1, 63);
        for (int cx = xa2; cx <= xb2; cx++) {
            if (cqy - r >= 0)  { int cc = cx * 64 + cqy - r; feed(OF[cc], OF[cc + 1]); }
            if (cqy + r <= 63) { int cc = cx * 64 + cqy + r; feed(OF[cc], OF[cc + 1]); }
        }
    }
    if (lane < 16) {
        float d2 = __uint_as_float((unsigned)(R >> 32));
        float d = sqrtf(d2);
        oidx[w * 16 + lane] = (int)(unsigned)(R & 0xffffffffu);
        odist[w * 16 + lane] = d;
        if (lane == 15) lastd[w] = d;
    }
}

// ---------------------------------------------------------------- kNN points->grid: one wave per query
__global__ void __launch_bounds__(256) k_knn_out(
    const float2* __restrict__ coords, const float4* __restrict__ gp,
    int* __restrict__ oidx, float* __restrict__ odist, float* __restrict__ lastd) {
    int lane = threadIdx.x & 63;
    int w = (blockIdx.x * blockDim.x + threadIdx.x) >> 6;
    float2 c = coords[w];
    float qx = c.x, qy = c.y;
    float q2 = __fadd_rn(__fmul_rn(qx, qx), __fmul_rn(qy, qy));
    int i0 = (int)floorf((qx + 1.0f) * 31.5f);
    int j0 = (int)floorf((qy + 1.0f) * 31.5f);
    int li = min(max(i0 - 3, 0), 56);
    int lj = min(max(j0 - 3, 0), 56);
    int p = (li + (lane >> 3)) * 64 + (lj + (lane & 7));
    float4 sp = gp[p];
    float dot = __fadd_rn(__fmul_rn(qx, sp.x), __fmul_rn(qy, sp.y));
    float d2 = fmaxf(__fsub_rn(__fadd_rn(q2, sp.z), 2.0f * dot), 0.0f);
    u64k key = ((u64k)__float_as_uint(d2) << 32) | (unsigned)p;
    bsort64(key, lane);
    if (lane < 16) {
        float dd = sqrtf(__uint_as_float((unsigned)(key >> 32)));
        oidx[w * 16 + lane] = (int)(unsigned)(key & 0xffffffffu);
        odist[w * 16 + lane] = dd;
        if (lane == 15) lastd[w] = dd;
    }
}

// ---------------------------------------------------------------- exact lower-median via 32-step bisection
__global__ void __launch_bounds__(1024) k_median_bis(
    const float* __restrict__ vals, int n, float* __restrict__ sig) {
    __shared__ int wred[2][16];
    int tid = threadIdx.x;
    int lane = tid & 63, wv = tid >> 6;
    int cnt_per = n >> 10;           // 8 or 16
    unsigned v[16];
    for (int i = 0; i < cnt_per; i++) v[i] = __float_as_uint(vals[tid + (i << 10)]);
    int r = (n - 1) >> 1;
    unsigned prefix = 0;
    for (int bit = 31; bit >= 0; bit--) {
        unsigned cand = prefix | (1u << bit);
        int c = 0;
        for (int i = 0; i < cnt_per; i++) c += (v[i] < cand) ? 1 : 0;
        for (int o = 32; o >= 1; o >>= 1) c += __shfl_down(c, o, 64);
        int buf = bit & 1;
        if (lane == 0) wred[buf][wv] = c;
        __syncthreads();
        int tot = 0;
#pragma unroll
        for (int k = 0; k < 16; k++) tot += wred[buf][k];
        prefix = (tot <= r) ? cand : prefix;
    }
    if (tid == 0) *sig = fmaxf(__uint_as_float(prefix), 1e-6f);
}

// ---------------------------------------------------------------- weight split/pack for MFMA edge MLP
// WB layout: 52 fragments of 64 lanes x 8 bf16 (1 KB each):
//   W1: f = (nt*5 + kc)*2 + h          (nt<2, kc<5, h: 0=hi 1=lo)   frags 0..19
//   W2: f = 20 + (nt*4 + kc)*2 + h                                  frags 20..35
//   W3: f = 36 + (nt*4 + kc)*2 + h                                  frags 36..51
// B-frag element (lane,i): k = kc*16 + (lane>>5)*8 + i, col = nt*32 + (lane&31).
// W1 row map (x slots): k<7 -> W1[k]; k==7 -> 0 (pad); 8<=k<72 -> W1[k-1]; k>=72 -> 0.
__global__ void k_wcvt(const float* __restrict__ W1s, const float* __restrict__ W2s,
                       const float* __restrict__ W3s, short* __restrict__ WB) {
    int t = blockIdx.x * blockDim.x + threadIdx.x;   // 52*64 = 3328 threads
    if (t >= 3328) return;
    int f = t >> 6, lane = t & 63;
    const float* W; int h, nt, kc, l1 = 0;
    if (f < 20)      { W = W1s; int r = f;      h = r & 1; r >>= 1; nt = r / 5; kc = r % 5; l1 = 1; }
    else if (f < 36) { W = W2s; int r = f - 20; h = r & 1; r >>= 1; nt = r / 4; kc = r % 4; }
    else             { W = W3s; int r = f - 36; h = r & 1; r >>= 1; nt = r / 4; kc = r % 4; }
    int col = nt * 32 + (lane & 31);
    bf16x8 out;
#pragma unroll
    for (int i = 0; i < 8; i++) {
        int k = kc * 16 + (lane >> 5) * 8 + i;
        float w = 0.f;
        if (l1) {
            if (k < 7) w = W[k * 64 + col];
            else if (k >= 8 && k < 72) w = W[(k - 1) * 64 + col];
        } else {
            w = W[k * 64 + col];
        }
        unsigned u = __float_as_uint(w);
        unsigned hi = (u + 0x7fffu + ((u >> 16) & 1u)) & 0xffff0000u;
        float lo = w - __uint_as_float(hi);
        unsigned ul = __float_as_uint(lo);
        unsigned lr = ul + 0x7fffu + ((ul >> 16) & 1u);
        out[i] = h ? (short)(lr >> 16) : (short)(hi >> 16);
    }
    *(bf16x8*)(WB + ((long)f * 64 + lane) * 8) = out;
}

// ---------------------------------------------------------------- edge MLP via split-bf16 MFMA (v3)
// One wave = 2 queries (32 edge rows = M of a 32x32x16 MFMA). N=64 -> 2 tiles.
// 3-term split: D = Ah*Bh + Al*Bh + Ah*Bl (fp32 acc), err ~2^-17 per product.
// v3 = v1 (single acc pair, 70us, no spill) + latency levers only.
// v2 lesson (81us, FETCH 70MB WRITE 133MB = scratch): 4 accs + 2 Frag4 blew the
// 128-reg cap from (256,4); split-K is NOT affordable. v3 budget: 32 acc + 16
// cur + 16 nxt + 8 x + 8 ah/al + ~25 misc ~= 105 < 128.
//  - one-kc-ahead B-fragment prefetch (cur/nxt), cross-layer, first issued
//    before staging
//  - one-kc-ahead A-side LDS read (xa/xb), guarded at the kc=3->4 g=1 pad
//  - feats gather batched: 8 loads -> regs, then 8 LDS writes (1 vmcnt drain)
//  - s_setprio(1) around MFMA clusters (barrier-free staggered waves)
// C/D layout (HW-verified): col = lane&31, row = (reg&3) + 8*(reg>>2) + 4*(lane>>5).
template <int MODE>
__global__ void __launch_bounds__(256, 4) k_edge_mfma(
    const int* __restrict__ idxb, const float* __restrict__ distb,
    const float* __restrict__ sigp,
    const float2* __restrict__ coords, const float4* __restrict__ gp,
    const float* __restrict__ feats, const short* __restrict__ WB,
    const float* __restrict__ b1, const float* __restrict__ b2,
    const float* __restrict__ b3,
    float* __restrict__ outb, int Nq, int srcRows) {
    __shared__ float X[4][2432];           // per wave: 32 rows x 76 floats
    const int tid = threadIdx.x, wv = tid >> 6, lane = tid & 63;
    const int r31 = lane & 31, g = lane >> 5;
    const int qbase = (blockIdx.x * 4 + wv) * 2;
    const float sig = *sigp;
    float* X_ = X[wv];

    // issue first B-fragment load immediately: in flight during staging
    Frag4 cur = ldfrag4(WB, 0, 5, 0, lane);

    // ---- staging: 32 (query,edge) rows by lanes 0..31
    int si = 0; float wt = 0.f;
    if (lane < 32) {
        int q = lane >> 4, e = lane & 15;
        int gq = qbase + q;
        int b = gq / Nq, p = gq - b * Nq;
        si = idxb[gq * 16 + e];
        float d = distb[gq * 16 + e];
        wt = expf(-d / sig);
        float qx, qy, sx, sy;
        if (MODE == 0) {
            float4 gv = gp[p]; qx = gv.x; qy = gv.y;
            float2 cc = coords[(long)b * srcRows + si]; sx = cc.x; sy = cc.y;
        } else {
            float2 cc = coords[(long)b * Nq + p]; qx = cc.x; qy = cc.y;
            float4 gv = gp[si]; sx = gv.x; sy = gv.y;
        }
        float* row = X_ + lane * 76;
        *(float4*)row       = make_float4(qx, qy, sx, sy);
        *(float4*)(row + 4) = make_float4(qx - sx, qy - sy, d, 0.f);
    }
    // per-query weight sums (within each 16-lane group)
    float swt = wt;
#pragma unroll
    for (int m = 1; m < 16; m <<= 1) swt += __shfl_xor(swt, m, 64);
    // ---- feats gather: 32 rows x 16 float4; batch loads -> regs, then write
    {
        float4 fv[8];
#pragma unroll
        for (int it = 0; it < 8; it++) {
            int slot = it * 64 + lane;
            int row = slot >> 4, f4 = slot & 15;
            int gq = qbase + (row >> 4);
            int b = gq / Nq;
            int sr = __shfl(si, row, 64);
            fv[it] = *(const float4*)&feats[((long)b * srcRows + sr) * 64 + f4 * 4];
        }
#pragma unroll
        for (int it = 0; it < 8; it++) {
            int slot = it * 64 + lane;
            int row = slot >> 4, f4 = slot & 15;
            *(float4*)&X_[row * 76 + 8 + f4 * 4] = fv[it];
        }
    }

    f32x16 acc0, acc1;
    float4 xa, xb;
    // ---------- layer 1: K = 71 (+pad), kc 0..4; kc=4 upper half is A=0
    {
        float bb0 = b1[r31], bb1 = b1[32 + r31];
#pragma unroll
        for (int i = 0; i < 16; i++) { acc0[i] = bb0; acc1[i] = bb1; }
        {
            const float* xp = &X_[r31 * 76 + g * 8];
            xa = *(const float4*)xp; xb = *(const float4*)(xp + 4);
        }
#pragma unroll
        for (int kc = 0; kc < 5; kc++) {
            Frag4 nxt = (kc < 4) ? ldfrag4(WB, 0, 5, kc + 1, lane)
                                 : ldfrag4(WB, 20, 4, 0, lane);   // layer-2 kc0
            bf16x8 ah, al;
            if (kc == 4 && g) {
#pragma unroll
                for (int i = 0; i < 8; i++) { ah[i] = 0; al[i] = 0; }
            } else {
                cvt8v(xa, xb, ah, al);
            }
            // prefetch next-kc A pair (skip kc=3,g=1: that is the zero pad region)
            if (kc < 4 && (kc != 3 || g == 0)) {
                const float* xp = &X_[r31 * 76 + (kc + 1) * 16 + g * 8];
                xa = *(const float4*)xp; xb = *(const float4*)(xp + 4);
            }
            __builtin_amdgcn_s_setprio(1);
            acc0 = __builtin_amdgcn_mfma_f32_32x32x16_bf16(ah, cur.h0, acc0, 0, 0, 0);
            acc1 = __builtin_amdgcn_mfma_f32_32x32x16_bf16(ah, cur.h1, acc1, 0, 0, 0);
            acc0 = __builtin_amdgcn_mfma_f32_32x32x16_bf16(al, cur.h0, acc0, 0, 0, 0);
            acc1 = __builtin_amdgcn_mfma_f32_32x32x16_bf16(al, cur.h1, acc1, 0, 0, 0);
            acc0 = __builtin_amdgcn_mfma_f32_32x32x16_bf16(ah, cur.l0, acc0, 0, 0, 0);
            acc1 = __builtin_amdgcn_mfma_f32_32x32x16_bf16(ah, cur.l1, acc1, 0, 0, 0);
            __builtin_amdgcn_s_setprio(0);
            cur = nxt;
        }
    }
    // h = gelu(acc) -> LDS (overwrites x slots 0..63; all layer-1 reads done)
#pragma unroll
    for (int reg = 0; reg < 16; reg++) {
        int row = (reg & 3) + 8 * (reg >> 2) + 4 * g;
        X_[row * 76 + r31]      = gelu_f(acc0[reg]);
        X_[row * 76 + 32 + r31] = gelu_f(acc1[reg]);
    }
    // ---------- layer 2
    {
        float bb0 = b2[r31], bb1 = b2[32 + r31];
#pragma unroll
        for (int i = 0; i < 16; i++) { acc0[i] = bb0; acc1[i] = bb1; }
        {
            const float* xp = &X_[r31 * 76 + g * 8];
            xa = *(const float4*)xp; xb = *(const float4*)(xp + 4);
        }
#pragma unroll
        for (int kc = 0; kc < 4; kc++) {
            Frag4 nxt = (kc < 3) ? ldfrag4(WB, 20, 4, kc + 1, lane)
                                 : ldfrag4(WB, 36, 4, 0, lane);   // layer-3 kc0
            bf16x8 ah, al;
            cvt8v(xa, xb, ah, al);
            if (kc < 3) {
                const float* xp = &X_[r31 * 76 + (kc + 1) * 16 + g * 8];
                xa = *(const float4*)xp; xb = *(const float4*)(xp + 4);
            }
            __builtin_amdgcn_s_setprio(1);
            acc0 = __builtin_amdgcn_mfma_f32_32x32x16_bf16(ah, cur.h0, acc0, 0, 0, 0);
            acc1 = __builtin_amdgcn_mfma_f32_32x32x16_bf16(ah, cur.h1, acc1, 0, 0, 0);
            acc0 = __builtin_amdgcn_mfma_f32_32x32x16_bf16(al, cur.h0, acc0, 0, 0, 0);
            acc1 = __builtin_amdgcn_mfma_f32_32x32x16_bf16(al, cur.h1, acc1, 0, 0, 0);
            acc0 = __builtin_amdgcn_mfma_f32_32x32x16_bf16(ah, cur.l0, acc0, 0, 0, 0);
            acc1 = __builtin_amdgcn_mfma_f32_32x32x16_bf16(ah, cur.l1, acc1, 0, 0, 0);
            __builtin_amdgcn_s_setprio(0);
            cur = nxt;
        }
    }
#pragma unroll
    for (int reg = 0; reg < 16; reg++) {
        int row = (reg & 3) + 8 * (reg >> 2) + 4 * g;
        X_[row * 76 + r31]      = gelu_f(acc0[reg]);
        X_[row * 76 + 32 + r31] = gelu_f(acc1[reg]);
    }
    // ---------- layer 3 (no activation)
    {
        float bb0 = b3[r31], bb1 = b3[32 + r31];
#pragma unroll
        for (int i = 0; i < 16; i++) { acc0[i] = bb0; acc1[i] = bb1; }
        {
            const float* xp = &X_[r31 * 76 + g * 8];
            xa = *(const float4*)xp; xb = *(const float4*)(xp + 4);
        }
#pragma unroll
        for (int kc = 0; kc < 4; kc++) {
            Frag4 nxt = cur;
            if (kc < 3) nxt = ldfrag4(WB, 36, 4, kc + 1, lane);
            bf16x8 ah, al;
            cvt8v(xa, xb, ah, al);
            if (kc < 3) {
                const float* xp = &X_[r31 * 76 + (kc + 1) * 16 + g * 8];
                xa = *(const float4*)xp; xb = *(const float4*)(xp + 4);
            }
            __builtin_amdgcn_s_setprio(1);
            acc0 = __builtin_amdgcn_mfma_f32_32x32x16_bf16(ah, cur.h0, acc0, 0, 0, 0);
            acc1 = __builtin_amdgcn_mfma_f32_32x32x16_bf16(ah, cur.h1, acc1, 0, 0, 0);
            acc0 = __builtin_amdgcn_mfma_f32_32x32x16_bf16(al, cur.h0, acc0, 0, 0, 0);
            acc1 = __builtin_amdgcn_mfma_f32_32x32x16_bf16(al, cur.h1, acc1, 0, 0, 0);
            acc0 = __builtin_amdgcn_mfma_f32_32x32x16_bf16(ah, cur.l0, acc0, 0, 0, 0);
            acc1 = __builtin_amdgcn_mfma_f32_32x32x16_bf16(ah, cur.l1, acc1, 0, 0, 0);
            __builtin_amdgcn_s_setprio(0);
            cur = nxt;
        }
    }
    // ---------- weighted aggregation over edges (rows) + output
    float wtv[16];
#pragma unroll
    for (int reg = 0; reg < 16; reg++)
        wtv[reg] = __shfl(wt, (reg & 3) + 8 * (reg >> 2) + 4 * g, 64);
    float s00 = 0.f, s01 = 0.f, s10 = 0.f, s11 = 0.f;   // s<query><ntile>
#pragma unroll
    for (int reg = 0; reg < 16; reg++) {
        if (reg < 8) { s00 = fmaf(wtv[reg], acc0[reg], s00); s01 = fmaf(wtv[reg], acc1[reg], s01); }
        else         { s10 = fmaf(wtv[reg], acc0[reg], s10); s11 = fmaf(wtv[reg], acc1[reg], s11); }
    }
    s00 += __shfl_xor(s00, 32, 64);
    s01 += __shfl_xor(s01, 32, 64);
    s10 += __shfl_xor(s10, 32, 64);
    s11 += __shfl_xor(s11, 32, 64);
    float sw0 = __shfl(swt, 0, 64), sw1 = __shfl(swt, 16, 64);
    if (g == 0) {
        float i0 = 1.0f / fmaxf(sw0, 1e-6f), i1 = 1.0f / fmaxf(sw1, 1e-6f);
        int gq0 = qbase, gq1 = qbase + 1;
        if (MODE == 0) {
            int b0 = gq0 / Nq, p0 = gq0 - b0 * Nq;
            int b1i = gq1 / Nq, p1 = gq1 - b1i * Nq;
            outb[((long)b0 * 64 + r31) * 4096 + p0]        = s00 * i0;   // transposed (b, col, p)
            outb[((long)b0 * 64 + 32 + r31) * 4096 + p0]   = s01 * i0;
            outb[((long)b1i * 64 + r31) * 4096 + p1]       = s10 * i1;
            outb[((long)b1i * 64 + 32 + r31) * 4096 + p1]  = s11 * i1;
        } else {
            outb[(long)gq0 * 64 + r31]      = s00 * i0;
            outb[(long)gq0 * 64 + 32 + r31] = s01 * i0;
            outb[(long)gq1 * 64 + r31]      = s10 * i1;
            outb[(long)gq1 * 64 + 32 + r31] = s11 * i1;
        }
    }
}

// ---------------------------------------------------------------- transpose (B,R,C) -> (B,C,R)
__global__ void k_transp(const float* __restrict__ src, float* __restrict__ dst, int R, int C) {
    __shared__ float t[32][33];
    int b = blockIdx.z;
    int c0 = blockIdx.x * 32, r0 = blockIdx.y * 32;
    int tx = threadIdx.x, ty0 = threadIdx.y;    // (32,8)
    for (int yy = ty0; yy < 32; yy += 8) {
        int r = r0 + yy, c = c0 + tx;
        if (r < R && c < C) t[yy][tx] = src[((long)b * R + r) * C + c];
    }
    __syncthreads();
    for (int yy = ty0; yy < 32; yy += 8) {
        int c = c0 + yy, r = r0 + tx;
        if (r < R && c < C) dst[((long)b * C + c) * R + r] = t[tx][yy];
    }
}

// ---------------------------------------------------------------- FNO: truncated forward DFT
__global__ void __launch_bounds__(1024) k_f1(const float* __restrict__ x, float* __restrict__ Xh) {
    int blk = blockIdx.x;    // b*64 + ch
    int tid = threadIdx.x;   // 1024
    __shared__ __align__(16) float img[4096];
    __shared__ float Tre[64][12], Tim[64][12];
    __shared__ float cs[64], sn[64];
    if (tid < 64) {
        double a = (2.0 * PI_ / 64.0) * (double)tid;
        cs[tid] = (float)cos(a);
        sn[tid] = (float)sin(a);
    }
    ((float4*)img)[tid] = ((const float4*)(x + (long)blk * 4096))[tid];
    __syncthreads();
    if (tid < 768) {                             // (h, c)
        int h = tid / 12, c = tid - 12 * h;
        float re = 0.f, im = 0.f;
        for (int w = 0; w < 64; w++) {
            float v = img[h * 64 + w];
            int k = (c * w) & 63;
            re = fmaf(v, cs[k], re);
            im = fmaf(-v, sn[k], im);
        }
        Tre[h][c] = re; Tim[h][c] = im;
    }
    __syncthreads();
    if (tid < 288) {                             // (x24, c12)
        int xx = tid / 12, c = tid - 12 * xx;
        int r = (xx < 12) ? xx : (xx + 40);
        float re = 0.f, im = 0.f;
        for (int h = 0; h < 64; h++) {
            int k = (r * h) & 63;
            float cr = cs[k], si = sn[k];
            float a = Tre[h][c], bb = Tim[h][c];
            re += a * cr + bb * si;
            im += bb * cr - a * si;
        }
        Xh[((long)blk * 288 + tid) * 2] = re;
        Xh[((long)blk * 288 + tid) * 2 + 1] = im;
    }
}

// mode-mix: Yhat[b,o,m] = sum_i Wc[i,o,m] * Xhat[b,i,m]
__global__ void __launch_bounds__(256) k_f2(const float* __restrict__ Xh, const float* __restrict__ s1,
                                            const float* __restrict__ s2, float* __restrict__ Yh) {
    int m = blockIdx.x;                  // 0..287
    int xx = m / 12, y = m - 12 * xx;
    const float* W; int xw;
    if (xx < 12) { W = s1; xw = xx; } else { W = s2; xw = xx - 12; }
    __shared__ float xr[128], xi[128];
    __shared__ float pr[256], pi[256];
    int tid = threadIdx.x;               // 256
    if (tid < 128) {
        int bb = tid >> 6, i = tid & 63;
        xr[tid] = Xh[(((long)bb * 64 + i) * 288 + m) * 2];
        xi[tid] = Xh[(((long)bb * 64 + i) * 288 + m) * 2 + 1];
    }
    __syncthreads();
    int half = tid >> 7;
    int t2 = tid & 127;
    int bb = t2 >> 6, o = t2 & 63;
    float re = 0.f, im = 0.f;
    for (int i = half * 32; i < half * 32 + 32; i++) {
        long wb = (long)i * 18432 + (long)o * 288 + xw * 24 + y * 2;
        float wr = W[wb], wi = W[wb + 1];
        float a = xr[bb * 64 + i], cc = xi[bb * 64 + i];
        re += a * wr - cc * wi;
        im += a * wi + cc * wr;
    }
    pr[tid] = re; pi[tid] = im;
    __syncthreads();
    if (tid < 128) {
        float re2 = pr[tid] + pr[tid + 128];
        float im2 = pi[tid] + pi[tid + 128];
        Yh[(((long)bb * 64 + o) * 288 + m) * 2] = re2;
        Yh[(((long)bb * 64 + o) * 288 + m) * 2 + 1] = im2;
    }
}

// inverse DFT + pointwise conv + bias + InstanceNorm + GELU, fused per (b, out-channel)
__global__ void __launch_bounds__(1024) k_f3(const float* __restrict__ Yh, const float* __restrict__ x,
                                             const float* __restrict__ pwW, const float* __restrict__ pwb,
                                             float* __restrict__ xo) {
    int blk = blockIdx.x;
    int b = blk >> 6, o = blk & 63;
    int tid = threadIdx.x;   // 1024; each thread owns 4 consecutive pixels
    __shared__ float yre[288], yim[288];
    __shared__ float Qre[64][12], Qim[64][12];
    __shared__ float cs[64], sn[64];
    __shared__ float red[1024];
    if (tid < 64) {
        double a = (2.0 * PI_ / 64.0) * (double)tid;
        cs[tid] = (float)cos(a);
        sn[tid] = (float)sin(a);
    }
    if (tid < 288) {
        yre[tid] = Yh[((long)blk * 288 + tid) * 2];
        yim[tid] = Yh[((long)blk * 288 + tid) * 2 + 1];
    }
    __syncthreads();
    if (tid < 768) {    // (h, c): complex ifft along rows (1/64 scale)
        int h = tid / 12, c = tid - 12 * h;
        float re = 0.f, im = 0.f;
#pragma unroll
        for (int xx = 0; xx < 24; xx++) {
            int r = (xx < 12) ? xx : (xx + 40);
            int k = (r * h) & 63;
            float wr = cs[k], wi = sn[k];
            float a = yre[xx * 12 + c], bb = yim[xx * 12 + c];
            re += a * wr - bb * wi;
            im += a * wi + bb * wr;
        }
        Qre[h][c] = re * (1.0f / 64.0f);
        Qim[h][c] = im * (1.0f / 64.0f);
    }
    __syncthreads();
    float bias = pwb[o];
    int h = tid >> 4;
    int w0 = (tid & 15) * 4;
    float sp0, sp1, sp2, sp3;
    {
        float base = Qre[h][0];
        sp0 = sp1 = sp2 = sp3 = base;
#pragma unroll
        for (int c = 1; c < 12; c++) {
            float qr = Qre[h][c], qi = Qim[h][c];
            int k0 = (c * w0) & 63, k1 = (c * (w0 + 1)) & 63;
            int k2 = (c * (w0 + 2)) & 63, k3 = (c * (w0 + 3)) & 63;
            sp0 += 2.0f * (qr * cs[k0] - qi * sn[k0]);
            sp1 += 2.0f * (qr * cs[k1] - qi * sn[k1]);
            sp2 += 2.0f * (qr * cs[k2] - qi * sn[k2]);
            sp3 += 2.0f * (qr * cs[k3] - qi * sn[k3]);
        }
    }
    float a0 = sp0 * (1.0f / 64.0f) + bias;
    float a1 = sp1 * (1.0f / 64.0f) + bias;
    float a2 = sp2 * (1.0f / 64.0f) + bias;
    float a3 = sp3 * (1.0f / 64.0f) + bias;
    const float* xb = x + ((long)b * 64) * 4096 + tid * 4;
    for (int i = 0; i < 64; i++) {
        float wv = pwW[o * 64 + i];
        const float4 xv = *(const float4*)(xb + (long)i * 4096);
        a0 = fmaf(xv.x, wv, a0);
        a1 = fmaf(xv.y, wv, a1);
        a2 = fmaf(xv.z, wv, a2);
        a3 = fmaf(xv.w, wv, a3);
    }
    red[tid] = a0 + a1 + a2 + a3;
    __syncthreads();
    for (int d = 512; d > 0; d >>= 1) { if (tid < d) red[tid] += red[tid + d]; __syncthreads(); }
    float mu = red[0] * (1.0f / 4096.0f);
    __syncthreads();
    float d0 = a0 - mu, d1 = a1 - mu, d2 = a2 - mu, d3 = a3 - mu;
    red[tid] = d0 * d0 + d1 * d1 + d2 * d2 + d3 * d3;
    __syncthreads();
    for (int d = 512; d > 0; d >>= 1) { if (tid < d) red[tid] += red[tid + d]; __syncthreads(); }
    float var = red[0] * (1.0f / 4096.0f);
    float inv = 1.0f / sqrtf(var + 1e-5f);
    float4 ov = make_float4(gelu_f(d0 * inv), gelu_f(d1 * inv), gelu_f(d2 * inv), gelu_f(d3 * inv));
    *(float4*)&xo[(long)blk * 4096 + tid * 4] = ov;
}

// ---------------------------------------------------------------- projection MLP (64 -> 64 -> 3)
__global__ void __launch_bounds__(256) k_proj(
    const float* __restrict__ y, const float* __restrict__ W1, const float* __restrict__ b1,
    const float* __restrict__ W2, const float* __restrict__ b2, float* __restrict__ out) {
    __shared__ __align__(16) float yr[4][64];
    __shared__ float h[4][64];
    int ql = threadIdx.x >> 6, j = threadIdx.x & 63;
    long node = (long)blockIdx.x * 4 + ql;
    yr[ql][j] = y[node * 64 + j];
    __syncthreads();
    float a = b1[j];
    for (int k = 0; k < 64; k += 4) {
        float w0 = W1[(k + 0) * 64 + j], w1 = W1[(k + 1) * 64 + j];
        float w2 = W1[(k + 2) * 64 + j], w3 = W1[(k + 3) * 64 + j];
        const float4 hv = *(const float4*)&yr[ql][k];
        a = fmaf(hv.x, w0, fmaf(hv.y, w1, fmaf(hv.z, w2, fmaf(hv.w, w3, a))));
    }
    h[ql][j] = gelu_f(a);
    __syncthreads();
    if (j < 3) {
        float a2 = b2[j];
        for (int k = 0; k < 64; k++) a2 = fmaf(h[ql][k], W2[k * 3 + j], a2);
        out[node * 3 + j] = a2;
    }
}

// ---------------------------------------------------------------- launch
extern "C" void kernel_launch(void* const* d_in, const int* in_sizes, int n_in,
                              void* d_out, int out_size, void* d_ws, size_t ws_size,
                              hipStream_t stream) {
    (void)in_sizes; (void)n_in; (void)out_size; (void)ws_size;
    const float* coords   = (const float*)d_in[0];
    const float* features = (const float*)d_in[1];
    const float* lift_W1 = (const float*)d_in[2];
    const float* lift_b1 = (const float*)d_in[3];
    const float* lift_W2 = (const float*)d_in[4];
    const float* lift_b2 = (const float*)d_in[5];
    const float* gin_W1 = (const float*)d_in[6];
    const float* gin_b1 = (const float*)d_in[7];
    const float* gin_W2 = (const float*)d_in[8];
    const float* gin_b2 = (const float*)d_in[9];
    const float* gin_W3 = (const float*)d_in[10];
    const float* gin_b3 = (const float*)d_in[11];
    const float* spec1 = (const float*)d_in[12];
    const float* spec2 = (const float*)d_in[13];
    const float* pw_W  = (const float*)d_in[14];
    const float* pw_b  = (const float*)d_in[15];
    const float* gout_W1 = (const float*)d_in[16];
    const float* gout_b1 = (const float*)d_in[17];
    const float* gout_W2 = (const float*)d_in[18];
    const float* gout_b2 = (const float*)d_in[19];
    const float* gout_W3 = (const float*)d_in[20];
    const float* gout_b3 = (const float*)d_in[21];
    const float* proj_W1 = (const float*)d_in[22];
    const float* proj_b1 = (const float*)d_in[23];
    const float* proj_W2 = (const float*)d_in[24];
    const float* proj_b2 = (const float*)d_in[25];

    char* ws = (char*)d_ws;
    size_t off = 0;
    auto alloc = [&](size_t bytes) -> char* {
        char* p = ws + off;
        off = (off + bytes + 255) & ~(size_t)255;
        return p;
    };
    float4* grid_pack = (float4*)alloc((size_t)NG * 16);
    float*  feat      = (float*)alloc((size_t)B_ * N_ * 64 * 4);
    int*    bin_cnt   = (int*)alloc((size_t)B_ * 4096 * 4);
    int*    bin_fill  = (int*)alloc((size_t)B_ * 4096 * 4);
    int*    bin_off   = (int*)alloc((size_t)B_ * 4097 * 4);
    float4* srt       = (float4*)alloc((size_t)B_ * N_ * 16);
    int*    idx_in    = (int*)alloc((size_t)B_ * NG * 16 * 4);
    float*  dist_in   = (float*)alloc((size_t)B_ * NG * 16 * 4);
    float*  lastd_in  = (float*)alloc((size_t)B_ * NG * 4);
    float*  sig_in    = (float*)alloc(256);
    float*  xb0       = (float*)alloc((size_t)B_ * 64 * NG * 4);
    float*  xb1       = (float*)alloc((size_t)B_ * 64 * NG * 4);
    float*  Xh        = (float*)alloc((size_t)B_ * 64 * 288 * 2 * 4);
    float*  Yh        = (float*)alloc((size_t)B_ * 64 * 288 * 2 * 4);
    float*  g2        = (float*)alloc((size_t)B_ * NG * 64 * 4);
    int*    idx_out   = (int*)alloc((size_t)B_ * N_ * 16 * 4);
    float*  dist_out  = (float*)alloc((size_t)B_ * N_ * 16 * 4);
    float*  lastd_out = (float*)alloc((size_t)B_ * N_ * 4);
    float*  sig_out   = (float*)alloc(256);
    float*  ybuf      = (float*)alloc((size_t)B_ * N_ * 64 * 4);
    short*  wb_in     = (short*)alloc((size_t)52 * 1024);   // 52 x 1KB bf16 hi/lo fragments
    short*  wb_out    = (short*)alloc((size_t)52 * 1024);

    hipMemsetAsync(bin_cnt, 0, (size_t)B_ * 4096 * 4, stream);
    hipMemsetAsync(bin_fill, 0, (size_t)B_ * 4096 * 4, stream);

    k_wcvt<<<13, 256, 0, stream>>>(gin_W1, gin_W2, gin_W3, wb_in);
    k_wcvt<<<13, 256, 0, stream>>>(gout_W1, gout_W2, gout_W3, wb_out);
    k_lift<<<(B_ * N_) / 4, 256, 0, stream>>>(features, lift_W1, lift_b1, lift_W2, lift_b2, feat);
    k_bincount<<<(B_ * N_) / 256, 256, 0, stream>>>((const float2*)coords, bin_cnt, grid_pack);
    k_binscan<<<B_, 1024, 0, stream>>>(bin_cnt, bin_off);
    k_binscatter<<<(B_ * N_) / 256, 256, 0, stream>>>((const float2*)coords, bin_off, bin_fill, srt);
    k_knn_in<<<(B_ * NG * 64) / 256, 256, 0, stream>>>(grid_pack, srt, bin_off, idx_in, dist_in, lastd_in);
    k_median_bis<<<1, 1024, 0, stream>>>(lastd_in, B_ * NG, sig_in);
    k_edge_mfma<0><<<(B_ * NG) / 8, 256, 0, stream>>>(idx_in, dist_in, sig_in,
        (const float2*)coords, grid_pack, feat, wb_in,
        gin_b1, gin_b2, gin_b3, xb0, NG, N_);
    float* xc = xb0; float* xn = xb1;
    for (int d = 0; d < 3; d++) {
        k_f1<<<B_ * 64, 1024, 0, stream>>>(xc, Xh);
        k_f2<<<288, 256, 0, stream>>>(Xh, spec1 + (size_t)d * 1179648, spec2 + (size_t)d * 1179648, Yh);
        k_f3<<<B_ * 64, 1024, 0, stream>>>(Yh, xc, pw_W + (size_t)d * 4096, pw_b + (size_t)d * 64, xn);
        float* tmp = xc; xc = xn; xn = tmp;
    }
    {
        dim3 g(NG / 32, 64 / 32, B_); dim3 t(32, 8);
        k_transp<<<g, t, 0, stream>>>(xc, g2, 64, NG);
    }
    k_knn_out<<<(B_ * N_ * 64) / 256, 256, 0, stream>>>((const float2*)coords, grid_pack, idx_out, dist_out, lastd_out);
    k_median_bis<<<1, 1024, 0, stream>>>(lastd_out, B_ * N_, sig_out);
    k_edge_mfma<1><<<(B_ * N_) / 8, 256, 0, stream>>>(idx_out, dist_out, sig_out,
        (const float2*)coords, grid_pack, g2, wb_out,
        gout_b1, gout_b2, gout_b3, ybuf, N_, NG);
    k_proj<<<(B_ * N_) / 4, 256, 0, stream>>>(ybuf, proj_W1, proj_b1, proj_W2, proj_b2, (float*)d_out);
}

// Round 4
// 450.999 us; speedup vs baseline: 1.2226x; 1.0016x over previous
//
#include <hip/hip_runtime.h>
#include <math.h>

#define B_ 2
#define N_ 8192          // points per batch
#define G_ 64
#define NG 4096          // G*G latent grid points
#define WID_ 64
#define K_ 16
#define CIN_ 6
#define COUT_ 3
#define PI_ 3.14159265358979323846

typedef unsigned long long u64k;
typedef __attribute__((ext_vector_type(8))) short bf16x8;   // 8 bf16 bit-patterns (4 VGPR)
typedef __attribute__((ext_vector_type(16))) float f32x16;  // 32x32 MFMA acc

// ---------------------------------------------------------------- helpers
__device__ __forceinline__ float gelu_f(float x) {
    return 0.5f * x * (1.0f + erff(x * 0.70710678118654752440f));
}
__device__ __forceinline__ int cellof(float v) {
    int c = (int)floorf((v + 1.0f) * 32.0f);
    return min(63, max(0, c));
}
__device__ __forceinline__ u64k umin64(u64k a, u64k b) { return a < b ? a : b; }
__device__ __forceinline__ u64k umax64(u64k a, u64k b) { return a < b ? b : a; }
__device__ __forceinline__ u64k shflxor64(u64k v, int m) {
    return (u64k)__shfl_xor((long long)v, m, 64);
}
__device__ __forceinline__ void bsort64(u64k& key, int lane) {
#pragma unroll
    for (int sz = 2; sz <= 64; sz <<= 1) {
#pragma unroll
        for (int j = sz >> 1; j >= 1; j >>= 1) {
            u64k o = shflxor64(key, j);
            bool keep_min = ((lane & j) == 0) == ((lane & sz) == 0);
            key = keep_min ? umin64(key, o) : umax64(key, o);
        }
    }
}
__device__ __forceinline__ void bmerge_into(u64k& R, u64k key, int lane) {
    u64k o = shflxor64(key, 63);
    u64k L = umin64(R, o);
#pragma unroll
    for (int j = 32; j >= 1; j >>= 1) {
        u64k t = shflxor64(L, j);
        L = ((lane & j) == 0) ? umin64(L, t) : umax64(L, t);
    }
    R = L;
}
// split fp32 -> bf16 hi (RNE) + bf16 lo (truncated residual); err ~2^-17 rel
__device__ __forceinline__ void cvt8v(float4 a, float4 b, bf16x8& hv, bf16x8& lv) {
    float v[8] = {a.x, a.y, a.z, a.w, b.x, b.y, b.z, b.w};
#pragma unroll
    for (int i = 0; i < 8; i++) {
        unsigned u = __float_as_uint(v[i]);
        unsigned r = u + 0x7fffu + ((u >> 16) & 1u);
        hv[i] = (short)(r >> 16);
        float lo = v[i] - __uint_as_float(r & 0xffff0000u);
        lv[i] = (short)(__float_as_uint(lo) >> 16);
    }
}
__device__ __forceinline__ bf16x8 ldfrag(const short* __restrict__ WB, int f, int lane) {
    return *(const bf16x8*)(WB + ((long)f * 64 + lane) * 8);
}
struct Frag4 { bf16x8 h0, l0, h1, l1; };
// base/nk select layer: L1 base=0 nk=5, L2 base=20 nk=4, L3 base=36 nk=4
__device__ __forceinline__ Frag4 ldfrag4(const short* __restrict__ WB, int base, int nk,
                                         int kc, int lane) {
    Frag4 f;
    f.h0 = ldfrag(WB, base + (0 * nk + kc) * 2 + 0, lane);
    f.l0 = ldfrag(WB, base + (0 * nk + kc) * 2 + 1, lane);
    f.h1 = ldfrag(WB, base + (1 * nk + kc) * 2 + 0, lane);
    f.l1 = ldfrag(WB, base + (1 * nk + kc) * 2 + 1, lane);
    return f;
}

// ---------------------------------------------------------------- binning (+ grid gen fused)
__global__ void k_bincount(const float2* __restrict__ coords, int* __restrict__ cnt,
                           float4* __restrict__ gp) {
    int t = blockIdx.x * blockDim.x + threadIdx.x;
    if (t < NG) {        // numpy linspace semantics grid gen
        int i = t >> 6, j = t & 63;
        double st = 2.0 / 63.0;
        float gx = (i == 63) ? 1.0f : (float)(-1.0 + st * (double)i);
        float gy = (j == 63) ? 1.0f : (float)(-1.0 + st * (double)j);
        float s2 = __fadd_rn(__fmul_rn(gx, gx), __fmul_rn(gy, gy));
        gp[t] = make_float4(gx, gy, s2, 0.f);
    }
    if (t >= B_ * N_) return;
    float2 c = coords[t];
    int b = t >> 13;
    int cell = cellof(c.x) * 64 + cellof(c.y);
    atomicAdd(&cnt[b * 4096 + cell], 1);
}
__global__ void k_binscan(const int* __restrict__ cnt, int* __restrict__ offs) {
    int b = blockIdx.x, t = threadIdx.x;    // 1024 threads
    __shared__ int s[1024];
    int4 v = ((const int4*)(cnt + b * 4096))[t];
    int sum = v.x + v.y + v.z + v.w;
    s[t] = sum;
    __syncthreads();
    for (int d = 1; d < 1024; d <<= 1) {
        int x = (t >= d) ? s[t - d] : 0;
        __syncthreads();
        s[t] += x;
        __syncthreads();
    }
    int incl = s[t], excl = incl - sum;
    int* ob = offs + b * 4097;
    ob[4 * t] = excl; ob[4 * t + 1] = excl + v.x;
    ob[4 * t + 2] = excl + v.x + v.y; ob[4 * t + 3] = excl + v.x + v.y + v.z;
    if (t == 1023) ob[4096] = incl;
}
__global__ void k_binscatter(const float2* __restrict__ coords, const int* __restrict__ offs,
                             int* __restrict__ fill, float4* __restrict__ srt) {
    int t = blockIdx.x * blockDim.x + threadIdx.x;
    if (t >= B_ * N_) return;
    float2 c = coords[t];
    int b = t >> 13, n = t & 8191;
    int cell = cellof(c.x) * 64 + cellof(c.y);
    int pos = offs[b * 4097 + cell] + atomicAdd(&fill[b * 4096 + cell], 1);
    float s2 = __fadd_rn(__fmul_rn(c.x, c.x), __fmul_rn(c.y, c.y));
    srt[b * N_ + pos] = make_float4(c.x, c.y, s2, __int_as_float(n));
}

// ---------------------------------------------------------------- lift MLP
__global__ void __launch_bounds__(256) k_lift(
    const float* __restrict__ fin, const float* __restrict__ W1,
    const float* __restrict__ b1, const float* __restrict__ W2,
    const float* __restrict__ b2, float* __restrict__ fout) {
    __shared__ float xr[4][8];
    __shared__ __align__(16) float h[4][64];
    int ql = threadIdx.x >> 6, j = threadIdx.x & 63;
    int node = blockIdx.x * 4 + ql;
    if (j < CIN_) xr[ql][j] = fin[node * CIN_ + j];
    __syncthreads();
    float a = b1[j];
#pragma unroll
    for (int i = 0; i < CIN_; i++) a = fmaf(xr[ql][i], W1[i * 64 + j], a);
    h[ql][j] = gelu_f(a);
    __syncthreads();
    float a2 = b2[j];
    for (int k = 0; k < 64; k += 4) {
        float w0 = W2[(k + 0) * 64 + j], w1 = W2[(k + 1) * 64 + j];
        float w2 = W2[(k + 2) * 64 + j], w3 = W2[(k + 3) * 64 + j];
        const float4 hv = *(const float4*)&h[ql][k];
        a2 = fmaf(hv.x, w0, fmaf(hv.y, w1, fmaf(hv.z, w2, fmaf(hv.w, w3, a2))));
    }
    fout[node * 64 + j] = a2;
}

// ---------------------------------------------------------------- kNN grid->points: one wave per query
__global__ void __launch_bounds__(256) k_knn_in(
    const float4* __restrict__ gp, const float4* __restrict__ srt,
    const int* __restrict__ offs, int* __restrict__ oidx,
    float* __restrict__ odist, float* __restrict__ lastd) {
    int lane = threadIdx.x & 63;
    int w = (blockIdx.x * blockDim.x + threadIdx.x) >> 6;
    int b = w >> 12, p = w & 4095;
    float4 q = gp[p];
    float qx = q.x, qy = q.y, q2 = q.z;
    int cqx = cellof(qx), cqy = cellof(qy);
    const float4* S = srt + b * N_;
    const int* OF = offs + b * 4097;

    u64k R = ~0ull;
    u64k pend = ~0ull;
    int fill = 0;

    auto flush = [&]() {
        bsort64(pend, lane);
        bmerge_into(R, pend, lane);
        pend = ~0ull;
        fill = 0;
    };
    auto feed = [&](int s0, int s1) {
        int cnt = s1 - s0;
        while (cnt > 0) {
            int take = min(cnt, 64 - fill);
            int t = lane - fill;
            if (t >= 0 && t < take) {
                float4 sp = S[s0 + t];
                float dot = __fadd_rn(__fmul_rn(qx, sp.x), __fmul_rn(qy, sp.y));
                float d2 = __fsub_rn(__fadd_rn(q2, sp.z), 2.0f * dot);
                d2 = fmaxf(d2, 0.0f);
                pend = ((u64k)__float_as_uint(d2) << 32) | (unsigned)__float_as_int(sp.w);
            }
            fill += take; s0 += take; cnt -= take;
            if (fill == 64) flush();
        }
    };

    {
        int xa = max(cqx - 2, 0), xb = min(cqx + 2, 63);
        int ya = max(cqy - 2, 0), yb = min(cqy + 2, 63);
        for (int cx = xa; cx <= xb; cx++) feed(OF[cx * 64 + ya], OF[cx * 64 + yb + 1]);
    }
    int r = 2;
    while (true) {
        if (fill) flush();
        u64k T = (u64k)__shfl((long long)R, 15, 64);
        float d16 = __uint_as_float((unsigned)(T >> 32));
        float bm = (float)r * 0.03125f;
        if (d16 < bm * bm - 1e-5f) break;
        if (cqx - r <= 0 && cqx + r >= 63 && cqy - r <= 0 && cqy + r >= 63) break;
        r++;
        int ya = max(cqy - r, 0), yb = min(cqy + r, 63);
        if (cqx - r >= 0)  { int c0 = (cqx - r) * 64; feed(OF[c0 + ya], OF[c0 + yb + 1]); }
        if (cqx + r <= 63) { int c0 = (cqx + r) * 64; feed(OF[c0 + ya], OF[c0 + yb + 1]); }
        int xa2 = max(cqx - r + 1, 0), xb2 = min(cqx + r - 1, 63);
        for (int cx = xa2; cx <= xb2; cx++) {
            if (cqy - r >= 0)  { int cc = cx * 64 + cqy - r; feed(OF[cc], OF[cc + 1]); }
            if (cqy + r <= 63) { int cc = cx * 64 + cqy + r; feed(OF[cc], OF[cc + 1]); }
        }
    }
    if (lane < 16) {
        float d2 = __uint_as_float((unsigned)(R >> 32));
        float d = sqrtf(d2);
        oidx[w * 16 + lane] = (int)(unsigned)(R & 0xffffffffu);
        odist[w * 16 + lane] = d;
        if (lane == 15) lastd[w] = d;
    }
}

// ---------------------------------------------------------------- kNN points->grid: one wave per query
__global__ void __launch_bounds__(256) k_knn_out(
    const float2* __restrict__ coords, const float4* __restrict__ gp,
    int* __restrict__ oidx, float* __restrict__ odist, float* __restrict__ lastd) {
    int lane = threadIdx.x & 63;
    int w = (blockIdx.x * blockDim.x + threadIdx.x) >> 6;
    float2 c = coords[w];
    float qx = c.x, qy = c.y;
    float q2 = __fadd_rn(__fmul_rn(qx, qx), __fmul_rn(qy, qy));
    int i0 = (int)floorf((qx + 1.0f) * 31.5f);
    int j0 = (int)floorf((qy + 1.0f) * 31.5f);
    int li = min(max(i0 - 3, 0), 56);
    int lj = min(max(j0 - 3, 0), 56);
    int p = (li + (lane >> 3)) * 64 + (lj + (lane & 7));
    float4 sp = gp[p];
    float dot = __fadd_rn(__fmul_rn(qx, sp.x), __fmul_rn(qy, sp.y));
    float d2 = fmaxf(__fsub_rn(__fadd_rn(q2, sp.z), 2.0f * dot), 0.0f);
    u64k key = ((u64k)__float_as_uint(d2) << 32) | (unsigned)p;
    bsort64(key, lane);
    if (lane < 16) {
        float dd = sqrtf(__uint_as_float((unsigned)(key >> 32)));
        oidx[w * 16 + lane] = (int)(unsigned)(key & 0xffffffffu);
        odist[w * 16 + lane] = dd;
        if (lane == 15) lastd[w] = dd;
    }
}

// ---------------------------------------------------------------- exact lower-median via 32-step bisection
__global__ void __launch_bounds__(1024) k_median_bis(
    const float* __restrict__ vals, int n, float* __restrict__ sig) {
    __shared__ int wred[2][16];
    int tid = threadIdx.x;
    int lane = tid & 63, wv = tid >> 6;
    int cnt_per = n >> 10;           // 8 or 16
    unsigned v[16];
    for (int i = 0; i < cnt_per; i++) v[i] = __float_as_uint(vals[tid + (i << 10)]);
    int r = (n - 1) >> 1;
    unsigned prefix = 0;
    for (int bit = 31; bit >= 0; bit--) {
        unsigned cand = prefix | (1u << bit);
        int c = 0;
        for (int i = 0; i < cnt_per; i++) c += (v[i] < cand) ? 1 : 0;
        for (int o = 32; o >= 1; o >>= 1) c += __shfl_down(c, o, 64);
        int buf = bit & 1;
        if (lane == 0) wred[buf][wv] = c;
        __syncthreads();
        int tot = 0;
#pragma unroll
        for (int k = 0; k < 16; k++) tot += wred[buf][k];
        prefix = (tot <= r) ? cand : prefix;
    }
    if (tid == 0) *sig = fmaxf(__uint_as_float(prefix), 1e-6f);
}

// ---------------------------------------------------------------- weight split/pack for MFMA edge MLP
// WB layout: 52 fragments of 64 lanes x 8 bf16 (1 KB each):
//   W1: f = (nt*5 + kc)*2 + h          (nt<2, kc<5, h: 0=hi 1=lo)   frags 0..19
//   W2: f = 20 + (nt*4 + kc)*2 + h                                  frags 20..35
//   W3: f = 36 + (nt*4 + kc)*2 + h                                  frags 36..51
// B-frag element (lane,i): k = kc*16 + (lane>>5)*8 + i, col = nt*32 + (lane&31).
// W1 row map (x slots): k<7 -> W1[k]; k==7 -> 0 (pad); 8<=k<72 -> W1[k-1]; k>=72 -> 0.
__global__ void k_wcvt(const float* __restrict__ W1s, const float* __restrict__ W2s,
                       const float* __restrict__ W3s, short* __restrict__ WB) {
    int t = blockIdx.x * blockDim.x + threadIdx.x;   // 52*64 = 3328 threads
    if (t >= 3328) return;
    int f = t >> 6, lane = t & 63;
    const float* W; int h, nt, kc, l1 = 0;
    if (f < 20)      { W = W1s; int r = f;      h = r & 1; r >>= 1; nt = r / 5; kc = r % 5; l1 = 1; }
    else if (f < 36) { W = W2s; int r = f - 20; h = r & 1; r >>= 1; nt = r / 4; kc = r % 4; }
    else             { W = W3s; int r = f - 36; h = r & 1; r >>= 1; nt = r / 4; kc = r % 4; }
    int col = nt * 32 + (lane & 31);
    bf16x8 out;
#pragma unroll
    for (int i = 0; i < 8; i++) {
        int k = kc * 16 + (lane >> 5) * 8 + i;
        float w = 0.f;
        if (l1) {
            if (k < 7) w = W[k * 64 + col];
            else if (k >= 8 && k < 72) w = W[(k - 1) * 64 + col];
        } else {
            w = W[k * 64 + col];
        }
        unsigned u = __float_as_uint(w);
        unsigned hi = (u + 0x7fffu + ((u >> 16) & 1u)) & 0xffff0000u;
        float lo = w - __uint_as_float(hi);
        unsigned ul = __float_as_uint(lo);
        unsigned lr = ul + 0x7fffu + ((ul >> 16) & 1u);
        out[i] = h ? (short)(lr >> 16) : (short)(hi >> 16);
    }
    *(bf16x8*)(WB + ((long)f * 64 + lane) * 8) = out;
}

// ---------------------------------------------------------------- edge MLP via split-bf16 MFMA (v4)
// One wave = 2 queries (32 edge rows = M of a 32x32x16 MFMA). N=64 -> 2 tiles.
// 3-term split: D = Ah*Bh + Al*Bh + Ah*Bl (fp32 acc), err ~2^-17 per product.
// v4 vs v3 (43us, MfmaUtil 19%, VALUBusy 60%, Occ 29.6% -- LDS-capped):
//  - 2-wave blocks (128 thr): LDS/block 38912 -> 19456 B => 8 blocks/CU
//    (155.6 KB of 160), occupancy cap 16 waves/CU vs ~9.4 measured at v3.
//    Same per-wave code; launch_bounds(128,4) keeps the 128-VGPR cap.
//  - Nq/srcRows are compile-time (both powers of 2): all magic-divide
//    sequences in staging/gather/epilogue become shifts/masks.
// C/D layout (HW-verified): col = lane&31, row = (reg&3) + 8*(reg>>2) + 4*(lane>>5).
template <int MODE>
__global__ void __launch_bounds__(128, 4) k_edge_mfma(
    const int* __restrict__ idxb, const float* __restrict__ distb,
    const float* __restrict__ sigp,
    const float2* __restrict__ coords, const float4* __restrict__ gp,
    const float* __restrict__ feats, const short* __restrict__ WB,
    const float* __restrict__ b1, const float* __restrict__ b2,
    const float* __restrict__ b3,
    float* __restrict__ outb) {
    constexpr int QSH  = (MODE == 0) ? 12 : 13;     // log2(Nq)
    constexpr int QMSK = (MODE == 0) ? 4095 : 8191;
    constexpr long SR  = (MODE == 0) ? 8192 : 4096; // srcRows
    __shared__ float X[2][2432];           // per wave: 32 rows x 76 floats
    const int tid = threadIdx.x, wv = tid >> 6, lane = tid & 63;
    const int r31 = lane & 31, g = lane >> 5;
    const int qbase = (blockIdx.x * 2 + wv) * 2;
    const float sig = *sigp;
    float* X_ = X[wv];

    // issue first B-fragment load immediately: in flight during staging
    Frag4 cur = ldfrag4(WB, 0, 5, 0, lane);

    // ---- staging: 32 (query,edge) rows by lanes 0..31
    int si = 0; float wt = 0.f;
    if (lane < 32) {
        int q = lane >> 4, e = lane & 15;
        int gq = qbase + q;
        int b = gq >> QSH, p = gq & QMSK;
        si = idxb[gq * 16 + e];
        float d = distb[gq * 16 + e];
        wt = expf(-d / sig);
        float qx, qy, sx, sy;
        if (MODE == 0) {
            float4 gv = gp[p]; qx = gv.x; qy = gv.y;
            float2 cc = coords[(long)b * SR + si]; sx = cc.x; sy = cc.y;
        } else {
            float2 cc = coords[gq]; qx = cc.x; qy = cc.y;   // b*Nq + p == gq
            float4 gv = gp[si]; sx = gv.x; sy = gv.y;
        }
        float* row = X_ + lane * 76;
        *(float4*)row       = make_float4(qx, qy, sx, sy);
        *(float4*)(row + 4) = make_float4(qx - sx, qy - sy, d, 0.f);
    }
    // per-query weight sums (within each 16-lane group)
    float swt = wt;
#pragma unroll
    for (int m = 1; m < 16; m <<= 1) swt += __shfl_xor(swt, m, 64);
    // ---- feats gather: 32 rows x 16 float4; batch loads -> regs, then write
    {
        float4 fv[8];
#pragma unroll
        for (int it = 0; it < 8; it++) {
            int slot = it * 64 + lane;
            int row = slot >> 4, f4 = slot & 15;
            int gq = qbase + (row >> 4);
            int b = gq >> QSH;
            int sr = __shfl(si, row, 64);
            fv[it] = *(const float4*)&feats[((long)b * SR + sr) * 64 + f4 * 4];
        }
#pragma unroll
        for (int it = 0; it < 8; it++) {
            int slot = it * 64 + lane;
            int row = slot >> 4, f4 = slot & 15;
            *(float4*)&X_[row * 76 + 8 + f4 * 4] = fv[it];
        }
    }

    f32x16 acc0, acc1;
    float4 xa, xb;
    // ---------- layer 1: K = 71 (+pad), kc 0..4; kc=4 upper half is A=0
    {
        float bb0 = b1[r31], bb1 = b1[32 + r31];
#pragma unroll
        for (int i = 0; i < 16; i++) { acc0[i] = bb0; acc1[i] = bb1; }
        {
            const float* xp = &X_[r31 * 76 + g * 8];
            xa = *(const float4*)xp; xb = *(const float4*)(xp + 4);
        }
#pragma unroll
        for (int kc = 0; kc < 5; kc++) {
            Frag4 nxt = (kc < 4) ? ldfrag4(WB, 0, 5, kc + 1, lane)
                                 : ldfrag4(WB, 20, 4, 0, lane);   // layer-2 kc0
            bf16x8 ah, al;
            if (kc == 4 && g) {
#pragma unroll
                for (int i = 0; i < 8; i++) { ah[i] = 0; al[i] = 0; }
            } else {
                cvt8v(xa, xb, ah, al);
            }
            // prefetch next-kc A pair (skip kc=3,g=1: that is the zero pad region)
            if (kc < 4 && (kc != 3 || g == 0)) {
                const float* xp = &X_[r31 * 76 + (kc + 1) * 16 + g * 8];
                xa = *(const float4*)xp; xb = *(const float4*)(xp + 4);
            }
            __builtin_amdgcn_s_setprio(1);
            acc0 = __builtin_amdgcn_mfma_f32_32x32x16_bf16(ah, cur.h0, acc0, 0, 0, 0);
            acc1 = __builtin_amdgcn_mfma_f32_32x32x16_bf16(ah, cur.h1, acc1, 0, 0, 0);
            acc0 = __builtin_amdgcn_mfma_f32_32x32x16_bf16(al, cur.h0, acc0, 0, 0, 0);
            acc1 = __builtin_amdgcn_mfma_f32_32x32x16_bf16(al, cur.h1, acc1, 0, 0, 0);
            acc0 = __builtin_amdgcn_mfma_f32_32x32x16_bf16(ah, cur.l0, acc0, 0, 0, 0);
            acc1 = __builtin_amdgcn_mfma_f32_32x32x16_bf16(ah, cur.l1, acc1, 0, 0, 0);
            __builtin_amdgcn_s_setprio(0);
            cur = nxt;
        }
    }
    // h = gelu(acc) -> LDS (overwrites x slots 0..63; all layer-1 reads done)
#pragma unroll
    for (int reg = 0; reg < 16; reg++) {
        int row = (reg & 3) + 8 * (reg >> 2) + 4 * g;
        X_[row * 76 + r31]      = gelu_f(acc0[reg]);
        X_[row * 76 + 32 + r31] = gelu_f(acc1[reg]);
    }
    // ---------- layer 2
    {
        float bb0 = b2[r31], bb1 = b2[32 + r31];
#pragma unroll
        for (int i = 0; i < 16; i++) { acc0[i] = bb0; acc1[i] = bb1; }
        {
            const float* xp = &X_[r31 * 76 + g * 8];
            xa = *(const float4*)xp; xb = *(const float4*)(xp + 4);
        }
#pragma unroll
        for (int kc = 0; kc < 4; kc++) {
            Frag4 nxt = (kc < 3) ? ldfrag4(WB, 20, 4, kc + 1, lane)
                                 : ldfrag4(WB, 36, 4, 0, lane);   // layer-3 kc0
            bf16x8 ah, al;
            cvt8v(xa, xb, ah, al);
            if (kc < 3) {
                const float* xp = &X_[r31 * 76 + (kc + 1) * 16 + g * 8];
                xa = *(const float4*)xp; xb = *(const float4*)(xp + 4);
            }
            __builtin_amdgcn_s_setprio(1);
            acc0 = __builtin_amdgcn_mfma_f32_32x32x16_bf16(ah, cur.h0, acc0, 0, 0, 0);
            acc1 = __builtin_amdgcn_mfma_f32_32x32x16_bf16(ah, cur.h1, acc1, 0, 0, 0);
            acc0 = __builtin_amdgcn_mfma_f32_32x32x16_bf16(al, cur.h0, acc0, 0, 0, 0);
            acc1 = __builtin_amdgcn_mfma_f32_32x32x16_bf16(al, cur.h1, acc1, 0, 0, 0);
            acc0 = __builtin_amdgcn_mfma_f32_32x32x16_bf16(ah, cur.l0, acc0, 0, 0, 0);
            acc1 = __builtin_amdgcn_mfma_f32_32x32x16_bf16(ah, cur.l1, acc1, 0, 0, 0);
            __builtin_amdgcn_s_setprio(0);
            cur = nxt;
        }
    }
#pragma unroll
    for (int reg = 0; reg < 16; reg++) {
        int row = (reg & 3) + 8 * (reg >> 2) + 4 * g;
        X_[row * 76 + r31]      = gelu_f(acc0[reg]);
        X_[row * 76 + 32 + r31] = gelu_f(acc1[reg]);
    }
    // ---------- layer 3 (no activation)
    {
        float bb0 = b3[r31], bb1 = b3[32 + r31];
#pragma unroll
        for (int i = 0; i < 16; i++) { acc0[i] = bb0; acc1[i] = bb1; }
        {
            const float* xp = &X_[r31 * 76 + g * 8];
            xa = *(const float4*)xp; xb = *(const float4*)(xp + 4);
        }
#pragma unroll
        for (int kc = 0; kc < 4; kc++) {
            Frag4 nxt = cur;
            if (kc < 3) nxt = ldfrag4(WB, 36, 4, kc + 1, lane);
            bf16x8 ah, al;
            cvt8v(xa, xb, ah, al);
            if (kc < 3) {
                const float* xp = &X_[r31 * 76 + (kc + 1) * 16 + g * 8];
                xa = *(const float4*)xp; xb = *(const float4*)(xp + 4);
            }
            __builtin_amdgcn_s_setprio(1);
            acc0 = __builtin_amdgcn_mfma_f32_32x32x16_bf16(ah, cur.h0, acc0, 0, 0, 0);
            acc1 = __builtin_amdgcn_mfma_f32_32x32x16_bf16(ah, cur.h1, acc1, 0, 0, 0);
            acc0 = __builtin_amdgcn_mfma_f32_32x32x16_bf16(al, cur.h0, acc0, 0, 0, 0);
            acc1 = __builtin_amdgcn_mfma_f32_32x32x16_bf16(al, cur.h1, acc1, 0, 0, 0);
            acc0 = __builtin_amdgcn_mfma_f32_32x32x16_bf16(ah, cur.l0, acc0, 0, 0, 0);
            acc1 = __builtin_amdgcn_mfma_f32_32x32x16_bf16(ah, cur.l1, acc1, 0, 0, 0);
            __builtin_amdgcn_s_setprio(0);
            cur = nxt;
        }
    }
    // ---------- weighted aggregation over edges (rows) + output
    float wtv[16];
#pragma unroll
    for (int reg = 0; reg < 16; reg++)
        wtv[reg] = __shfl(wt, (reg & 3) + 8 * (reg >> 2) + 4 * g, 64);
    float s00 = 0.f, s01 = 0.f, s10 = 0.f, s11 = 0.f;   // s<query><ntile>
#pragma unroll
    for (int reg = 0; reg < 16; reg++) {
        if (reg < 8) { s00 = fmaf(wtv[reg], acc0[reg], s00); s01 = fmaf(wtv[reg], acc1[reg], s01); }
        else         { s10 = fmaf(wtv[reg], acc0[reg], s10); s11 = fmaf(wtv[reg], acc1[reg], s11); }
    }
    s00 += __shfl_xor(s00, 32, 64);
    s01 += __shfl_xor(s01, 32, 64);
    s10 += __shfl_xor(s10, 32, 64);
    s11 += __shfl_xor(s11, 32, 64);
    float sw0 = __shfl(swt, 0, 64), sw1 = __shfl(swt, 16, 64);
    if (g == 0) {
        float i0 = 1.0f / fmaxf(sw0, 1e-6f), i1 = 1.0f / fmaxf(sw1, 1e-6f);
        int gq0 = qbase, gq1 = qbase + 1;
        if (MODE == 0) {
            int b0 = gq0 >> QSH, p0 = gq0 & QMSK;
            int b1i = gq1 >> QSH, p1 = gq1 & QMSK;
            outb[((long)b0 * 64 + r31) * 4096 + p0]        = s00 * i0;   // transposed (b, col, p)
            outb[((long)b0 * 64 + 32 + r31) * 4096 + p0]   = s01 * i0;
            outb[((long)b1i * 64 + r31) * 4096 + p1]       = s10 * i1;
            outb[((long)b1i * 64 + 32 + r31) * 4096 + p1]  = s11 * i1;
        } else {
            outb[(long)gq0 * 64 + r31]      = s00 * i0;
            outb[(long)gq0 * 64 + 32 + r31] = s01 * i0;
            outb[(long)gq1 * 64 + r31]      = s10 * i1;
            outb[(long)gq1 * 64 + 32 + r31] = s11 * i1;
        }
    }
}

// ---------------------------------------------------------------- transpose (B,R,C) -> (B,C,R)
__global__ void k_transp(const float* __restrict__ src, float* __restrict__ dst, int R, int C) {
    __shared__ float t[32][33];
    int b = blockIdx.z;
    int c0 = blockIdx.x * 32, r0 = blockIdx.y * 32;
    int tx = threadIdx.x, ty0 = threadIdx.y;    // (32,8)
    for (int yy = ty0; yy < 32; yy += 8) {
        int r = r0 + yy, c = c0 + tx;
        if (r < R && c < C) t[yy][tx] = src[((long)b * R + r) * C + c];
    }
    __syncthreads();
    for (int yy = ty0; yy < 32; yy += 8) {
        int c = c0 + yy, r = r0 + tx;
        if (r < R && c < C) dst[((long)b * C + c) * R + r] = t[tx][yy];
    }
}

// ---------------------------------------------------------------- FNO: truncated forward DFT
__global__ void __launch_bounds__(1024) k_f1(const float* __restrict__ x, float* __restrict__ Xh) {
    int blk = blockIdx.x;    // b*64 + ch
    int tid = threadIdx.x;   // 1024
    __shared__ __align__(16) float img[4096];
    __shared__ float Tre[64][12], Tim[64][12];
    __shared__ float cs[64], sn[64];
    if (tid < 64) {
        double a = (2.0 * PI_ / 64.0) * (double)tid;
        cs[tid] = (float)cos(a);
        sn[tid] = (float)sin(a);
    }
    ((float4*)img)[tid] = ((const float4*)(x + (long)blk * 4096))[tid];
    __syncthreads();
    if (tid < 768) {                             // (h, c)
        int h = tid / 12, c = tid - 12 * h;
        float re = 0.f, im = 0.f;
        for (int w = 0; w < 64; w++) {
            float v = img[h * 64 + w];
            int k = (c * w) & 63;
            re = fmaf(v, cs[k], re);
            im = fmaf(-v, sn[k], im);
        }
        Tre[h][c] = re; Tim[h][c] = im;
    }
    __syncthreads();
    if (tid < 288) {                             // (x24, c12)
        int xx = tid / 12, c = tid - 12 * xx;
        int r = (xx < 12) ? xx : (xx + 40);
        float re = 0.f, im = 0.f;
        for (int h = 0; h < 64; h++) {
            int k = (r * h) & 63;
            float cr = cs[k], si = sn[k];
            float a = Tre[h][c], bb = Tim[h][c];
            re += a * cr + bb * si;
            im += bb * cr - a * si;
        }
        Xh[((long)blk * 288 + tid) * 2] = re;
        Xh[((long)blk * 288 + tid) * 2 + 1] = im;
    }
}

// mode-mix: Yhat[b,o,m] = sum_i Wc[i,o,m] * Xhat[b,i,m]
__global__ void __launch_bounds__(256) k_f2(const float* __restrict__ Xh, const float* __restrict__ s1,
                                            const float* __restrict__ s2, float* __restrict__ Yh) {
    int m = blockIdx.x;                  // 0..287
    int xx = m / 12, y = m - 12 * xx;
    const float* W; int xw;
    if (xx < 12) { W = s1; xw = xx; } else { W = s2; xw = xx - 12; }
    __shared__ float xr[128], xi[128];
    __shared__ float pr[256], pi[256];
    int tid = threadIdx.x;               // 256
    if (tid < 128) {
        int bb = tid >> 6, i = tid & 63;
        xr[tid] = Xh[(((long)bb * 64 + i) * 288 + m) * 2];
        xi[tid] = Xh[(((long)bb * 64 + i) * 288 + m) * 2 + 1];
    }
    __syncthreads();
    int half = tid >> 7;
    int t2 = tid & 127;
    int bb = t2 >> 6, o = t2 & 63;
    float re = 0.f, im = 0.f;
    for (int i = half * 32; i < half * 32 + 32; i++) {
        long wb = (long)i * 18432 + (long)o * 288 + xw * 24 + y * 2;
        float wr = W[wb], wi = W[wb + 1];
        float a = xr[bb * 64 + i], cc = xi[bb * 64 + i];
        re += a * wr - cc * wi;
        im += a * wi + cc * wr;
    }
    pr[tid] = re; pi[tid] = im;
    __syncthreads();
    if (tid < 128) {
        float re2 = pr[tid] + pr[tid + 128];
        float im2 = pi[tid] + pi[tid + 128];
        Yh[(((long)bb * 64 + o) * 288 + m) * 2] = re2;
        Yh[(((long)bb * 64 + o) * 288 + m) * 2 + 1] = im2;
    }
}

// inverse DFT + pointwise conv + bias + InstanceNorm + GELU, fused per (b, out-channel)
__global__ void __launch_bounds__(1024) k_f3(const float* __restrict__ Yh, const float* __restrict__ x,
                                             const float* __restrict__ pwW, const float* __restrict__ pwb,
                                             float* __restrict__ xo) {
    int blk = blockIdx.x;
    int b = blk >> 6, o = blk & 63;
    int tid = threadIdx.x;   // 1024; each thread owns 4 consecutive pixels
    __shared__ float yre[288], yim[288];
    __shared__ float Qre[64][12], Qim[64][12];
    __shared__ float cs[64], sn[64];
    __shared__ float red[16];
    if (tid < 64) {
        double a = (2.0 * PI_ / 64.0) * (double)tid;
        cs[tid] = (float)cos(a);
        sn[tid] = (float)sin(a);
    }
    if (tid < 288) {
        yre[tid] = Yh[((long)blk * 288 + tid) * 2];
        yim[tid] = Yh[((long)blk * 288 + tid) * 2 + 1];
    }
    __syncthreads();
    if (tid < 768) {    // (h, c): complex ifft along rows (1/64 scale)
        int h = tid / 12, c = tid - 12 * h;
        float re = 0.f, im = 0.f;
#pragma unroll
        for (int xx = 0; xx < 24; xx++) {
            int r = (xx < 12) ? xx : (xx + 40);
            int k = (r * h) & 63;
            float wr = cs[k], wi = sn[k];
            float a = yre[xx * 12 + c], bb = yim[xx * 12 + c];
            re += a * wr - bb * wi;
            im += a * wi + bb * wr;
        }
        Qre[h][c] = re * (1.0f / 64.0f);
        Qim[h][c] = im * (1.0f / 64.0f);
    }
    __syncthreads();
    float bias = pwb[o];
    int h = tid >> 4;
    int w0 = (tid & 15) * 4;
    float sp0, sp1, sp2, sp3;
    {
        float base = Qre[h][0];
        sp0 = sp1 = sp2 = sp3 = base;
#pragma unroll
        for (int c = 1; c < 12; c++) {
            float qr = Qre[h][c], qi = Qim[h][c];
            int k0 = (c * w0) & 63, k1 = (c * (w0 + 1)) & 63;
            int k2 = (c * (w0 + 2)) & 63, k3 = (c * (w0 + 3)) & 63;
            sp0 += 2.0f * (qr * cs[k0] - qi * sn[k0]);
            sp1 += 2.0f * (qr * cs[k1] - qi * sn[k1]);
            sp2 += 2.0f * (qr * cs[k2] - qi * sn[k2]);
            sp3 += 2.0f * (qr * cs[k3] - qi * sn[k3]);
        }
    }
    float a0 = sp0 * (1.0f / 64.0f) + bias;
    float a1 = sp1 * (1.0f / 64.0f) + bias;
    float a2 = sp2 * (1.0f / 64.0f) + bias;
    float a3 = sp3 * (1.0f / 64.0f) + bias;
    const float* xb = x + ((long)b * 64) * 4096 + tid * 4;
    for (int i = 0; i < 64; i++) {
        float wv = pwW[o * 64 + i];
        const float4 xv = *(const float4*)(xb + (long)i * 4096);
        a0 = fmaf(xv.x, wv, a0);
        a1 = fmaf(xv.y, wv, a1);
        a2 = fmaf(xv.z, wv, a2);
        a3 = fmaf(xv.w, wv, a3);
    }
    // block reduction: wave shfl-reduce + 16-partial sum (3 barriers vs 20)
    float ssum = a0 + a1 + a2 + a3;
#pragma unroll
    for (int m = 1; m < 64; m <<= 1) ssum += __shfl_xor(ssum, m, 64);
    if ((tid & 63) == 0) red[tid >> 6] = ssum;
    __syncthreads();
    float mu = 0.f;
#pragma unroll
    for (int k = 0; k < 16; k++) mu += red[k];
    mu *= (1.0f / 4096.0f);
    __syncthreads();
    float d0 = a0 - mu, d1 = a1 - mu, d2 = a2 - mu, d3 = a3 - mu;
    float sq = d0 * d0 + d1 * d1 + d2 * d2 + d3 * d3;
#pragma unroll
    for (int m = 1; m < 64; m <<= 1) sq += __shfl_xor(sq, m, 64);
    if ((tid & 63) == 0) red[tid >> 6] = sq;
    __syncthreads();
    float var = 0.f;
#pragma unroll
    for (int k = 0; k < 16; k++) var += red[k];
    var *= (1.0f / 4096.0f);
    float inv = 1.0f / sqrtf(var + 1e-5f);
    float4 ov = make_float4(gelu_f(d0 * inv), gelu_f(d1 * inv), gelu_f(d2 * inv), gelu_f(d3 * inv));
    *(float4*)&xo[(long)blk * 4096 + tid * 4] = ov;
}

// ---------------------------------------------------------------- projection MLP (64 -> 64 -> 3)
__global__ void __launch_bounds__(256) k_proj(
    const float* __restrict__ y, const float* __restrict__ W1, const float* __restrict__ b1,
    const float* __restrict__ W2, const float* __restrict__ b2, float* __restrict__ out) {
    __shared__ __align__(16) float yr[4][64];
    __shared__ float h[4][64];
    int ql = threadIdx.x >> 6, j = threadIdx.x & 63;
    long node = (long)blockIdx.x * 4 + ql;
    yr[ql][j] = y[node * 64 + j];
    __syncthreads();
    float a = b1[j];
    for (int k = 0; k < 64; k += 4) {
        float w0 = W1[(k + 0) * 64 + j], w1 = W1[(k + 1) * 64 + j];
        float w2 = W1[(k + 2) * 64 + j], w3 = W1[(k + 3) * 64 + j];
        const float4 hv = *(const float4*)&yr[ql][k];
        a = fmaf(hv.x, w0, fmaf(hv.y, w1, fmaf(hv.z, w2, fmaf(hv.w, w3, a))));
    }
    h[ql][j] = gelu_f(a);
    __syncthreads();
    if (j < 3) {
        float a2 = b2[j];
        for (int k = 0; k < 64; k++) a2 = fmaf(h[ql][k], W2[k * 3 + j], a2);
        out[node * 3 + j] = a2;
    }
}

// ---------------------------------------------------------------- launch
extern "C" void kernel_launch(void* const* d_in, const int* in_sizes, int n_in,
                              void* d_out, int out_size, void* d_ws, size_t ws_size,
                              hipStream_t stream) {
    (void)in_sizes; (void)n_in; (void)out_size; (void)ws_size;
    const float* coords   = (const float*)d_in[0];
    const float* features = (const float*)d_in[1];
    const float* lift_W1 = (const float*)d_in[2];
    const float* lift_b1 = (const float*)d_in[3];
    const float* lift_W2 = (const float*)d_in[4];
    const float* lift_b2 = (const float*)d_in[5];
    const float* gin_W1 = (const float*)d_in[6];
    const float* gin_b1 = (const float*)d_in[7];
    const float* gin_W2 = (const float*)d_in[8];
    const float* gin_b2 = (const float*)d_in[9];
    const float* gin_W3 = (const float*)d_in[10];
    const float* gin_b3 = (const float*)d_in[11];
    const float* spec1 = (const float*)d_in[12];
    const float* spec2 = (const float*)d_in[13];
    const float* pw_W  = (const float*)d_in[14];
    const float* pw_b  = (const float*)d_in[15];
    const float* gout_W1 = (const float*)d_in[16];
    const float* gout_b1 = (const float*)d_in[17];
    const float* gout_W2 = (const float*)d_in[18];
    const float* gout_b2 = (const float*)d_in[19];
    const float* gout_W3 = (const float*)d_in[20];
    const float* gout_b3 = (const float*)d_in[21];
    const float* proj_W1 = (const float*)d_in[22];
    const float* proj_b1 = (const float*)d_in[23];
    const float* proj_W2 = (const float*)d_in[24];
    const float* proj_b2 = (const float*)d_in[25];

    char* ws = (char*)d_ws;
    size_t off = 0;
    auto alloc = [&](size_t bytes) -> char* {
        char* p = ws + off;
        off = (off + bytes + 255) & ~(size_t)255;
        return p;
    };
    float4* grid_pack = (float4*)alloc((size_t)NG * 16);
    float*  feat      = (float*)alloc((size_t)B_ * N_ * 64 * 4);
    int*    bin_cnt   = (int*)alloc((size_t)B_ * 4096 * 4);
    int*    bin_fill  = (int*)alloc((size_t)B_ * 4096 * 4);   // contiguous after bin_cnt
    int*    bin_off   = (int*)alloc((size_t)B_ * 4097 * 4);
    float4* srt       = (float4*)alloc((size_t)B_ * N_ * 16);
    int*    idx_in    = (int*)alloc((size_t)B_ * NG * 16 * 4);
    float*  dist_in   = (float*)alloc((size_t)B_ * NG * 16 * 4);
    float*  lastd_in  = (float*)alloc((size_t)B_ * NG * 4);
    float*  sig_in    = (float*)alloc(256);
    float*  xb0       = (float*)alloc((size_t)B_ * 64 * NG * 4);
    float*  xb1       = (float*)alloc((size_t)B_ * 64 * NG * 4);
    float*  Xh        = (float*)alloc((size_t)B_ * 64 * 288 * 2 * 4);
    float*  Yh        = (float*)alloc((size_t)B_ * 64 * 288 * 2 * 4);
    float*  g2        = (float*)alloc((size_t)B_ * NG * 64 * 4);
    int*    idx_out   = (int*)alloc((size_t)B_ * N_ * 16 * 4);
    float*  dist_out  = (float*)alloc((size_t)B_ * N_ * 16 * 4);
    float*  lastd_out = (float*)alloc((size_t)B_ * N_ * 4);
    float*  sig_out   = (float*)alloc(256);
    float*  ybuf      = (float*)alloc((size_t)B_ * N_ * 64 * 4);
    short*  wb_in     = (short*)alloc((size_t)52 * 1024);   // 52 x 1KB bf16 hi/lo fragments
    short*  wb_out    = (short*)alloc((size_t)52 * 1024);

    // bin_cnt and bin_fill are contiguous 256B-aligned blocks: one memset
    hipMemsetAsync(bin_cnt, 0, (size_t)B_ * 4096 * 4 * 2, stream);

    k_wcvt<<<13, 256, 0, stream>>>(gin_W1, gin_W2, gin_W3, wb_in);
    k_wcvt<<<13, 256, 0, stream>>>(gout_W1, gout_W2, gout_W3, wb_out);
    k_lift<<<(B_ * N_) / 4, 256, 0, stream>>>(features, lift_W1, lift_b1, lift_W2, lift_b2, feat);
    k_bincount<<<(B_ * N_) / 256, 256, 0, stream>>>((const float2*)coords, bin_cnt, grid_pack);
    k_binscan<<<B_, 1024, 0, stream>>>(bin_cnt, bin_off);
    k_binscatter<<<(B_ * N_) / 256, 256, 0, stream>>>((const float2*)coords, bin_off, bin_fill, srt);
    k_knn_in<<<(B_ * NG * 64) / 256, 256, 0, stream>>>(grid_pack, srt, bin_off, idx_in, dist_in, lastd_in);
    k_median_bis<<<1, 1024, 0, stream>>>(lastd_in, B_ * NG, sig_in);
    k_edge_mfma<0><<<(B_ * NG) / 4, 128, 0, stream>>>(idx_in, dist_in, sig_in,
        (const float2*)coords, grid_pack, feat, wb_in,
        gin_b1, gin_b2, gin_b3, xb0);
    float* xc = xb0; float* xn = xb1;
    for (int d = 0; d < 3; d++) {
        k_f1<<<B_ * 64, 1024, 0, stream>>>(xc, Xh);
        k_f2<<<288, 256, 0, stream>>>(Xh, spec1 + (size_t)d * 1179648, spec2 + (size_t)d * 1179648, Yh);
        k_f3<<<B_ * 64, 1024, 0, stream>>>(Yh, xc, pw_W + (size_t)d * 4096, pw_b + (size_t)d * 64, xn);
        float* tmp = xc; xc = xn; xn = tmp;
    }
    {
        dim3 g(NG / 32, 64 / 32, B_); dim3 t(32, 8);
        k_transp<<<g, t, 0, stream>>>(xc, g2, 64, NG);
    }
    k_knn_out<<<(B_ * N_ * 64) / 256, 256, 0, stream>>>((const float2*)coords, grid_pack, idx_out, dist_out, lastd_out);
    k_median_bis<<<1, 1024, 0, stream>>>(lastd_out, B_ * N_, sig_out);
    k_edge_mfma<1><<<(B_ * N_) / 4, 128, 0, stream>>>(idx_out, dist_out, sig_out,
        (const float2*)coords, grid_pack, g2, wb_out,
        gout_b1, gout_b2, gout_b3, ybuf);
    k_proj<<<(B_ * N_) / 4, 256, 0, stream>>>(ybuf, proj_W1, proj_b1, proj_W2, proj_b2, (float*)d_out);
}

// Round 5
// 448.274 us; speedup vs baseline: 1.2300x; 1.0061x over previous
//
#include <hip/hip_runtime.h>
#include <math.h>

#define B_ 2
#define N_ 8192          // points per batch
#define G_ 64
#define NG 4096          // G*G latent grid points
#define WID_ 64
#define K_ 16
#define CIN_ 6
#define COUT_ 3
#define PI_ 3.14159265358979323846

typedef unsigned long long u64k;
typedef __attribute__((ext_vector_type(8))) short bf16x8;   // 8 bf16 bit-patterns (4 VGPR)
typedef __attribute__((ext_vector_type(16))) float f32x16;  // 32x32 MFMA acc

// ---------------------------------------------------------------- helpers
// exact-erf GELU via Abramowitz-Stegun 7.1.26 (|eps_erf| <= 1.5e-7), branchless.
// ~16 insts vs library erff's ~25-30 with divergent exp tail.
__device__ __forceinline__ float gelu_f(float x) {
    float u = fabsf(x) * 0.70710678118654752440f;
    float t = __builtin_amdgcn_rcpf(fmaf(0.3275911f, u, 1.0f));
    float p = fmaf(fmaf(fmaf(fmaf(1.061405429f, t, -1.453152027f), t, 1.421413741f),
                        t, -0.284496736f), t, 0.254829592f) * t;
    float e = __expf(-u * u);
    float erfc_u = p * e;                               // erfc(u), u >= 0
    float phi = (x >= 0.f) ? fmaf(-0.5f, erfc_u, 1.0f) : (0.5f * erfc_u);
    return x * phi;
}
__device__ __forceinline__ int cellof(float v) {
    int c = (int)floorf((v + 1.0f) * 32.0f);
    return min(63, max(0, c));
}
__device__ __forceinline__ u64k umin64(u64k a, u64k b) { return a < b ? a : b; }
__device__ __forceinline__ u64k umax64(u64k a, u64k b) { return a < b ? b : a; }
__device__ __forceinline__ u64k shflxor64(u64k v, int m) {
    return (u64k)__shfl_xor((long long)v, m, 64);
}
__device__ __forceinline__ void bsort64(u64k& key, int lane) {
#pragma unroll
    for (int sz = 2; sz <= 64; sz <<= 1) {
#pragma unroll
        for (int j = sz >> 1; j >= 1; j >>= 1) {
            u64k o = shflxor64(key, j);
            bool keep_min = ((lane & j) == 0) == ((lane & sz) == 0);
            key = keep_min ? umin64(key, o) : umax64(key, o);
        }
    }
}
__device__ __forceinline__ void bmerge_into(u64k& R, u64k key, int lane) {
    u64k o = shflxor64(key, 63);
    u64k L = umin64(R, o);
#pragma unroll
    for (int j = 32; j >= 1; j >>= 1) {
        u64k t = shflxor64(L, j);
        L = ((lane & j) == 0) ? umin64(L, t) : umax64(L, t);
    }
    R = L;
}
// split fp32 -> bf16 hi (round-half-up, 0.5-ulp) + bf16 lo (truncated residual)
// same error bound as RNE (ties only); 3 fewer insts/elem than the RNE form.
__device__ __forceinline__ void cvt8v(float4 a, float4 b, bf16x8& hv, bf16x8& lv) {
    float v[8] = {a.x, a.y, a.z, a.w, b.x, b.y, b.z, b.w};
#pragma unroll
    for (int i = 0; i < 8; i++) {
        unsigned u = __float_as_uint(v[i]);
        unsigned r = (u + 0x8000u) & 0xffff0000u;
        hv[i] = (short)(r >> 16);
        float lo = v[i] - __uint_as_float(r);
        lv[i] = (short)(__float_as_uint(lo) >> 16);
    }
}
__device__ __forceinline__ bf16x8 ldfrag(const short* __restrict__ WB, int f, int lane) {
    return *(const bf16x8*)(WB + ((long)f * 64 + lane) * 8);
}
struct Frag4 { bf16x8 h0, l0, h1, l1; };
// base/nk select layer: L1 base=0 nk=5, L2 base=20 nk=4, L3 base=36 nk=4
__device__ __forceinline__ Frag4 ldfrag4(const short* __restrict__ WB, int base, int nk,
                                         int kc, int lane) {
    Frag4 f;
    f.h0 = ldfrag(WB, base + (0 * nk + kc) * 2 + 0, lane);
    f.l0 = ldfrag(WB, base + (0 * nk + kc) * 2 + 1, lane);
    f.h1 = ldfrag(WB, base + (1 * nk + kc) * 2 + 0, lane);
    f.l1 = ldfrag(WB, base + (1 * nk + kc) * 2 + 1, lane);
    return f;
}

// ---------------------------------------------------------------- binning (+ grid gen fused)
__global__ void k_bincount(const float2* __restrict__ coords, int* __restrict__ cnt,
                           float4* __restrict__ gp) {
    int t = blockIdx.x * blockDim.x + threadIdx.x;
    if (t < NG) {        // numpy linspace semantics grid gen
        int i = t >> 6, j = t & 63;
        double st = 2.0 / 63.0;
        float gx = (i == 63) ? 1.0f : (float)(-1.0 + st * (double)i);
        float gy = (j == 63) ? 1.0f : (float)(-1.0 + st * (double)j);
        float s2 = __fadd_rn(__fmul_rn(gx, gx), __fmul_rn(gy, gy));
        gp[t] = make_float4(gx, gy, s2, 0.f);
    }
    if (t >= B_ * N_) return;
    float2 c = coords[t];
    int b = t >> 13;
    int cell = cellof(c.x) * 64 + cellof(c.y);
    atomicAdd(&cnt[b * 4096 + cell], 1);
}
__global__ void k_binscan(const int* __restrict__ cnt, int* __restrict__ offs) {
    int b = blockIdx.x, t = threadIdx.x;    // 1024 threads
    __shared__ int s[1024];
    int4 v = ((const int4*)(cnt + b * 4096))[t];
    int sum = v.x + v.y + v.z + v.w;
    s[t] = sum;
    __syncthreads();
    for (int d = 1; d < 1024; d <<= 1) {
        int x = (t >= d) ? s[t - d] : 0;
        __syncthreads();
        s[t] += x;
        __syncthreads();
    }
    int incl = s[t], excl = incl - sum;
    int* ob = offs + b * 4097;
    ob[4 * t] = excl; ob[4 * t + 1] = excl + v.x;
    ob[4 * t + 2] = excl + v.x + v.y; ob[4 * t + 3] = excl + v.x + v.y + v.z;
    if (t == 1023) ob[4096] = incl;
}
__global__ void k_binscatter(const float2* __restrict__ coords, const int* __restrict__ offs,
                             int* __restrict__ fill, float4* __restrict__ srt) {
    int t = blockIdx.x * blockDim.x + threadIdx.x;
    if (t >= B_ * N_) return;
    float2 c = coords[t];
    int b = t >> 13, n = t & 8191;
    int cell = cellof(c.x) * 64 + cellof(c.y);
    int pos = offs[b * 4097 + cell] + atomicAdd(&fill[b * 4096 + cell], 1);
    float s2 = __fadd_rn(__fmul_rn(c.x, c.x), __fmul_rn(c.y, c.y));
    srt[b * N_ + pos] = make_float4(c.x, c.y, s2, __int_as_float(n));
}

// ---------------------------------------------------------------- lift MLP
__global__ void __launch_bounds__(256) k_lift(
    const float* __restrict__ fin, const float* __restrict__ W1,
    const float* __restrict__ b1, const float* __restrict__ W2,
    const float* __restrict__ b2, float* __restrict__ fout) {
    __shared__ float xr[4][8];
    __shared__ __align__(16) float h[4][64];
    int ql = threadIdx.x >> 6, j = threadIdx.x & 63;
    int node = blockIdx.x * 4 + ql;
    if (j < CIN_) xr[ql][j] = fin[node * CIN_ + j];
    __syncthreads();
    float a = b1[j];
#pragma unroll
    for (int i = 0; i < CIN_; i++) a = fmaf(xr[ql][i], W1[i * 64 + j], a);
    h[ql][j] = gelu_f(a);
    __syncthreads();
    float a2 = b2[j];
    for (int k = 0; k < 64; k += 4) {
        float w0 = W2[(k + 0) * 64 + j], w1 = W2[(k + 1) * 64 + j];
        float w2 = W2[(k + 2) * 64 + j], w3 = W2[(k + 3) * 64 + j];
        const float4 hv = *(const float4*)&h[ql][k];
        a2 = fmaf(hv.x, w0, fmaf(hv.y, w1, fmaf(hv.z, w2, fmaf(hv.w, w3, a2))));
    }
    fout[node * 64 + j] = a2;
}

// ---------------------------------------------------------------- kNN grid->points: one wave per query
__global__ void __launch_bounds__(256) k_knn_in(
    const float4* __restrict__ gp, const float4* __restrict__ srt,
    const int* __restrict__ offs, int* __restrict__ oidx,
    float* __restrict__ odist, float* __restrict__ lastd) {
    int lane = threadIdx.x & 63;
    int w = (blockIdx.x * blockDim.x + threadIdx.x) >> 6;
    int b = w >> 12, p = w & 4095;
    float4 q = gp[p];
    float qx = q.x, qy = q.y, q2 = q.z;
    int cqx = cellof(qx), cqy = cellof(qy);
    const float4* S = srt + b * N_;
    const int* OF = offs + b * 4097;

    u64k R = ~0ull;
    u64k pend = ~0ull;
    int fill = 0;

    auto flush = [&]() {
        bsort64(pend, lane);
        bmerge_into(R, pend, lane);
        pend = ~0ull;
        fill = 0;
    };
    auto feed = [&](int s0, int s1) {
        int cnt = s1 - s0;
        while (cnt > 0) {
            int take = min(cnt, 64 - fill);
            int t = lane - fill;
            if (t >= 0 && t < take) {
                float4 sp = S[s0 + t];
                float dot = __fadd_rn(__fmul_rn(qx, sp.x), __fmul_rn(qy, sp.y));
                float d2 = __fsub_rn(__fadd_rn(q2, sp.z), 2.0f * dot);
                d2 = fmaxf(d2, 0.0f);
                pend = ((u64k)__float_as_uint(d2) << 32) | (unsigned)__float_as_int(sp.w);
            }
            fill += take; s0 += take; cnt -= take;
            if (fill == 64) flush();
        }
    };

    {
        int xa = max(cqx - 2, 0), xb = min(cqx + 2, 63);
        int ya = max(cqy - 2, 0), yb = min(cqy + 2, 63);
        for (int cx = xa; cx <= xb; cx++) feed(OF[cx * 64 + ya], OF[cx * 64 + yb + 1]);
    }
    int r = 2;
    while (true) {
        if (fill) flush();
        u64k T = (u64k)__shfl((long long)R, 15, 64);
        float d16 = __uint_as_float((unsigned)(T >> 32));
        float bm = (float)r * 0.03125f;
        if (d16 < bm * bm - 1e-5f) break;
        if (cqx - r <= 0 && cqx + r >= 63 && cqy - r <= 0 && cqy + r >= 63) break;
        r++;
        int ya = max(cqy - r, 0), yb = min(cqy + r, 63);
        if (cqx - r >= 0)  { int c0 = (cqx - r) * 64; feed(OF[c0 + ya], OF[c0 + yb + 1]); }
        if (cqx + r <= 63) { int c0 = (cqx + r) * 64; feed(OF[c0 + ya], OF[c0 + yb + 1]); }
        int xa2 = max(cqx - r + 1, 0), xb2 = min(cqx + r - 1, 63);
        for (int cx = xa2; cx <= xb2; cx++) {
            if (cqy - r >= 0)  { int cc = cx * 64 + cqy - r; feed(OF[cc], OF[cc + 1]); }
            if (cqy + r <= 63) { int cc = cx * 64 + cqy + r; feed(OF[cc], OF[cc + 1]); }
        }
    }
    if (lane < 16) {
        float d2 = __uint_as_float((unsigned)(R >> 32));
        float d = sqrtf(d2);
        oidx[w * 16 + lane] = (int)(unsigned)(R & 0xffffffffu);
        odist[w * 16 + lane] = d;
        if (lane == 15) lastd[w] = d;
    }
}

// ---------------------------------------------------------------- kNN points->grid: one wave per query
__global__ void __launch_bounds__(256) k_knn_out(
    const float2* __restrict__ coords, const float4* __restrict__ gp,
    int* __restrict__ oidx, float* __restrict__ odist, float* __restrict__ lastd) {
    int lane = threadIdx.x & 63;
    int w = (blockIdx.x * blockDim.x + threadIdx.x) >> 6;
    float2 c = coords[w];
    float qx = c.x, qy = c.y;
    float q2 = __fadd_rn(__fmul_rn(qx, qx), __fmul_rn(qy, qy));
    int i0 = (int)floorf((qx + 1.0f) * 31.5f);
    int j0 = (int)floorf((qy + 1.0f) * 31.5f);
    int li = min(max(i0 - 3, 0), 56);
    int lj = min(max(j0 - 3, 0), 56);
    int p = (li + (lane >> 3)) * 64 + (lj + (lane & 7));
    float4 sp = gp[p];
    float dot = __fadd_rn(__fmul_rn(qx, sp.x), __fmul_rn(qy, sp.y));
    float d2 = fmaxf(__fsub_rn(__fadd_rn(q2, sp.z), 2.0f * dot), 0.0f);
    u64k key = ((u64k)__float_as_uint(d2) << 32) | (unsigned)p;
    bsort64(key, lane);
    if (lane < 16) {
        float dd = sqrtf(__uint_as_float((unsigned)(key >> 32)));
        oidx[w * 16 + lane] = (int)(unsigned)(key & 0xffffffffu);
        odist[w * 16 + lane] = dd;
        if (lane == 15) lastd[w] = dd;
    }
}

// ---------------------------------------------------------------- exact lower-median via 32-step bisection
__global__ void __launch_bounds__(1024) k_median_bis(
    const float* __restrict__ vals, int n, float* __restrict__ sig) {
    __shared__ int wred[2][16];
    int tid = threadIdx.x;
    int lane = tid & 63, wv = tid >> 6;
    int cnt_per = n >> 10;           // 8 or 16
    unsigned v[16];
    for (int i = 0; i < cnt_per; i++) v[i] = __float_as_uint(vals[tid + (i << 10)]);
    int r = (n - 1) >> 1;
    unsigned prefix = 0;
    for (int bit = 31; bit >= 0; bit--) {
        unsigned cand = prefix | (1u << bit);
        int c = 0;
        for (int i = 0; i < cnt_per; i++) c += (v[i] < cand) ? 1 : 0;
        for (int o = 32; o >= 1; o >>= 1) c += __shfl_down(c, o, 64);
        int buf = bit & 1;
        if (lane == 0) wred[buf][wv] = c;
        __syncthreads();
        int tot = 0;
#pragma unroll
        for (int k = 0; k < 16; k++) tot += wred[buf][k];
        prefix = (tot <= r) ? cand : prefix;
    }
    if (tid == 0) *sig = fmaxf(__uint_as_float(prefix), 1e-6f);
}

// ---------------------------------------------------------------- weight split/pack for MFMA edge MLP
// Both weight sets (gin, gout) in ONE launch: t < 3328 -> set A, else set B.
// WB layout: 52 fragments of 64 lanes x 8 bf16 (1 KB each):
//   W1: f = (nt*5 + kc)*2 + h          (nt<2, kc<5, h: 0=hi 1=lo)   frags 0..19
//   W2: f = 20 + (nt*4 + kc)*2 + h                                  frags 20..35
//   W3: f = 36 + (nt*4 + kc)*2 + h                                  frags 36..51
// B-frag element (lane,i): k = kc*16 + (lane>>5)*8 + i, col = nt*32 + (lane&31).
// W1 row map (x slots): k<7 -> W1[k]; k==7 -> 0 (pad); 8<=k<72 -> W1[k-1]; k>=72 -> 0.
__global__ void k_wcvt(const float* __restrict__ W1a, const float* __restrict__ W2a,
                       const float* __restrict__ W3a, short* __restrict__ WBa,
                       const float* __restrict__ W1b, const float* __restrict__ W2b,
                       const float* __restrict__ W3b, short* __restrict__ WBb) {
    int t = blockIdx.x * blockDim.x + threadIdx.x;   // 2 * 52*64 = 6656 threads
    if (t >= 6656) return;
    int setb = (t >= 3328);
    int tt = t - (setb ? 3328 : 0);
    const float* W1s = setb ? W1b : W1a;
    const float* W2s = setb ? W2b : W2a;
    const float* W3s = setb ? W3b : W3a;
    short* WB = setb ? WBb : WBa;
    int f = tt >> 6, lane = tt & 63;
    const float* W; int h, nt, kc, l1 = 0;
    if (f < 20)      { W = W1s; int r = f;      h = r & 1; r >>= 1; nt = r / 5; kc = r % 5; l1 = 1; }
    else if (f < 36) { W = W2s; int r = f - 20; h = r & 1; r >>= 1; nt = r / 4; kc = r % 4; }
    else             { W = W3s; int r = f - 36; h = r & 1; r >>= 1; nt = r / 4; kc = r % 4; }
    int col = nt * 32 + (lane & 31);
    bf16x8 out;
#pragma unroll
    for (int i = 0; i < 8; i++) {
        int k = kc * 16 + (lane >> 5) * 8 + i;
        float w = 0.f;
        if (l1) {
            if (k < 7) w = W[k * 64 + col];
            else if (k >= 8 && k < 72) w = W[(k - 1) * 64 + col];
        } else {
            w = W[k * 64 + col];
        }
        unsigned u = __float_as_uint(w);
        unsigned hi = (u + 0x7fffu + ((u >> 16) & 1u)) & 0xffff0000u;
        float lo = w - __uint_as_float(hi);
        unsigned ul = __float_as_uint(lo);
        unsigned lr = ul + 0x7fffu + ((ul >> 16) & 1u);
        out[i] = h ? (short)(lr >> 16) : (short)(hi >> 16);
    }
    *(bf16x8*)(WB + ((long)f * 64 + lane) * 8) = out;
}

// ---------------------------------------------------------------- edge MLP via split-bf16 MFMA (v5)
// One wave = 2 queries (32 edge rows = M of a 32x32x16 MFMA). N=64 -> 2 tiles.
// 3-term split: D = Ah*Bh + Al*Bh + Ah*Bl (fp32 acc), err ~2^-17 per product.
// v5 vs v4 (43.9us, MfmaUtil 18%, VALUBusy 55%, Occ 29%):
//  - v4 lesson: occupancy is VGPR-capped at 4 waves/SIMD in BOTH v3/v4 (LDS
//    was never the binder); measured 29% is time-averaged skew. Attack VALU
//    WORK instead: A&S-7.1.26 branchless gelu (~16 insts vs erff ~25-30) and
//    cheaper bf16-split rounding (half-up, 3 fewer insts/elem).
// C/D layout (HW-verified): col = lane&31, row = (reg&3) + 8*(reg>>2) + 4*(lane>>5).
template <int MODE>
__global__ void __launch_bounds__(128, 4) k_edge_mfma(
    const int* __restrict__ idxb, const float* __restrict__ distb,
    const float* __restrict__ sigp,
    const float2* __restrict__ coords, const float4* __restrict__ gp,
    const float* __restrict__ feats, const short* __restrict__ WB,
    const float* __restrict__ b1, const float* __restrict__ b2,
    const float* __restrict__ b3,
    float* __restrict__ outb) {
    constexpr int QSH  = (MODE == 0) ? 12 : 13;     // log2(Nq)
    constexpr int QMSK = (MODE == 0) ? 4095 : 8191;
    constexpr long SR  = (MODE == 0) ? 8192 : 4096; // srcRows
    __shared__ float X[2][2432];           // per wave: 32 rows x 76 floats
    const int tid = threadIdx.x, wv = tid >> 6, lane = tid & 63;
    const int r31 = lane & 31, g = lane >> 5;
    const int qbase = (blockIdx.x * 2 + wv) * 2;
    const float sig = *sigp;
    float* X_ = X[wv];

    // issue first B-fragment load immediately: in flight during staging
    Frag4 cur = ldfrag4(WB, 0, 5, 0, lane);

    // ---- staging: 32 (query,edge) rows by lanes 0..31
    int si = 0; float wt = 0.f;
    if (lane < 32) {
        int q = lane >> 4, e = lane & 15;
        int gq = qbase + q;
        int b = gq >> QSH, p = gq & QMSK;
        si = idxb[gq * 16 + e];
        float d = distb[gq * 16 + e];
        wt = __expf(-d / sig);
        float qx, qy, sx, sy;
        if (MODE == 0) {
            float4 gv = gp[p]; qx = gv.x; qy = gv.y;
            float2 cc = coords[(long)b * SR + si]; sx = cc.x; sy = cc.y;
        } else {
            float2 cc = coords[gq]; qx = cc.x; qy = cc.y;   // b*Nq + p == gq
            float4 gv = gp[si]; sx = gv.x; sy = gv.y;
        }
        float* row = X_ + lane * 76;
        *(float4*)row       = make_float4(qx, qy, sx, sy);
        *(float4*)(row + 4) = make_float4(qx - sx, qy - sy, d, 0.f);
    }
    // per-query weight sums (within each 16-lane group)
    float swt = wt;
#pragma unroll
    for (int m = 1; m < 16; m <<= 1) swt += __shfl_xor(swt, m, 64);
    // ---- feats gather: 32 rows x 16 float4; batch loads -> regs, then write
    {
        float4 fv[8];
#pragma unroll
        for (int it = 0; it < 8; it++) {
            int slot = it * 64 + lane;
            int row = slot >> 4, f4 = slot & 15;
            int gq = qbase + (row >> 4);
            int b = gq >> QSH;
            int sr = __shfl(si, row, 64);
            fv[it] = *(const float4*)&feats[((long)b * SR + sr) * 64 + f4 * 4];
        }
#pragma unroll
        for (int it = 0; it < 8; it++) {
            int slot = it * 64 + lane;
            int row = slot >> 4, f4 = slot & 15;
            *(float4*)&X_[row * 76 + 8 + f4 * 4] = fv[it];
        }
    }

    f32x16 acc0, acc1;
    float4 xa, xb;
    // ---------- layer 1: K = 71 (+pad), kc 0..4; kc=4 upper half is A=0
    {
        float bb0 = b1[r31], bb1 = b1[32 + r31];
#pragma unroll
        for (int i = 0; i < 16; i++) { acc0[i] = bb0; acc1[i] = bb1; }
        {
            const float* xp = &X_[r31 * 76 + g * 8];
            xa = *(const float4*)xp; xb = *(const float4*)(xp + 4);
        }
#pragma unroll
        for (int kc = 0; kc < 5; kc++) {
            Frag4 nxt = (kc < 4) ? ldfrag4(WB, 0, 5, kc + 1, lane)
                                 : ldfrag4(WB, 20, 4, 0, lane);   // layer-2 kc0
            bf16x8 ah, al;
            if (kc == 4 && g) {
#pragma unroll
                for (int i = 0; i < 8; i++) { ah[i] = 0; al[i] = 0; }
            } else {
                cvt8v(xa, xb, ah, al);
            }
            // prefetch next-kc A pair (skip kc=3,g=1: that is the zero pad region)
            if (kc < 4 && (kc != 3 || g == 0)) {
                const float* xp = &X_[r31 * 76 + (kc + 1) * 16 + g * 8];
                xa = *(const float4*)xp; xb = *(const float4*)(xp + 4);
            }
            __builtin_amdgcn_s_setprio(1);
            acc0 = __builtin_amdgcn_mfma_f32_32x32x16_bf16(ah, cur.h0, acc0, 0, 0, 0);
            acc1 = __builtin_amdgcn_mfma_f32_32x32x16_bf16(ah, cur.h1, acc1, 0, 0, 0);
            acc0 = __builtin_amdgcn_mfma_f32_32x32x16_bf16(al, cur.h0, acc0, 0, 0, 0);
            acc1 = __builtin_amdgcn_mfma_f32_32x32x16_bf16(al, cur.h1, acc1, 0, 0, 0);
            acc0 = __builtin_amdgcn_mfma_f32_32x32x16_bf16(ah, cur.l0, acc0, 0, 0, 0);
            acc1 = __builtin_amdgcn_mfma_f32_32x32x16_bf16(ah, cur.l1, acc1, 0, 0, 0);
            __builtin_amdgcn_s_setprio(0);
            cur = nxt;
        }
    }
    // h = gelu(acc) -> LDS (overwrites x slots 0..63; all layer-1 reads done)
#pragma unroll
    for (int reg = 0; reg < 16; reg++) {
        int row = (reg & 3) + 8 * (reg >> 2) + 4 * g;
        X_[row * 76 + r31]      = gelu_f(acc0[reg]);
        X_[row * 76 + 32 + r31] = gelu_f(acc1[reg]);
    }
    // ---------- layer 2
    {
        float bb0 = b2[r31], bb1 = b2[32 + r31];
#pragma unroll
        for (int i = 0; i < 16; i++) { acc0[i] = bb0; acc1[i] = bb1; }
        {
            const float* xp = &X_[r31 * 76 + g * 8];
            xa = *(const float4*)xp; xb = *(const float4*)(xp + 4);
        }
#pragma unroll
        for (int kc = 0; kc < 4; kc++) {
            Frag4 nxt = (kc < 3) ? ldfrag4(WB, 20, 4, kc + 1, lane)
                                 : ldfrag4(WB, 36, 4, 0, lane);   // layer-3 kc0
            bf16x8 ah, al;
            cvt8v(xa, xb, ah, al);
            if (kc < 3) {
                const float* xp = &X_[r31 * 76 + (kc + 1) * 16 + g * 8];
                xa = *(const float4*)xp; xb = *(const float4*)(xp + 4);
            }
            __builtin_amdgcn_s_setprio(1);
            acc0 = __builtin_amdgcn_mfma_f32_32x32x16_bf16(ah, cur.h0, acc0, 0, 0, 0);
            acc1 = __builtin_amdgcn_mfma_f32_32x32x16_bf16(ah, cur.h1, acc1, 0, 0, 0);
            acc0 = __builtin_amdgcn_mfma_f32_32x32x16_bf16(al, cur.h0, acc0, 0, 0, 0);
            acc1 = __builtin_amdgcn_mfma_f32_32x32x16_bf16(al, cur.h1, acc1, 0, 0, 0);
            acc0 = __builtin_amdgcn_mfma_f32_32x32x16_bf16(ah, cur.l0, acc0, 0, 0, 0);
            acc1 = __builtin_amdgcn_mfma_f32_32x32x16_bf16(ah, cur.l1, acc1, 0, 0, 0);
            __builtin_amdgcn_s_setprio(0);
            cur = nxt;
        }
    }
#pragma unroll
    for (int reg = 0; reg < 16; reg++) {
        int row = (reg & 3) + 8 * (reg >> 2) + 4 * g;
        X_[row * 76 + r31]      = gelu_f(acc0[reg]);
        X_[row * 76 + 32 + r31] = gelu_f(acc1[reg]);
    }
    // ---------- layer 3 (no activation)
    {
        float bb0 = b3[r31], bb1 = b3[32 + r31];
#pragma unroll
        for (int i = 0; i < 16; i++) { acc0[i] = bb0; acc1[i] = bb1; }
        {
            const float* xp = &X_[r31 * 76 + g * 8];
            xa = *(const float4*)xp; xb = *(const float4*)(xp + 4);
        }
#pragma unroll
        for (int kc = 0; kc < 4; kc++) {
            Frag4 nxt = cur;
            if (kc < 3) nxt = ldfrag4(WB, 36, 4, kc + 1, lane);
            bf16x8 ah, al;
            cvt8v(xa, xb, ah, al);
            if (kc < 3) {
                const float* xp = &X_[r31 * 76 + (kc + 1) * 16 + g * 8];
                xa = *(const float4*)xp; xb = *(const float4*)(xp + 4);
            }
            __builtin_amdgcn_s_setprio(1);
            acc0 = __builtin_amdgcn_mfma_f32_32x32x16_bf16(ah, cur.h0, acc0, 0, 0, 0);
            acc1 = __builtin_amdgcn_mfma_f32_32x32x16_bf16(ah, cur.h1, acc1, 0, 0, 0);
            acc0 = __builtin_amdgcn_mfma_f32_32x32x16_bf16(al, cur.h0, acc0, 0, 0, 0);
            acc1 = __builtin_amdgcn_mfma_f32_32x32x16_bf16(al, cur.h1, acc1, 0, 0, 0);
            acc0 = __builtin_amdgcn_mfma_f32_32x32x16_bf16(ah, cur.l0, acc0, 0, 0, 0);
            acc1 = __builtin_amdgcn_mfma_f32_32x32x16_bf16(ah, cur.l1, acc1, 0, 0, 0);
            __builtin_amdgcn_s_setprio(0);
            cur = nxt;
        }
    }
    // ---------- weighted aggregation over edges (rows) + output
    float wtv[16];
#pragma unroll
    for (int reg = 0; reg < 16; reg++)
        wtv[reg] = __shfl(wt, (reg & 3) + 8 * (reg >> 2) + 4 * g, 64);
    float s00 = 0.f, s01 = 0.f, s10 = 0.f, s11 = 0.f;   // s<query><ntile>
#pragma unroll
    for (int reg = 0; reg < 16; reg++) {
        if (reg < 8) { s00 = fmaf(wtv[reg], acc0[reg], s00); s01 = fmaf(wtv[reg], acc1[reg], s01); }
        else         { s10 = fmaf(wtv[reg], acc0[reg], s10); s11 = fmaf(wtv[reg], acc1[reg], s11); }
    }
    s00 += __shfl_xor(s00, 32, 64);
    s01 += __shfl_xor(s01, 32, 64);
    s10 += __shfl_xor(s10, 32, 64);
    s11 += __shfl_xor(s11, 32, 64);
    float sw0 = __shfl(swt, 0, 64), sw1 = __shfl(swt, 16, 64);
    if (g == 0) {
        float i0 = 1.0f / fmaxf(sw0, 1e-6f), i1 = 1.0f / fmaxf(sw1, 1e-6f);
        int gq0 = qbase, gq1 = qbase + 1;
        if (MODE == 0) {
            int b0 = gq0 >> QSH, p0 = gq0 & QMSK;
            int b1i = gq1 >> QSH, p1 = gq1 & QMSK;
            outb[((long)b0 * 64 + r31) * 4096 + p0]        = s00 * i0;   // transposed (b, col, p)
            outb[((long)b0 * 64 + 32 + r31) * 4096 + p0]   = s01 * i0;
            outb[((long)b1i * 64 + r31) * 4096 + p1]       = s10 * i1;
            outb[((long)b1i * 64 + 32 + r31) * 4096 + p1]  = s11 * i1;
        } else {
            outb[(long)gq0 * 64 + r31]      = s00 * i0;
            outb[(long)gq0 * 64 + 32 + r31] = s01 * i0;
            outb[(long)gq1 * 64 + r31]      = s10 * i1;
            outb[(long)gq1 * 64 + 32 + r31] = s11 * i1;
        }
    }
}

// ---------------------------------------------------------------- transpose (B,R,C) -> (B,C,R)
__global__ void k_transp(const float* __restrict__ src, float* __restrict__ dst, int R, int C) {
    __shared__ float t[32][33];
    int b = blockIdx.z;
    int c0 = blockIdx.x * 32, r0 = blockIdx.y * 32;
    int tx = threadIdx.x, ty0 = threadIdx.y;    // (32,8)
    for (int yy = ty0; yy < 32; yy += 8) {
        int r = r0 + yy, c = c0 + tx;
        if (r < R && c < C) t[yy][tx] = src[((long)b * R + r) * C + c];
    }
    __syncthreads();
    for (int yy = ty0; yy < 32; yy += 8) {
        int c = c0 + yy, r = r0 + tx;
        if (r < R && c < C) dst[((long)b * C + c) * R + r] = t[tx][yy];
    }
}

// ---------------------------------------------------------------- FNO: truncated forward DFT
__global__ void __launch_bounds__(1024) k_f1(const float* __restrict__ x, float* __restrict__ Xh) {
    int blk = blockIdx.x;    // b*64 + ch
    int tid = threadIdx.x;   // 1024
    __shared__ __align__(16) float img[4096];
    __shared__ float Tre[64][12], Tim[64][12];
    __shared__ float cs[64], sn[64];
    if (tid < 64) {
        double a = (2.0 * PI_ / 64.0) * (double)tid;
        cs[tid] = (float)cos(a);
        sn[tid] = (float)sin(a);
    }
    ((float4*)img)[tid] = ((const float4*)(x + (long)blk * 4096))[tid];
    __syncthreads();
    if (tid < 768) {                             // (h, c)
        int h = tid / 12, c = tid - 12 * h;
        float re = 0.f, im = 0.f;
        for (int w = 0; w < 64; w++) {
            float v = img[h * 64 + w];
            int k = (c * w) & 63;
            re = fmaf(v, cs[k], re);
            im = fmaf(-v, sn[k], im);
        }
        Tre[h][c] = re; Tim[h][c] = im;
    }
    __syncthreads();
    if (tid < 288) {                             // (x24, c12)
        int xx = tid / 12, c = tid - 12 * xx;
        int r = (xx < 12) ? xx : (xx + 40);
        float re = 0.f, im = 0.f;
        for (int h = 0; h < 64; h++) {
            int k = (r * h) & 63;
            float cr = cs[k], si = sn[k];
            float a = Tre[h][c], bb = Tim[h][c];
            re += a * cr + bb * si;
            im += bb * cr - a * si;
        }
        Xh[((long)blk * 288 + tid) * 2] = re;
        Xh[((long)blk * 288 + tid) * 2 + 1] = im;
    }
}

// mode-mix: Yhat[b,o,m] = sum_i Wc[i,o,m] * Xhat[b,i,m]
__global__ void __launch_bounds__(256) k_f2(const float* __restrict__ Xh, const float* __restrict__ s1,
                                            const float* __restrict__ s2, float* __restrict__ Yh) {
    int m = blockIdx.x;                  // 0..287
    int xx = m / 12, y = m - 12 * xx;
    const float* W; int xw;
    if (xx < 12) { W = s1; xw = xx; } else { W = s2; xw = xx - 12; }
    __shared__ float xr[128], xi[128];
    __shared__ float pr[256], pi[256];
    int tid = threadIdx.x;               // 256
    if (tid < 128) {
        int bb = tid >> 6, i = tid & 63;
        xr[tid] = Xh[(((long)bb * 64 + i) * 288 + m) * 2];
        xi[tid] = Xh[(((long)bb * 64 + i) * 288 + m) * 2 + 1];
    }
    __syncthreads();
    int half = tid >> 7;
    int t2 = tid & 127;
    int bb = t2 >> 6, o = t2 & 63;
    float re = 0.f, im = 0.f;
    for (int i = half * 32; i < half * 32 + 32; i++) {
        long wb = (long)i * 18432 + (long)o * 288 + xw * 24 + y * 2;
        float wr = W[wb], wi = W[wb + 1];
        float a = xr[bb * 64 + i], cc = xi[bb * 64 + i];
        re += a * wr - cc * wi;
        im += a * wi + cc * wr;
    }
    pr[tid] = re; pi[tid] = im;
    __syncthreads();
    if (tid < 128) {
        float re2 = pr[tid] + pr[tid + 128];
        float im2 = pi[tid] + pi[tid + 128];
        Yh[(((long)bb * 64 + o) * 288 + m) * 2] = re2;
        Yh[(((long)bb * 64 + o) * 288 + m) * 2 + 1] = im2;
    }
}

// inverse DFT + pointwise conv + bias + InstanceNorm + GELU, fused per (b, out-channel)
__global__ void __launch_bounds__(1024) k_f3(const float* __restrict__ Yh, const float* __restrict__ x,
                                             const float* __restrict__ pwW, const float* __restrict__ pwb,
                                             float* __restrict__ xo) {
    int blk = blockIdx.x;
    int b = blk >> 6, o = blk & 63;
    int tid = threadIdx.x;   // 1024; each thread owns 4 consecutive pixels
    __shared__ float yre[288], yim[288];
    __shared__ float Qre[64][12], Qim[64][12];
    __shared__ float cs[64], sn[64];
    __shared__ float red[16];
    if (tid < 64) {
        double a = (2.0 * PI_ / 64.0) * (double)tid;
        cs[tid] = (float)cos(a);
        sn[tid] = (float)sin(a);
    }
    if (tid < 288) {
        yre[tid] = Yh[((long)blk * 288 + tid) * 2];
        yim[tid] = Yh[((long)blk * 288 + tid) * 2 + 1];
    }
    __syncthreads();
    if (tid < 768) {    // (h, c): complex ifft along rows (1/64 scale)
        int h = tid / 12, c = tid - 12 * h;
        float re = 0.f, im = 0.f;
#pragma unroll
        for (int xx = 0; xx < 24; xx++) {
            int r = (xx < 12) ? xx : (xx + 40);
            int k = (r * h) & 63;
            float wr = cs[k], wi = sn[k];
            float a = yre[xx * 12 + c], bb = yim[xx * 12 + c];
            re += a * wr - bb * wi;
            im += a * wi + bb * wr;
        }
        Qre[h][c] = re * (1.0f / 64.0f);
        Qim[h][c] = im * (1.0f / 64.0f);
    }
    __syncthreads();
    float bias = pwb[o];
    int h = tid >> 4;
    int w0 = (tid & 15) * 4;
    float sp0, sp1, sp2, sp3;
    {
        float base = Qre[h][0];
        sp0 = sp1 = sp2 = sp3 = base;
#pragma unroll
        for (int c = 1; c < 12; c++) {
            float qr = Qre[h][c], qi = Qim[h][c];
            int k0 = (c * w0) & 63, k1 = (c * (w0 + 1)) & 63;
            int k2 = (c * (w0 + 2)) & 63, k3 = (c * (w0 + 3)) & 63;
            sp0 += 2.0f * (qr * cs[k0] - qi * sn[k0]);
            sp1 += 2.0f * (qr * cs[k1] - qi * sn[k1]);
            sp2 += 2.0f * (qr * cs[k2] - qi * sn[k2]);
            sp3 += 2.0f * (qr * cs[k3] - qi * sn[k3]);
        }
    }
    float a0 = sp0 * (1.0f / 64.0f) + bias;
    float a1 = sp1 * (1.0f / 64.0f) + bias;
    float a2 = sp2 * (1.0f / 64.0f) + bias;
    float a3 = sp3 * (1.0f / 64.0f) + bias;
    const float* xb = x + ((long)b * 64) * 4096 + tid * 4;
    for (int i = 0; i < 64; i++) {
        float wv = pwW[o * 64 + i];
        const float4 xv = *(const float4*)(xb + (long)i * 4096);
        a0 = fmaf(xv.x, wv, a0);
        a1 = fmaf(xv.y, wv, a1);
        a2 = fmaf(xv.z, wv, a2);
        a3 = fmaf(xv.w, wv, a3);
    }
    // block reduction: wave shfl-reduce + 16-partial sum (3 barriers vs 20)
    float ssum = a0 + a1 + a2 + a3;
#pragma unroll
    for (int m = 1; m < 64; m <<= 1) ssum += __shfl_xor(ssum, m, 64);
    if ((tid & 63) == 0) red[tid >> 6] = ssum;
    __syncthreads();
    float mu = 0.f;
#pragma unroll
    for (int k = 0; k < 16; k++) mu += red[k];
    mu *= (1.0f / 4096.0f);
    __syncthreads();
    float d0 = a0 - mu, d1 = a1 - mu, d2 = a2 - mu, d3 = a3 - mu;
    float sq = d0 * d0 + d1 * d1 + d2 * d2 + d3 * d3;
#pragma unroll
    for (int m = 1; m < 64; m <<= 1) sq += __shfl_xor(sq, m, 64);
    if ((tid & 63) == 0) red[tid >> 6] = sq;
    __syncthreads();
    float var = 0.f;
#pragma unroll
    for (int k = 0; k < 16; k++) var += red[k];
    var *= (1.0f / 4096.0f);
    float inv = 1.0f / sqrtf(var + 1e-5f);
    float4 ov = make_float4(gelu_f(d0 * inv), gelu_f(d1 * inv), gelu_f(d2 * inv), gelu_f(d3 * inv));
    *(float4*)&xo[(long)blk * 4096 + tid * 4] = ov;
}

// ---------------------------------------------------------------- projection MLP (64 -> 64 -> 3)
__global__ void __launch_bounds__(256) k_proj(
    const float* __restrict__ y, const float* __restrict__ W1, const float* __restrict__ b1,
    const float* __restrict__ W2, const float* __restrict__ b2, float* __restrict__ out) {
    __shared__ __align__(16) float yr[4][64];
    __shared__ float h[4][64];
    int ql = threadIdx.x >> 6, j = threadIdx.x & 63;
    long node = (long)blockIdx.x * 4 + ql;
    yr[ql][j] = y[node * 64 + j];
    __syncthreads();
    float a = b1[j];
    for (int k = 0; k < 64; k += 4) {
        float w0 = W1[(k + 0) * 64 + j], w1 = W1[(k + 1) * 64 + j];
        float w2 = W1[(k + 2) * 64 + j], w3 = W1[(k + 3) * 64 + j];
        const float4 hv = *(const float4*)&yr[ql][k];
        a = fmaf(hv.x, w0, fmaf(hv.y, w1, fmaf(hv.z, w2, fmaf(hv.w, w3, a))));
    }
    h[ql][j] = gelu_f(a);
    __syncthreads();
    if (j < 3) {
        float a2 = b2[j];
        for (int k = 0; k < 64; k++) a2 = fmaf(h[ql][k], W2[k * 3 + j], a2);
        out[node * 3 + j] = a2;
    }
}

// ---------------------------------------------------------------- launch
extern "C" void kernel_launch(void* const* d_in, const int* in_sizes, int n_in,
                              void* d_out, int out_size, void* d_ws, size_t ws_size,
                              hipStream_t stream) {
    (void)in_sizes; (void)n_in; (void)out_size; (void)ws_size;
    const float* coords   = (const float*)d_in[0];
    const float* features = (const float*)d_in[1];
    const float* lift_W1 = (const float*)d_in[2];
    const float* lift_b1 = (const float*)d_in[3];
    const float* lift_W2 = (const float*)d_in[4];
    const float* lift_b2 = (const float*)d_in[5];
    const float* gin_W1 = (const float*)d_in[6];
    const float* gin_b1 = (const float*)d_in[7];
    const float* gin_W2 = (const float*)d_in[8];
    const float* gin_b2 = (const float*)d_in[9];
    const float* gin_W3 = (const float*)d_in[10];
    const float* gin_b3 = (const float*)d_in[11];
    const float* spec1 = (const float*)d_in[12];
    const float* spec2 = (const float*)d_in[13];
    const float* pw_W  = (const float*)d_in[14];
    const float* pw_b  = (const float*)d_in[15];
    const float* gout_W1 = (const float*)d_in[16];
    const float* gout_b1 = (const float*)d_in[17];
    const float* gout_W2 = (const float*)d_in[18];
    const float* gout_b2 = (const float*)d_in[19];
    const float* gout_W3 = (const float*)d_in[20];
    const float* gout_b3 = (const float*)d_in[21];
    const float* proj_W1 = (const float*)d_in[22];
    const float* proj_b1 = (const float*)d_in[23];
    const float* proj_W2 = (const float*)d_in[24];
    const float* proj_b2 = (const float*)d_in[25];

    char* ws = (char*)d_ws;
    size_t off = 0;
    auto alloc = [&](size_t bytes) -> char* {
        char* p = ws + off;
        off = (off + bytes + 255) & ~(size_t)255;
        return p;
    };
    float4* grid_pack = (float4*)alloc((size_t)NG * 16);
    float*  feat      = (float*)alloc((size_t)B_ * N_ * 64 * 4);
    int*    bin_cnt   = (int*)alloc((size_t)B_ * 4096 * 4);
    int*    bin_fill  = (int*)alloc((size_t)B_ * 4096 * 4);   // contiguous after bin_cnt
    int*    bin_off   = (int*)alloc((size_t)B_ * 4097 * 4);
    float4* srt       = (float4*)alloc((size_t)B_ * N_ * 16);
    int*    idx_in    = (int*)alloc((size_t)B_ * NG * 16 * 4);
    float*  dist_in   = (float*)alloc((size_t)B_ * NG * 16 * 4);
    float*  lastd_in  = (float*)alloc((size_t)B_ * NG * 4);
    float*  sig_in    = (float*)alloc(256);
    float*  xb0       = (float*)alloc((size_t)B_ * 64 * NG * 4);
    float*  xb1       = (float*)alloc((size_t)B_ * 64 * NG * 4);
    float*  Xh        = (float*)alloc((size_t)B_ * 64 * 288 * 2 * 4);
    float*  Yh        = (float*)alloc((size_t)B_ * 64 * 288 * 2 * 4);
    float*  g2        = (float*)alloc((size_t)B_ * NG * 64 * 4);
    int*    idx_out   = (int*)alloc((size_t)B_ * N_ * 16 * 4);
    float*  dist_out  = (float*)alloc((size_t)B_ * N_ * 16 * 4);
    float*  lastd_out = (float*)alloc((size_t)B_ * N_ * 4);
    float*  sig_out   = (float*)alloc(256);
    float*  ybuf      = (float*)alloc((size_t)B_ * N_ * 64 * 4);
    short*  wb_in     = (short*)alloc((size_t)52 * 1024);   // 52 x 1KB bf16 hi/lo fragments
    short*  wb_out    = (short*)alloc((size_t)52 * 1024);

    // bin_cnt and bin_fill are contiguous 256B-aligned blocks: one memset
    hipMemsetAsync(bin_cnt, 0, (size_t)B_ * 4096 * 4 * 2, stream);

    k_wcvt<<<26, 256, 0, stream>>>(gin_W1, gin_W2, gin_W3, wb_in,
                                   gout_W1, gout_W2, gout_W3, wb_out);
    k_lift<<<(B_ * N_) / 4, 256, 0, stream>>>(features, lift_W1, lift_b1, lift_W2, lift_b2, feat);
    k_bincount<<<(B_ * N_) / 256, 256, 0, stream>>>((const float2*)coords, bin_cnt, grid_pack);
    k_binscan<<<B_, 1024, 0, stream>>>(bin_cnt, bin_off);
    k_binscatter<<<(B_ * N_) / 256, 256, 0, stream>>>((const float2*)coords, bin_off, bin_fill, srt);
    k_knn_in<<<(B_ * NG * 64) / 256, 256, 0, stream>>>(grid_pack, srt, bin_off, idx_in, dist_in, lastd_in);
    k_median_bis<<<1, 1024, 0, stream>>>(lastd_in, B_ * NG, sig_in);
    k_edge_mfma<0><<<(B_ * NG) / 4, 128, 0, stream>>>(idx_in, dist_in, sig_in,
        (const float2*)coords, grid_pack, feat, wb_in,
        gin_b1, gin_b2, gin_b3, xb0);
    float* xc = xb0; float* xn = xb1;
    for (int d = 0; d < 3; d++) {
        k_f1<<<B_ * 64, 1024, 0, stream>>>(xc, Xh);
        k_f2<<<288, 256, 0, stream>>>(Xh, spec1 + (size_t)d * 1179648, spec2 + (size_t)d * 1179648, Yh);
        k_f3<<<B_ * 64, 1024, 0, stream>>>(Yh, xc, pw_W + (size_t)d * 4096, pw_b + (size_t)d * 64, xn);
        float* tmp = xc; xc = xn; xn = tmp;
    }
    {
        dim3 g(NG / 32, 64 / 32, B_); dim3 t(32, 8);
        k_transp<<<g, t, 0, stream>>>(xc, g2, 64, NG);
    }
    k_knn_out<<<(B_ * N_ * 64) / 256, 256, 0, stream>>>((const float2*)coords, grid_pack, idx_out, dist_out, lastd_out);
    k_median_bis<<<1, 1024, 0, stream>>>(lastd_out, B_ * N_, sig_out);
    k_edge_mfma<1><<<(B_ * N_) / 4, 128, 0, stream>>>(idx_out, dist_out, sig_out,
        (const float2*)coords, grid_pack, g2, wb_out,
        gout_b1, gout_b2, gout_b3, ybuf);
    k_proj<<<(B_ * N_) / 4, 256, 0, stream>>>(ybuf, proj_W1, proj_b1, proj_W2, proj_b2, (float*)d_out);
}

// Round 6
// 403.776 us; speedup vs baseline: 1.3656x; 1.1102x over previous
//
#include <hip/hip_runtime.h>
#include <math.h>

#define B_ 2
#define N_ 8192          // points per batch
#define G_ 64
#define NG 4096          // G*G latent grid points
#define WID_ 64
#define K_ 16
#define CIN_ 6
#define COUT_ 3
#define PI_ 3.14159265358979323846

typedef unsigned long long u64k;
typedef __attribute__((ext_vector_type(8))) short bf16x8;   // 8 bf16 bit-patterns (4 VGPR)
typedef __attribute__((ext_vector_type(16))) float f32x16;  // 32x32 MFMA acc

// ---------------------------------------------------------------- helpers
// exact-erf GELU via Abramowitz-Stegun 7.1.26 (|eps_erf| <= 1.5e-7), branchless.
__device__ __forceinline__ float gelu_f(float x) {
    float u = fabsf(x) * 0.70710678118654752440f;
    float t = __builtin_amdgcn_rcpf(fmaf(0.3275911f, u, 1.0f));
    float p = fmaf(fmaf(fmaf(fmaf(1.061405429f, t, -1.453152027f), t, 1.421413741f),
                        t, -0.284496736f), t, 0.254829592f) * t;
    float e = __expf(-u * u);
    float erfc_u = p * e;                               // erfc(u), u >= 0
    float phi = (x >= 0.f) ? fmaf(-0.5f, erfc_u, 1.0f) : (0.5f * erfc_u);
    return x * phi;
}
__device__ __forceinline__ int cellof(float v) {
    int c = (int)floorf((v + 1.0f) * 32.0f);
    return min(63, max(0, c));
}
__device__ __forceinline__ u64k umin64(u64k a, u64k b) { return a < b ? a : b; }
__device__ __forceinline__ u64k umax64(u64k a, u64k b) { return a < b ? b : a; }
__device__ __forceinline__ u64k shflxor64(u64k v, int m) {
    return (u64k)__shfl_xor((long long)v, m, 64);
}
__device__ __forceinline__ void bsort64(u64k& key, int lane) {
#pragma unroll
    for (int sz = 2; sz <= 64; sz <<= 1) {
#pragma unroll
        for (int j = sz >> 1; j >= 1; j >>= 1) {
            u64k o = shflxor64(key, j);
            bool keep_min = ((lane & j) == 0) == ((lane & sz) == 0);
            key = keep_min ? umin64(key, o) : umax64(key, o);
        }
    }
}
__device__ __forceinline__ void bmerge_into(u64k& R, u64k key, int lane) {
    u64k o = shflxor64(key, 63);
    u64k L = umin64(R, o);
#pragma unroll
    for (int j = 32; j >= 1; j >>= 1) {
        u64k t = shflxor64(L, j);
        L = ((lane & j) == 0) ? umin64(L, t) : umax64(L, t);
    }
    R = L;
}
// split fp32 -> bf16 hi (round-half-up, 0.5-ulp) + bf16 lo (truncated residual)
__device__ __forceinline__ void cvt8v(float4 a, float4 b, bf16x8& hv, bf16x8& lv) {
    float v[8] = {a.x, a.y, a.z, a.w, b.x, b.y, b.z, b.w};
#pragma unroll
    for (int i = 0; i < 8; i++) {
        unsigned u = __float_as_uint(v[i]);
        unsigned r = (u + 0x8000u) & 0xffff0000u;
        hv[i] = (short)(r >> 16);
        float lo = v[i] - __uint_as_float(r);
        lv[i] = (short)(__float_as_uint(lo) >> 16);
    }
}
__device__ __forceinline__ bf16x8 ldfrag(const short* __restrict__ WB, int f, int lane) {
    return *(const bf16x8*)(WB + ((long)f * 64 + lane) * 8);
}
struct Frag4 { bf16x8 h0, l0, h1, l1; };
// base/nk select layer: L1 base=0 nk=5, L2 base=20 nk=4, L3 base=36 nk=4
__device__ __forceinline__ Frag4 ldfrag4(const short* __restrict__ WB, int base, int nk,
                                         int kc, int lane) {
    Frag4 f;
    f.h0 = ldfrag(WB, base + (0 * nk + kc) * 2 + 0, lane);
    f.l0 = ldfrag(WB, base + (0 * nk + kc) * 2 + 1, lane);
    f.h1 = ldfrag(WB, base + (1 * nk + kc) * 2 + 0, lane);
    f.l1 = ldfrag(WB, base + (1 * nk + kc) * 2 + 1, lane);
    return f;
}

// ---------------------------------------------------------------- binning (+ grid gen fused)
__global__ void k_bincount(const float2* __restrict__ coords, int* __restrict__ cnt,
                           float4* __restrict__ gp) {
    int t = blockIdx.x * blockDim.x + threadIdx.x;
    if (t < NG) {        // numpy linspace semantics grid gen
        int i = t >> 6, j = t & 63;
        double st = 2.0 / 63.0;
        float gx = (i == 63) ? 1.0f : (float)(-1.0 + st * (double)i);
        float gy = (j == 63) ? 1.0f : (float)(-1.0 + st * (double)j);
        float s2 = __fadd_rn(__fmul_rn(gx, gx), __fmul_rn(gy, gy));
        gp[t] = make_float4(gx, gy, s2, 0.f);
    }
    if (t >= B_ * N_) return;
    float2 c = coords[t];
    int b = t >> 13;
    int cell = cellof(c.x) * 64 + cellof(c.y);
    atomicAdd(&cnt[b * 4096 + cell], 1);
}
// v2: wave shfl_up scan + 16-partial combine -> 1 barrier (was 10)
__global__ void k_binscan(const int* __restrict__ cnt, int* __restrict__ offs) {
    int b = blockIdx.x, t = threadIdx.x;    // 1024 threads
    __shared__ int part[16];
    int4 v = ((const int4*)(cnt + b * 4096))[t];
    int sum = v.x + v.y + v.z + v.w;
    int lane = t & 63, wv = t >> 6;
    int ws = sum;
#pragma unroll
    for (int o = 1; o < 64; o <<= 1) {
        int u = __shfl_up(ws, o, 64);
        if (lane >= o) ws += u;
    }
    if (lane == 63) part[wv] = ws;
    __syncthreads();
    int base = 0;
#pragma unroll
    for (int k = 0; k < 16; k++) base += (k < wv) ? part[k] : 0;
    int incl = base + ws, excl = incl - sum;
    int* ob = offs + b * 4097;
    ob[4 * t] = excl; ob[4 * t + 1] = excl + v.x;
    ob[4 * t + 2] = excl + v.x + v.y; ob[4 * t + 3] = excl + v.x + v.y + v.z;
    if (t == 1023) ob[4096] = incl;
}
__global__ void k_binscatter(const float2* __restrict__ coords, const int* __restrict__ offs,
                             int* __restrict__ fill, float4* __restrict__ srt) {
    int t = blockIdx.x * blockDim.x + threadIdx.x;
    if (t >= B_ * N_) return;
    float2 c = coords[t];
    int b = t >> 13, n = t & 8191;
    int cell = cellof(c.x) * 64 + cellof(c.y);
    int pos = offs[b * 4097 + cell] + atomicAdd(&fill[b * 4096 + cell], 1);
    float s2 = __fadd_rn(__fmul_rn(c.x, c.x), __fmul_rn(c.y, c.y));
    srt[b * N_ + pos] = make_float4(c.x, c.y, s2, __int_as_float(n));
}

// ---------------------------------------------------------------- lift MLP
__global__ void __launch_bounds__(256) k_lift(
    const float* __restrict__ fin, const float* __restrict__ W1,
    const float* __restrict__ b1, const float* __restrict__ W2,
    const float* __restrict__ b2, float* __restrict__ fout) {
    __shared__ float xr[4][8];
    __shared__ __align__(16) float h[4][64];
    int ql = threadIdx.x >> 6, j = threadIdx.x & 63;
    int node = blockIdx.x * 4 + ql;
    if (j < CIN_) xr[ql][j] = fin[node * CIN_ + j];
    __syncthreads();
    float a = b1[j];
#pragma unroll
    for (int i = 0; i < CIN_; i++) a = fmaf(xr[ql][i], W1[i * 64 + j], a);
    h[ql][j] = gelu_f(a);
    __syncthreads();
    float a2 = b2[j];
    for (int k = 0; k < 64; k += 4) {
        float w0 = W2[(k + 0) * 64 + j], w1 = W2[(k + 1) * 64 + j];
        float w2 = W2[(k + 2) * 64 + j], w3 = W2[(k + 3) * 64 + j];
        const float4 hv = *(const float4*)&h[ql][k];
        a2 = fmaf(hv.x, w0, fmaf(hv.y, w1, fmaf(hv.z, w2, fmaf(hv.w, w3, a2))));
    }
    fout[node * 64 + j] = a2;
}

// ---------------------------------------------------------------- kNN grid->points: one wave per query
__global__ void __launch_bounds__(256) k_knn_in(
    const float4* __restrict__ gp, const float4* __restrict__ srt,
    const int* __restrict__ offs, int* __restrict__ oidx,
    float* __restrict__ odist, float* __restrict__ lastd) {
    int lane = threadIdx.x & 63;
    int w = (blockIdx.x * blockDim.x + threadIdx.x) >> 6;
    int b = w >> 12, p = w & 4095;
    float4 q = gp[p];
    float qx = q.x, qy = q.y, q2 = q.z;
    int cqx = cellof(qx), cqy = cellof(qy);
    const float4* S = srt + b * N_;
    const int* OF = offs + b * 4097;

    u64k R = ~0ull;
    u64k pend = ~0ull;
    int fill = 0;

    auto flush = [&]() {
        bsort64(pend, lane);
        bmerge_into(R, pend, lane);
        pend = ~0ull;
        fill = 0;
    };
    auto feed = [&](int s0, int s1) {
        int cnt = s1 - s0;
        while (cnt > 0) {
            int take = min(cnt, 64 - fill);
            int t = lane - fill;
            if (t >= 0 && t < take) {
                float4 sp = S[s0 + t];
                float dot = __fadd_rn(__fmul_rn(qx, sp.x), __fmul_rn(qy, sp.y));
                float d2 = __fsub_rn(__fadd_rn(q2, sp.z), 2.0f * dot);
                d2 = fmaxf(d2, 0.0f);
                pend = ((u64k)__float_as_uint(d2) << 32) | (unsigned)__float_as_int(sp.w);
            }
            fill += take; s0 += take; cnt -= take;
            if (fill == 64) flush();
        }
    };

    {
        int xa = max(cqx - 2, 0), xb = min(cqx + 2, 63);
        int ya = max(cqy - 2, 0), yb = min(cqy + 2, 63);
        for (int cx = xa; cx <= xb; cx++) feed(OF[cx * 64 + ya], OF[cx * 64 + yb + 1]);
    }
    int r = 2;
    while (true) {
        if (fill) flush();
        u64k T = (u64k)__shfl((long long)R, 15, 64);
        float d16 = __uint_as_float((unsigned)(T >> 32));
        float bm = (float)r * 0.03125f;
        if (d16 < bm * bm - 1e-5f) break;
        if (cqx - r <= 0 && cqx + r >= 63 && cqy - r <= 0 && cqy + r >= 63) break;
        r++;
        int ya = max(cqy - r, 0), yb = min(cqy + r, 63);
        if (cqx - r >= 0)  { int c0 = (cqx - r) * 64; feed(OF[c0 + ya], OF[c0 + yb + 1]); }
        if (cqx + r <= 63) { int c0 = (cqx + r) * 64; feed(OF[c0 + ya], OF[c0 + yb + 1]); }
        int xa2 = max(cqx - r + 1, 0), xb2 = min(cqx + r - 1, 63);
        for (int cx = xa2; cx <= xb2; cx++) {
            if (cqy - r >= 0)  { int cc = cx * 64 + cqy - r; feed(OF[cc], OF[cc + 1]); }
            if (cqy + r <= 63) { int cc = cx * 64 + cqy + r; feed(OF[cc], OF[cc + 1]); }
        }
    }
    if (lane < 16) {
        float d2 = __uint_as_float((unsigned)(R >> 32));
        float d = sqrtf(d2);
        oidx[w * 16 + lane] = (int)(unsigned)(R & 0xffffffffu);
        odist[w * 16 + lane] = d;
        if (lane == 15) lastd[w] = d;
    }
}

// ---------------------------------------------------------------- kNN points->grid: one wave per query
__global__ void __launch_bounds__(256) k_knn_out(
    const float2* __restrict__ coords, const float4* __restrict__ gp,
    int* __restrict__ oidx, float* __restrict__ odist, float* __restrict__ lastd) {
    int lane = threadIdx.x & 63;
    int w = (blockIdx.x * blockDim.x + threadIdx.x) >> 6;
    float2 c = coords[w];
    float qx = c.x, qy = c.y;
    float q2 = __fadd_rn(__fmul_rn(qx, qx), __fmul_rn(qy, qy));
    int i0 = (int)floorf((qx + 1.0f) * 31.5f);
    int j0 = (int)floorf((qy + 1.0f) * 31.5f);
    int li = min(max(i0 - 3, 0), 56);
    int lj = min(max(j0 - 3, 0), 56);
    int p = (li + (lane >> 3)) * 64 + (lj + (lane & 7));
    float4 sp = gp[p];
    float dot = __fadd_rn(__fmul_rn(qx, sp.x), __fmul_rn(qy, sp.y));
    float d2 = fmaxf(__fsub_rn(__fadd_rn(q2, sp.z), 2.0f * dot), 0.0f);
    u64k key = ((u64k)__float_as_uint(d2) << 32) | (unsigned)p;
    bsort64(key, lane);
    if (lane < 16) {
        float dd = sqrtf(__uint_as_float((unsigned)(key >> 32)));
        oidx[w * 16 + lane] = (int)(unsigned)(key & 0xffffffffu);
        odist[w * 16 + lane] = dd;
        if (lane == 15) lastd[w] = dd;
    }
}

// ---------------------------------------------------------------- exact lower-median via 32-step bisection
__global__ void __launch_bounds__(1024) k_median_bis(
    const float* __restrict__ vals, int n, float* __restrict__ sig) {
    __shared__ int wred[2][16];
    int tid = threadIdx.x;
    int lane = tid & 63, wv = tid >> 6;
    int cnt_per = n >> 10;           // 8 or 16
    unsigned v[16];
    for (int i = 0; i < cnt_per; i++) v[i] = __float_as_uint(vals[tid + (i << 10)]);
    int r = (n - 1) >> 1;
    unsigned prefix = 0;
    for (int bit = 31; bit >= 0; bit--) {
        unsigned cand = prefix | (1u << bit);
        int c = 0;
        for (int i = 0; i < cnt_per; i++) c += (v[i] < cand) ? 1 : 0;
        for (int o = 32; o >= 1; o >>= 1) c += __shfl_down(c, o, 64);
        int buf = bit & 1;
        if (lane == 0) wred[buf][wv] = c;
        __syncthreads();
        int tot = 0;
#pragma unroll
        for (int k = 0; k < 16; k++) tot += wred[buf][k];
        prefix = (tot <= r) ? cand : prefix;
    }
    if (tid == 0) *sig = fmaxf(__uint_as_float(prefix), 1e-6f);
}

// ---------------------------------------------------------------- weight split/pack for MFMA edge MLP
// Both weight sets (gin, gout) in ONE launch: t < 3328 -> set A, else set B.
__global__ void k_wcvt(const float* __restrict__ W1a, const float* __restrict__ W2a,
                       const float* __restrict__ W3a, short* __restrict__ WBa,
                       const float* __restrict__ W1b, const float* __restrict__ W2b,
                       const float* __restrict__ W3b, short* __restrict__ WBb) {
    int t = blockIdx.x * blockDim.x + threadIdx.x;   // 2 * 52*64 = 6656 threads
    if (t >= 6656) return;
    int setb = (t >= 3328);
    int tt = t - (setb ? 3328 : 0);
    const float* W1s = setb ? W1b : W1a;
    const float* W2s = setb ? W2b : W2a;
    const float* W3s = setb ? W3b : W3a;
    short* WB = setb ? WBb : WBa;
    int f = tt >> 6, lane = tt & 63;
    const float* W; int h, nt, kc, l1 = 0;
    if (f < 20)      { W = W1s; int r = f;      h = r & 1; r >>= 1; nt = r / 5; kc = r % 5; l1 = 1; }
    else if (f < 36) { W = W2s; int r = f - 20; h = r & 1; r >>= 1; nt = r / 4; kc = r % 4; }
    else             { W = W3s; int r = f - 36; h = r & 1; r >>= 1; nt = r / 4; kc = r % 4; }
    int col = nt * 32 + (lane & 31);
    bf16x8 out;
#pragma unroll
    for (int i = 0; i < 8; i++) {
        int k = kc * 16 + (lane >> 5) * 8 + i;
        float w = 0.f;
        if (l1) {
            if (k < 7) w = W[k * 64 + col];
            else if (k >= 8 && k < 72) w = W[(k - 1) * 64 + col];
        } else {
            w = W[k * 64 + col];
        }
        unsigned u = __float_as_uint(w);
        unsigned hi = (u + 0x7fffu + ((u >> 16) & 1u)) & 0xffff0000u;
        float lo = w - __uint_as_float(hi);
        unsigned ul = __float_as_uint(lo);
        unsigned lr = ul + 0x7fffu + ((ul >> 16) & 1u);
        out[i] = h ? (short)(lr >> 16) : (short)(hi >> 16);
    }
    *(bf16x8*)(WB + ((long)f * 64 + lane) * 8) = out;
}

// ---------------------------------------------------------------- edge MLP via split-bf16 MFMA (v5, stable)
// Plateaued at ~43-44us over v3/v4/v5: occupancy pinned at 4 waves/SIMD by the
// unified VGPR+AGPR budget (32-reg acc counts); VALU cuts neutral. Left as-is.
// C/D layout (HW-verified): col = lane&31, row = (reg&3) + 8*(reg>>2) + 4*(lane>>5).
template <int MODE>
__global__ void __launch_bounds__(128, 4) k_edge_mfma(
    const int* __restrict__ idxb, const float* __restrict__ distb,
    const float* __restrict__ sigp,
    const float2* __restrict__ coords, const float4* __restrict__ gp,
    const float* __restrict__ feats, const short* __restrict__ WB,
    const float* __restrict__ b1, const float* __restrict__ b2,
    const float* __restrict__ b3,
    float* __restrict__ outb) {
    constexpr int QSH  = (MODE == 0) ? 12 : 13;     // log2(Nq)
    constexpr int QMSK = (MODE == 0) ? 4095 : 8191;
    constexpr long SR  = (MODE == 0) ? 8192 : 4096; // srcRows
    __shared__ float X[2][2432];           // per wave: 32 rows x 76 floats
    const int tid = threadIdx.x, wv = tid >> 6, lane = tid & 63;
    const int r31 = lane & 31, g = lane >> 5;
    const int qbase = (blockIdx.x * 2 + wv) * 2;
    const float sig = *sigp;
    float* X_ = X[wv];

    // issue first B-fragment load immediately: in flight during staging
    Frag4 cur = ldfrag4(WB, 0, 5, 0, lane);

    // ---- staging: 32 (query,edge) rows by lanes 0..31
    int si = 0; float wt = 0.f;
    if (lane < 32) {
        int q = lane >> 4, e = lane & 15;
        int gq = qbase + q;
        int b = gq >> QSH, p = gq & QMSK;
        si = idxb[gq * 16 + e];
        float d = distb[gq * 16 + e];
        wt = __expf(-d / sig);
        float qx, qy, sx, sy;
        if (MODE == 0) {
            float4 gv = gp[p]; qx = gv.x; qy = gv.y;
            float2 cc = coords[(long)b * SR + si]; sx = cc.x; sy = cc.y;
        } else {
            float2 cc = coords[gq]; qx = cc.x; qy = cc.y;   // b*Nq + p == gq
            float4 gv = gp[si]; sx = gv.x; sy = gv.y;
        }
        float* row = X_ + lane * 76;
        *(float4*)row       = make_float4(qx, qy, sx, sy);
        *(float4*)(row + 4) = make_float4(qx - sx, qy - sy, d, 0.f);
    }
    // per-query weight sums (within each 16-lane group)
    float swt = wt;
#pragma unroll
    for (int m = 1; m < 16; m <<= 1) swt += __shfl_xor(swt, m, 64);
    // ---- feats gather: 32 rows x 16 float4; batch loads -> regs, then write
    {
        float4 fv[8];
#pragma unroll
        for (int it = 0; it < 8; it++) {
            int slot = it * 64 + lane;
            int row = slot >> 4, f4 = slot & 15;
            int gq = qbase + (row >> 4);
            int b = gq >> QSH;
            int sr = __shfl(si, row, 64);
            fv[it] = *(const float4*)&feats[((long)b * SR + sr) * 64 + f4 * 4];
        }
#pragma unroll
        for (int it = 0; it < 8; it++) {
            int slot = it * 64 + lane;
            int row = slot >> 4, f4 = slot & 15;
            *(float4*)&X_[row * 76 + 8 + f4 * 4] = fv[it];
        }
    }

    f32x16 acc0, acc1;
    float4 xa, xb;
    // ---------- layer 1: K = 71 (+pad), kc 0..4; kc=4 upper half is A=0
    {
        float bb0 = b1[r31], bb1 = b1[32 + r31];
#pragma unroll
        for (int i = 0; i < 16; i++) { acc0[i] = bb0; acc1[i] = bb1; }
        {
            const float* xp = &X_[r31 * 76 + g * 8];
            xa = *(const float4*)xp; xb = *(const float4*)(xp + 4);
        }
#pragma unroll
        for (int kc = 0; kc < 5; kc++) {
            Frag4 nxt = (kc < 4) ? ldfrag4(WB, 0, 5, kc + 1, lane)
                                 : ldfrag4(WB, 20, 4, 0, lane);   // layer-2 kc0
            bf16x8 ah, al;
            if (kc == 4 && g) {
#pragma unroll
                for (int i = 0; i < 8; i++) { ah[i] = 0; al[i] = 0; }
            } else {
                cvt8v(xa, xb, ah, al);
            }
            // prefetch next-kc A pair (skip kc=3,g=1: that is the zero pad region)
            if (kc < 4 && (kc != 3 || g == 0)) {
                const float* xp = &X_[r31 * 76 + (kc + 1) * 16 + g * 8];
                xa = *(const float4*)xp; xb = *(const float4*)(xp + 4);
            }
            __builtin_amdgcn_s_setprio(1);
            acc0 = __builtin_amdgcn_mfma_f32_32x32x16_bf16(ah, cur.h0, acc0, 0, 0, 0);
            acc1 = __builtin_amdgcn_mfma_f32_32x32x16_bf16(ah, cur.h1, acc1, 0, 0, 0);
            acc0 = __builtin_amdgcn_mfma_f32_32x32x16_bf16(al, cur.h0, acc0, 0, 0, 0);
            acc1 = __builtin_amdgcn_mfma_f32_32x32x16_bf16(al, cur.h1, acc1, 0, 0, 0);
            acc0 = __builtin_amdgcn_mfma_f32_32x32x16_bf16(ah, cur.l0, acc0, 0, 0, 0);
            acc1 = __builtin_amdgcn_mfma_f32_32x32x16_bf16(ah, cur.l1, acc1, 0, 0, 0);
            __builtin_amdgcn_s_setprio(0);
            cur = nxt;
        }
    }
    // h = gelu(acc) -> LDS (overwrites x slots 0..63; all layer-1 reads done)
#pragma unroll
    for (int reg = 0; reg < 16; reg++) {
        int row = (reg & 3) + 8 * (reg >> 2) + 4 * g;
        X_[row * 76 + r31]      = gelu_f(acc0[reg]);
        X_[row * 76 + 32 + r31] = gelu_f(acc1[reg]);
    }
    // ---------- layer 2
    {
        float bb0 = b2[r31], bb1 = b2[32 + r31];
#pragma unroll
        for (int i = 0; i < 16; i++) { acc0[i] = bb0; acc1[i] = bb1; }
        {
            const float* xp = &X_[r31 * 76 + g * 8];
            xa = *(const float4*)xp; xb = *(const float4*)(xp + 4);
        }
#pragma unroll
        for (int kc = 0; kc < 4; kc++) {
            Frag4 nxt = (kc < 3) ? ldfrag4(WB, 20, 4, kc + 1, lane)
                                 : ldfrag4(WB, 36, 4, 0, lane);   // layer-3 kc0
            bf16x8 ah, al;
            cvt8v(xa, xb, ah, al);
            if (kc < 3) {
                const float* xp = &X_[r31 * 76 + (kc + 1) * 16 + g * 8];
                xa = *(const float4*)xp; xb = *(const float4*)(xp + 4);
            }
            __builtin_amdgcn_s_setprio(1);
            acc0 = __builtin_amdgcn_mfma_f32_32x32x16_bf16(ah, cur.h0, acc0, 0, 0, 0);
            acc1 = __builtin_amdgcn_mfma_f32_32x32x16_bf16(ah, cur.h1, acc1, 0, 0, 0);
            acc0 = __builtin_amdgcn_mfma_f32_32x32x16_bf16(al, cur.h0, acc0, 0, 0, 0);
            acc1 = __builtin_amdgcn_mfma_f32_32x32x16_bf16(al, cur.h1, acc1, 0, 0, 0);
            acc0 = __builtin_amdgcn_mfma_f32_32x32x16_bf16(ah, cur.l0, acc0, 0, 0, 0);
            acc1 = __builtin_amdgcn_mfma_f32_32x32x16_bf16(ah, cur.l1, acc1, 0, 0, 0);
            __builtin_amdgcn_s_setprio(0);
            cur = nxt;
        }
    }
#pragma unroll
    for (int reg = 0; reg < 16; reg++) {
        int row = (reg & 3) + 8 * (reg >> 2) + 4 * g;
        X_[row * 76 + r31]      = gelu_f(acc0[reg]);
        X_[row * 76 + 32 + r31] = gelu_f(acc1[reg]);
    }
    // ---------- layer 3 (no activation)
    {
        float bb0 = b3[r31], bb1 = b3[32 + r31];
#pragma unroll
        for (int i = 0; i < 16; i++) { acc0[i] = bb0; acc1[i] = bb1; }
        {
            const float* xp = &X_[r31 * 76 + g * 8];
            xa = *(const float4*)xp; xb = *(const float4*)(xp + 4);
        }
#pragma unroll
        for (int kc = 0; kc < 4; kc++) {
            Frag4 nxt = cur;
            if (kc < 3) nxt = ldfrag4(WB, 36, 4, kc + 1, lane);
            bf16x8 ah, al;
            cvt8v(xa, xb, ah, al);
            if (kc < 3) {
                const float* xp = &X_[r31 * 76 + (kc + 1) * 16 + g * 8];
                xa = *(const float4*)xp; xb = *(const float4*)(xp + 4);
            }
            __builtin_amdgcn_s_setprio(1);
            acc0 = __builtin_amdgcn_mfma_f32_32x32x16_bf16(ah, cur.h0, acc0, 0, 0, 0);
            acc1 = __builtin_amdgcn_mfma_f32_32x32x16_bf16(ah, cur.h1, acc1, 0, 0, 0);
            acc0 = __builtin_amdgcn_mfma_f32_32x32x16_bf16(al, cur.h0, acc0, 0, 0, 0);
            acc1 = __builtin_amdgcn_mfma_f32_32x32x16_bf16(al, cur.h1, acc1, 0, 0, 0);
            acc0 = __builtin_amdgcn_mfma_f32_32x32x16_bf16(ah, cur.l0, acc0, 0, 0, 0);
            acc1 = __builtin_amdgcn_mfma_f32_32x32x16_bf16(ah, cur.l1, acc1, 0, 0, 0);
            __builtin_amdgcn_s_setprio(0);
            cur = nxt;
        }
    }
    // ---------- weighted aggregation over edges (rows) + output
    float wtv[16];
#pragma unroll
    for (int reg = 0; reg < 16; reg++)
        wtv[reg] = __shfl(wt, (reg & 3) + 8 * (reg >> 2) + 4 * g, 64);
    float s00 = 0.f, s01 = 0.f, s10 = 0.f, s11 = 0.f;   // s<query><ntile>
#pragma unroll
    for (int reg = 0; reg < 16; reg++) {
        if (reg < 8) { s00 = fmaf(wtv[reg], acc0[reg], s00); s01 = fmaf(wtv[reg], acc1[reg], s01); }
        else         { s10 = fmaf(wtv[reg], acc0[reg], s10); s11 = fmaf(wtv[reg], acc1[reg], s11); }
    }
    s00 += __shfl_xor(s00, 32, 64);
    s01 += __shfl_xor(s01, 32, 64);
    s10 += __shfl_xor(s10, 32, 64);
    s11 += __shfl_xor(s11, 32, 64);
    float sw0 = __shfl(swt, 0, 64), sw1 = __shfl(swt, 16, 64);
    if (g == 0) {
        float i0 = 1.0f / fmaxf(sw0, 1e-6f), i1 = 1.0f / fmaxf(sw1, 1e-6f);
        int gq0 = qbase, gq1 = qbase + 1;
        if (MODE == 0) {
            int b0 = gq0 >> QSH, p0 = gq0 & QMSK;
            int b1i = gq1 >> QSH, p1 = gq1 & QMSK;
            outb[((long)b0 * 64 + r31) * 4096 + p0]        = s00 * i0;   // transposed (b, col, p)
            outb[((long)b0 * 64 + 32 + r31) * 4096 + p0]   = s01 * i0;
            outb[((long)b1i * 64 + r31) * 4096 + p1]       = s10 * i1;
            outb[((long)b1i * 64 + 32 + r31) * 4096 + p1]  = s11 * i1;
        } else {
            outb[(long)gq0 * 64 + r31]      = s00 * i0;
            outb[(long)gq0 * 64 + 32 + r31] = s01 * i0;
            outb[(long)gq1 * 64 + r31]      = s10 * i1;
            outb[(long)gq1 * 64 + 32 + r31] = s11 * i1;
        }
    }
}

// ---------------------------------------------------------------- transpose (B,R,C) -> (B,C,R)
__global__ void k_transp(const float* __restrict__ src, float* __restrict__ dst, int R, int C) {
    __shared__ float t[32][33];
    int b = blockIdx.z;
    int c0 = blockIdx.x * 32, r0 = blockIdx.y * 32;
    int tx = threadIdx.x, ty0 = threadIdx.y;    // (32,8)
    for (int yy = ty0; yy < 32; yy += 8) {
        int r = r0 + yy, c = c0 + tx;
        if (r < R && c < C) t[yy][tx] = src[((long)b * R + r) * C + c];
    }
    __syncthreads();
    for (int yy = ty0; yy < 32; yy += 8) {
        int c = c0 + yy, r = r0 + tx;
        if (r < R && c < C) dst[((long)b * C + c) * R + r] = t[tx][yy];
    }
}

// ---------------------------------------------------------------- FNO: truncated forward DFT (v2)
// 2 blocks per (b,ch) image (chalf = 6 of 12 freq cols each) -> 256 blocks (full
// GPU vs 128). Phasor-rotation replaces per-iter trig LDS reads (192 -> 64 DS
// ops/thread in phase 1); drift bounded by mid-loop reseed from the exact table.
__global__ void __launch_bounds__(384) k_f1(const float* __restrict__ x, float* __restrict__ Xh) {
    int blk = blockIdx.x >> 1;       // b*64 + ch
    int chalf = blockIdx.x & 1;
    int tid = threadIdx.x;           // 384
    __shared__ __align__(16) float img[4096];
    __shared__ float Tre[64][6], Tim[64][6];
    __shared__ float cs[64], sn[64];
    if (tid < 64) {
        double a = (2.0 * PI_ / 64.0) * (double)tid;
        cs[tid] = (float)cos(a);
        sn[tid] = (float)sin(a);
    }
    for (int t = tid; t < 1024; t += 384)
        ((float4*)img)[t] = ((const float4*)(x + (long)blk * 4096))[t];
    __syncthreads();
    {                                 // (h 64, c 6) = 384 threads, all active
        int h = tid / 6, cl = tid - 6 * h;
        int c = chalf * 6 + cl;
        float cr = cs[c], sr = sn[c];
        float pr = 1.f, pi = 0.f;     // (cos, sin)(2pi c w / 64)
        float re = 0.f, im = 0.f;
#pragma unroll 16
        for (int w = 0; w < 64; w++) {
            if (w == 32) {            // reseed: kill accumulated rotation drift
                int k = (c * 32) & 63;
                pr = cs[k]; pi = sn[k];
            }
            float v = img[h * 64 + w];
            re = fmaf(v, pr, re);
            im = fmaf(-v, pi, im);
            float nr = pr * cr - pi * sr;
            pi = fmaf(pr, sr, pi * cr);
            pr = nr;
        }
        Tre[h][cl] = re; Tim[h][cl] = im;
    }
    __syncthreads();
    if (tid < 144) {                  // (x 24, c 6)
        int xx = tid / 6, cl = tid - 6 * xx;
        int r = (xx < 12) ? xx : (xx + 40);
        float cr = cs[r], sr = sn[r];
        float pr = 1.f, pi = 0.f;     // (cos, sin)(2pi r h / 64)
        float re = 0.f, im = 0.f;
#pragma unroll 16
        for (int h = 0; h < 64; h++) {
            if (h == 32) {
                int k = (r * 32) & 63;
                pr = cs[k]; pi = sn[k];
            }
            float a = Tre[h][cl], bb = Tim[h][cl];
            re += a * pr + bb * pi;
            im += bb * pr - a * pi;
            float nr = pr * cr - pi * sr;
            pi = fmaf(pr, sr, pi * cr);
            pr = nr;
        }
        int m = xx * 12 + chalf * 6 + cl;
        Xh[((long)blk * 288 + m) * 2] = re;
        Xh[((long)blk * 288 + m) * 2 + 1] = im;
    }
}

// ---------------------------------------------------------------- mode-mix (v2, coalesced)
// Yhat[b,o,m] = sum_i Wc[i,o,m] * Xhat[b,i,m].  Block = (b,o) -> 128 blocks;
// lane = m. For fixed (i,o) the W offsets xw*24+y*2 are CONTIGUOUS over m
// (verified incl. xx boundaries) -> fully coalesced float2 loads; Xh likewise.
// Old layout had lanes at 1152B stride = 12.5% line utilization on 9.4MB/depth.
__global__ void __launch_bounds__(320) k_f2(const float* __restrict__ Xh, const float* __restrict__ s1,
                                            const float* __restrict__ s2, float* __restrict__ Yh) {
    int bo = blockIdx.x;             // b*64 + o
    int b = bo >> 6, o = bo & 63;
    int m = threadIdx.x;
    if (m >= 288) return;
    int xx = m / 12, y = m - 12 * xx;
    const float* W; int xw;
    if (xx < 12) { W = s1; xw = xx; } else { W = s2; xw = xx - 12; }
    long wbase = (long)o * 288 + xw * 24 + y * 2;
    const float* Xb = Xh + ((long)b * 64) * 576;      // 288 cplx = 576 floats per (b,i)
    float re = 0.f, im = 0.f;
    for (int i = 0; i < 64; i++) {
        float2 wv = *(const float2*)&W[(long)i * 18432 + wbase];
        float2 xv = *(const float2*)&Xb[(long)i * 576 + m * 2];
        re += xv.x * wv.x - xv.y * wv.y;
        im += xv.x * wv.y + xv.y * wv.x;
    }
    float* Yb = Yh + (((long)b * 64 + o) * 288 + m) * 2;
    Yb[0] = re; Yb[1] = im;
}

// inverse DFT + pointwise conv + bias + InstanceNorm + GELU, fused per (b, out-channel)
__global__ void __launch_bounds__(1024) k_f3(const float* __restrict__ Yh, const float* __restrict__ x,
                                             const float* __restrict__ pwW, const float* __restrict__ pwb,
                                             float* __restrict__ xo) {
    int blk = blockIdx.x;
    int b = blk >> 6, o = blk & 63;
    int tid = threadIdx.x;   // 1024; each thread owns 4 consecutive pixels
    __shared__ float yre[288], yim[288];
    __shared__ float Qre[64][12], Qim[64][12];
    __shared__ float cs[64], sn[64];
    __shared__ float red[16];
    if (tid < 64) {
        double a = (2.0 * PI_ / 64.0) * (double)tid;
        cs[tid] = (float)cos(a);
        sn[tid] = (float)sin(a);
    }
    if (tid < 288) {
        yre[tid] = Yh[((long)blk * 288 + tid) * 2];
        yim[tid] = Yh[((long)blk * 288 + tid) * 2 + 1];
    }
    __syncthreads();
    if (tid < 768) {    // (h, c): complex ifft along rows (1/64 scale)
        int h = tid / 12, c = tid - 12 * h;
        float re = 0.f, im = 0.f;
#pragma unroll
        for (int xx = 0; xx < 24; xx++) {
            int r = (xx < 12) ? xx : (xx + 40);
            int k = (r * h) & 63;
            float wr = cs[k], wi = sn[k];
            float a = yre[xx * 12 + c], bb = yim[xx * 12 + c];
            re += a * wr - bb * wi;
            im += a * wi + bb * wr;
        }
        Qre[h][c] = re * (1.0f / 64.0f);
        Qim[h][c] = im * (1.0f / 64.0f);
    }
    __syncthreads();
    float bias = pwb[o];
    int h = tid >> 4;
    int w0 = (tid & 15) * 4;
    float sp0, sp1, sp2, sp3;
    {
        float base = Qre[h][0];
        sp0 = sp1 = sp2 = sp3 = base;
#pragma unroll
        for (int c = 1; c < 12; c++) {
            float qr = Qre[h][c], qi = Qim[h][c];
            int k0 = (c * w0) & 63, k1 = (c * (w0 + 1)) & 63;
            int k2 = (c * (w0 + 2)) & 63, k3 = (c * (w0 + 3)) & 63;
            sp0 += 2.0f * (qr * cs[k0] - qi * sn[k0]);
            sp1 += 2.0f * (qr * cs[k1] - qi * sn[k1]);
            sp2 += 2.0f * (qr * cs[k2] - qi * sn[k2]);
            sp3 += 2.0f * (qr * cs[k3] - qi * sn[k3]);
        }
    }
    float a0 = sp0 * (1.0f / 64.0f) + bias;
    float a1 = sp1 * (1.0f / 64.0f) + bias;
    float a2 = sp2 * (1.0f / 64.0f) + bias;
    float a3 = sp3 * (1.0f / 64.0f) + bias;
    const float* xb = x + ((long)b * 64) * 4096 + tid * 4;
    for (int i = 0; i < 64; i++) {
        float wv = pwW[o * 64 + i];
        const float4 xv = *(const float4*)(xb + (long)i * 4096);
        a0 = fmaf(xv.x, wv, a0);
        a1 = fmaf(xv.y, wv, a1);
        a2 = fmaf(xv.z, wv, a2);
        a3 = fmaf(xv.w, wv, a3);
    }
    // block reduction: wave shfl-reduce + 16-partial sum (3 barriers vs 20)
    float ssum = a0 + a1 + a2 + a3;
#pragma unroll
    for (int m = 1; m < 64; m <<= 1) ssum += __shfl_xor(ssum, m, 64);
    if ((tid & 63) == 0) red[tid >> 6] = ssum;
    __syncthreads();
    float mu = 0.f;
#pragma unroll
    for (int k = 0; k < 16; k++) mu += red[k];
    mu *= (1.0f / 4096.0f);
    __syncthreads();
    float d0 = a0 - mu, d1 = a1 - mu, d2 = a2 - mu, d3 = a3 - mu;
    float sq = d0 * d0 + d1 * d1 + d2 * d2 + d3 * d3;
#pragma unroll
    for (int m = 1; m < 64; m <<= 1) sq += __shfl_xor(sq, m, 64);
    if ((tid & 63) == 0) red[tid >> 6] = sq;
    __syncthreads();
    float var = 0.f;
#pragma unroll
    for (int k = 0; k < 16; k++) var += red[k];
    var *= (1.0f / 4096.0f);
    float inv = 1.0f / sqrtf(var + 1e-5f);
    float4 ov = make_float4(gelu_f(d0 * inv), gelu_f(d1 * inv), gelu_f(d2 * inv), gelu_f(d3 * inv));
    *(float4*)&xo[(long)blk * 4096 + tid * 4] = ov;
}

// ---------------------------------------------------------------- projection MLP (64 -> 64 -> 3)
__global__ void __launch_bounds__(256) k_proj(
    const float* __restrict__ y, const float* __restrict__ W1, const float* __restrict__ b1,
    const float* __restrict__ W2, const float* __restrict__ b2, float* __restrict__ out) {
    __shared__ __align__(16) float yr[4][64];
    __shared__ float h[4][64];
    int ql = threadIdx.x >> 6, j = threadIdx.x & 63;
    long node = (long)blockIdx.x * 4 + ql;
    yr[ql][j] = y[node * 64 + j];
    __syncthreads();
    float a = b1[j];
    for (int k = 0; k < 64; k += 4) {
        float w0 = W1[(k + 0) * 64 + j], w1 = W1[(k + 1) * 64 + j];
        float w2 = W1[(k + 2) * 64 + j], w3 = W1[(k + 3) * 64 + j];
        const float4 hv = *(const float4*)&yr[ql][k];
        a = fmaf(hv.x, w0, fmaf(hv.y, w1, fmaf(hv.z, w2, fmaf(hv.w, w3, a))));
    }
    h[ql][j] = gelu_f(a);
    __syncthreads();
    if (j < 3) {
        float a2 = b2[j];
        for (int k = 0; k < 64; k++) a2 = fmaf(h[ql][k], W2[k * 3 + j], a2);
        out[node * 3 + j] = a2;
    }
}

// ---------------------------------------------------------------- launch
extern "C" void kernel_launch(void* const* d_in, const int* in_sizes, int n_in,
                              void* d_out, int out_size, void* d_ws, size_t ws_size,
                              hipStream_t stream) {
    (void)in_sizes; (void)n_in; (void)out_size; (void)ws_size;
    const float* coords   = (const float*)d_in[0];
    const float* features = (const float*)d_in[1];
    const float* lift_W1 = (const float*)d_in[2];
    const float* lift_b1 = (const float*)d_in[3];
    const float* lift_W2 = (const float*)d_in[4];
    const float* lift_b2 = (const float*)d_in[5];
    const float* gin_W1 = (const float*)d_in[6];
    const float* gin_b1 = (const float*)d_in[7];
    const float* gin_W2 = (const float*)d_in[8];
    const float* gin_b2 = (const float*)d_in[9];
    const float* gin_W3 = (const float*)d_in[10];
    const float* gin_b3 = (const float*)d_in[11];
    const float* spec1 = (const float*)d_in[12];
    const float* spec2 = (const float*)d_in[13];
    const float* pw_W  = (const float*)d_in[14];
    const float* pw_b  = (const float*)d_in[15];
    const float* gout_W1 = (const float*)d_in[16];
    const float* gout_b1 = (const float*)d_in[17];
    const float* gout_W2 = (const float*)d_in[18];
    const float* gout_b2 = (const float*)d_in[19];
    const float* gout_W3 = (const float*)d_in[20];
    const float* gout_b3 = (const float*)d_in[21];
    const float* proj_W1 = (const float*)d_in[22];
    const float* proj_b1 = (const float*)d_in[23];
    const float* proj_W2 = (const float*)d_in[24];
    const float* proj_b2 = (const float*)d_in[25];

    char* ws = (char*)d_ws;
    size_t off = 0;
    auto alloc = [&](size_t bytes) -> char* {
        char* p = ws + off;
        off = (off + bytes + 255) & ~(size_t)255;
        return p;
    };
    float4* grid_pack = (float4*)alloc((size_t)NG * 16);
    float*  feat      = (float*)alloc((size_t)B_ * N_ * 64 * 4);
    int*    bin_cnt   = (int*)alloc((size_t)B_ * 4096 * 4);
    int*    bin_fill  = (int*)alloc((size_t)B_ * 4096 * 4);   // contiguous after bin_cnt
    int*    bin_off   = (int*)alloc((size_t)B_ * 4097 * 4);
    float4* srt       = (float4*)alloc((size_t)B_ * N_ * 16);
    int*    idx_in    = (int*)alloc((size_t)B_ * NG * 16 * 4);
    float*  dist_in   = (float*)alloc((size_t)B_ * NG * 16 * 4);
    float*  lastd_in  = (float*)alloc((size_t)B_ * NG * 4);
    float*  sig_in    = (float*)alloc(256);
    float*  xb0       = (float*)alloc((size_t)B_ * 64 * NG * 4);
    float*  xb1       = (float*)alloc((size_t)B_ * 64 * NG * 4);
    float*  Xh        = (float*)alloc((size_t)B_ * 64 * 288 * 2 * 4);
    float*  Yh        = (float*)alloc((size_t)B_ * 64 * 288 * 2 * 4);
    float*  g2        = (float*)alloc((size_t)B_ * NG * 64 * 4);
    int*    idx_out   = (int*)alloc((size_t)B_ * N_ * 16 * 4);
    float*  dist_out  = (float*)alloc((size_t)B_ * N_ * 16 * 4);
    float*  lastd_out = (float*)alloc((size_t)B_ * N_ * 4);
    float*  sig_out   = (float*)alloc(256);
    float*  ybuf      = (float*)alloc((size_t)B_ * N_ * 64 * 4);
    short*  wb_in     = (short*)alloc((size_t)52 * 1024);   // 52 x 1KB bf16 hi/lo fragments
    short*  wb_out    = (short*)alloc((size_t)52 * 1024);

    // bin_cnt and bin_fill are contiguous 256B-aligned blocks: one memset
    hipMemsetAsync(bin_cnt, 0, (size_t)B_ * 4096 * 4 * 2, stream);

    k_wcvt<<<26, 256, 0, stream>>>(gin_W1, gin_W2, gin_W3, wb_in,
                                   gout_W1, gout_W2, gout_W3, wb_out);
    k_lift<<<(B_ * N_) / 4, 256, 0, stream>>>(features, lift_W1, lift_b1, lift_W2, lift_b2, feat);
    k_bincount<<<(B_ * N_) / 256, 256, 0, stream>>>((const float2*)coords, bin_cnt, grid_pack);
    k_binscan<<<B_, 1024, 0, stream>>>(bin_cnt, bin_off);
    k_binscatter<<<(B_ * N_) / 256, 256, 0, stream>>>((const float2*)coords, bin_off, bin_fill, srt);
    k_knn_in<<<(B_ * NG * 64) / 256, 256, 0, stream>>>(grid_pack, srt, bin_off, idx_in, dist_in, lastd_in);
    k_median_bis<<<1, 1024, 0, stream>>>(lastd_in, B_ * NG, sig_in);
    k_edge_mfma<0><<<(B_ * NG) / 4, 128, 0, stream>>>(idx_in, dist_in, sig_in,
        (const float2*)coords, grid_pack, feat, wb_in,
        gin_b1, gin_b2, gin_b3, xb0);
    float* xc = xb0; float* xn = xb1;
    for (int d = 0; d < 3; d++) {
        k_f1<<<B_ * 64 * 2, 384, 0, stream>>>(xc, Xh);
        k_f2<<<B_ * 64, 320, 0, stream>>>(Xh, spec1 + (size_t)d * 1179648, spec2 + (size_t)d * 1179648, Yh);
        k_f3<<<B_ * 64, 1024, 0, stream>>>(Yh, xc, pw_W + (size_t)d * 4096, pw_b + (size_t)d * 64, xn);
        float* tmp = xc; xc = xn; xn = tmp;
    }
    {
        dim3 g(NG / 32, 64 / 32, B_); dim3 t(32, 8);
        k_transp<<<g, t, 0, stream>>>(xc, g2, 64, NG);
    }
    k_knn_out<<<(B_ * N_ * 64) / 256, 256, 0, stream>>>((const float2*)coords, grid_pack, idx_out, dist_out, lastd_out);
    k_median_bis<<<1, 1024, 0, stream>>>(lastd_out, B_ * N_, sig_out);
    k_edge_mfma<1><<<(B_ * N_) / 4, 128, 0, stream>>>(idx_out, dist_out, sig_out,
        (const float2*)coords, grid_pack, g2, wb_out,
        gout_b1, gout_b2, gout_b3, ybuf);
    k_proj<<<(B_ * N_) / 4, 256, 0, stream>>>(ybuf, proj_W1, proj_b1, proj_W2, proj_b2, (float*)d_out);
}

// Round 7
// 362.991 us; speedup vs baseline: 1.5190x; 1.1124x over previous
//
#include <hip/hip_runtime.h>
#include <math.h>

#define B_ 2
#define N_ 8192          // points per batch
#define G_ 64
#define NG 4096          // G*G latent grid points
#define WID_ 64
#define K_ 16
#define CIN_ 6
#define COUT_ 3
#define PI_ 3.14159265358979323846

typedef unsigned long long u64k;
typedef __attribute__((ext_vector_type(8))) short bf16x8;   // 8 bf16 bit-patterns (4 VGPR)
typedef __attribute__((ext_vector_type(16))) float f32x16;  // 32x32 MFMA acc

// ---------------------------------------------------------------- helpers
// exact-erf GELU via Abramowitz-Stegun 7.1.26 (|eps_erf| <= 1.5e-7), branchless.
__device__ __forceinline__ float gelu_f(float x) {
    float u = fabsf(x) * 0.70710678118654752440f;
    float t = __builtin_amdgcn_rcpf(fmaf(0.3275911f, u, 1.0f));
    float p = fmaf(fmaf(fmaf(fmaf(1.061405429f, t, -1.453152027f), t, 1.421413741f),
                        t, -0.284496736f), t, 0.254829592f) * t;
    float e = __expf(-u * u);
    float erfc_u = p * e;                               // erfc(u), u >= 0
    float phi = (x >= 0.f) ? fmaf(-0.5f, erfc_u, 1.0f) : (0.5f * erfc_u);
    return x * phi;
}
__device__ __forceinline__ int cellof(float v) {
    int c = (int)floorf((v + 1.0f) * 32.0f);
    return min(63, max(0, c));
}
__device__ __forceinline__ u64k umin64(u64k a, u64k b) { return a < b ? a : b; }
__device__ __forceinline__ u64k umax64(u64k a, u64k b) { return a < b ? b : a; }
__device__ __forceinline__ u64k shflxor64(u64k v, int m) {
    return (u64k)__shfl_xor((long long)v, m, 64);
}
__device__ __forceinline__ void bsort64(u64k& key, int lane) {
#pragma unroll
    for (int sz = 2; sz <= 64; sz <<= 1) {
#pragma unroll
        for (int j = sz >> 1; j >= 1; j >>= 1) {
            u64k o = shflxor64(key, j);
            bool keep_min = ((lane & j) == 0) == ((lane & sz) == 0);
            key = keep_min ? umin64(key, o) : umax64(key, o);
        }
    }
}
__device__ __forceinline__ void bmerge_into(u64k& R, u64k key, int lane) {
    u64k o = shflxor64(key, 63);
    u64k L = umin64(R, o);
#pragma unroll
    for (int j = 32; j >= 1; j >>= 1) {
        u64k t = shflxor64(L, j);
        L = ((lane & j) == 0) ? umin64(L, t) : umax64(L, t);
    }
    R = L;
}
// split fp32 -> bf16 hi (round-half-up, 0.5-ulp) + bf16 lo (truncated residual)
__device__ __forceinline__ void cvt8v(float4 a, float4 b, bf16x8& hv, bf16x8& lv) {
    float v[8] = {a.x, a.y, a.z, a.w, b.x, b.y, b.z, b.w};
#pragma unroll
    for (int i = 0; i < 8; i++) {
        unsigned u = __float_as_uint(v[i]);
        unsigned r = (u + 0x8000u) & 0xffff0000u;
        hv[i] = (short)(r >> 16);
        float lo = v[i] - __uint_as_float(r);
        lv[i] = (short)(__float_as_uint(lo) >> 16);
    }
}
__device__ __forceinline__ bf16x8 ldfrag(const short* __restrict__ WB, int f, int lane) {
    return *(const bf16x8*)(WB + ((long)f * 64 + lane) * 8);
}
struct Frag4 { bf16x8 h0, l0, h1, l1; };
// base/nk select layer: L1 base=0 nk=5, L2 base=20 nk=4, L3 base=36 nk=4
__device__ __forceinline__ Frag4 ldfrag4(const short* __restrict__ WB, int base, int nk,
                                         int kc, int lane) {
    Frag4 f;
    f.h0 = ldfrag(WB, base + (0 * nk + kc) * 2 + 0, lane);
    f.l0 = ldfrag(WB, base + (0 * nk + kc) * 2 + 1, lane);
    f.h1 = ldfrag(WB, base + (1 * nk + kc) * 2 + 0, lane);
    f.l1 = ldfrag(WB, base + (1 * nk + kc) * 2 + 1, lane);
    return f;
}

// ---------------------------------------------------------------- prep mega-kernel
// Fuses 4 independent preprocessing stages by block section (saves 3 dispatches
// + the hipMemsetAsync dispatch; bodies verbatim from the split kernels):
//   blocks [0,4096)      : lift MLP (features -> feat), 4 nodes/block
//   blocks [4096,4122)   : weight split/pack (both gin & gout sets)
//   blocks [4122,4138)   : latent grid gen (numpy linspace semantics)
//   blocks [4138,4202)   : zero bin_cnt + bin_fill (16384 ints contiguous)
__global__ void __launch_bounds__(256) k_prep(
    const float* __restrict__ fin, const float* __restrict__ lW1,
    const float* __restrict__ lb1, const float* __restrict__ lW2,
    const float* __restrict__ lb2, float* __restrict__ fout,
    const float* __restrict__ W1a, const float* __restrict__ W2a,
    const float* __restrict__ W3a, short* __restrict__ WBa,
    const float* __restrict__ W1b, const float* __restrict__ W2b,
    const float* __restrict__ W3b, short* __restrict__ WBb,
    float4* __restrict__ gp, int* __restrict__ bins) {
    __shared__ float xr[4][8];
    __shared__ __align__(16) float h[4][64];
    int blk = blockIdx.x;
    if (blk < 4096) {                       // ---- lift
        int ql = threadIdx.x >> 6, j = threadIdx.x & 63;
        int node = blk * 4 + ql;
        if (j < CIN_) xr[ql][j] = fin[node * CIN_ + j];
        __syncthreads();
        float a = lb1[j];
#pragma unroll
        for (int i = 0; i < CIN_; i++) a = fmaf(xr[ql][i], lW1[i * 64 + j], a);
        h[ql][j] = gelu_f(a);
        __syncthreads();
        float a2 = lb2[j];
        for (int k = 0; k < 64; k += 4) {
            float w0 = lW2[(k + 0) * 64 + j], w1 = lW2[(k + 1) * 64 + j];
            float w2 = lW2[(k + 2) * 64 + j], w3 = lW2[(k + 3) * 64 + j];
            const float4 hv = *(const float4*)&h[ql][k];
            a2 = fmaf(hv.x, w0, fmaf(hv.y, w1, fmaf(hv.z, w2, fmaf(hv.w, w3, a2))));
        }
        fout[node * 64 + j] = a2;
    } else if (blk < 4122) {                // ---- wcvt (both sets)
        int t = (blk - 4096) * 256 + threadIdx.x;
        if (t >= 6656) return;
        int setb = (t >= 3328);
        int tt = t - (setb ? 3328 : 0);
        const float* W1s = setb ? W1b : W1a;
        const float* W2s = setb ? W2b : W2a;
        const float* W3s = setb ? W3b : W3a;
        short* WB = setb ? WBb : WBa;
        int f = tt >> 6, lane = tt & 63;
        const float* W; int hh, nt, kc, l1 = 0;
        if (f < 20)      { W = W1s; int r = f;      hh = r & 1; r >>= 1; nt = r / 5; kc = r % 5; l1 = 1; }
        else if (f < 36) { W = W2s; int r = f - 20; hh = r & 1; r >>= 1; nt = r / 4; kc = r % 4; }
        else             { W = W3s; int r = f - 36; hh = r & 1; r >>= 1; nt = r / 4; kc = r % 4; }
        int col = nt * 32 + (lane & 31);
        bf16x8 out;
#pragma unroll
        for (int i = 0; i < 8; i++) {
            int k = kc * 16 + (lane >> 5) * 8 + i;
            float w = 0.f;
            if (l1) {
                if (k < 7) w = W[k * 64 + col];
                else if (k >= 8 && k < 72) w = W[(k - 1) * 64 + col];
            } else {
                w = W[k * 64 + col];
            }
            unsigned u = __float_as_uint(w);
            unsigned hi = (u + 0x7fffu + ((u >> 16) & 1u)) & 0xffff0000u;
            float lo = w - __uint_as_float(hi);
            unsigned ul = __float_as_uint(lo);
            unsigned lr = ul + 0x7fffu + ((ul >> 16) & 1u);
            out[i] = hh ? (short)(lr >> 16) : (short)(hi >> 16);
        }
        *(bf16x8*)(WB + ((long)f * 64 + lane) * 8) = out;
    } else if (blk < 4138) {                // ---- grid gen
        int t = (blk - 4122) * 256 + threadIdx.x;    // 0..4095
        int i = t >> 6, j = t & 63;
        double st = 2.0 / 63.0;
        float gx = (i == 63) ? 1.0f : (float)(-1.0 + st * (double)i);
        float gy = (j == 63) ? 1.0f : (float)(-1.0 + st * (double)j);
        float s2 = __fadd_rn(__fmul_rn(gx, gx), __fmul_rn(gy, gy));
        gp[t] = make_float4(gx, gy, s2, 0.f);
    } else {                                // ---- zero bins (cnt+fill contiguous)
        int t = (blk - 4138) * 256 + threadIdx.x;    // 0..16383
        bins[t] = 0;
    }
}

// ---------------------------------------------------------------- binning
__global__ void k_bincount(const float2* __restrict__ coords, int* __restrict__ cnt) {
    int t = blockIdx.x * blockDim.x + threadIdx.x;
    if (t >= B_ * N_) return;
    float2 c = coords[t];
    int b = t >> 13;
    int cell = cellof(c.x) * 64 + cellof(c.y);
    atomicAdd(&cnt[b * 4096 + cell], 1);
}
// wave shfl_up scan + 16-partial combine -> 1 barrier
__global__ void k_binscan(const int* __restrict__ cnt, int* __restrict__ offs) {
    int b = blockIdx.x, t = threadIdx.x;    // 1024 threads
    __shared__ int part[16];
    int4 v = ((const int4*)(cnt + b * 4096))[t];
    int sum = v.x + v.y + v.z + v.w;
    int lane = t & 63, wv = t >> 6;
    int ws = sum;
#pragma unroll
    for (int o = 1; o < 64; o <<= 1) {
        int u = __shfl_up(ws, o, 64);
        if (lane >= o) ws += u;
    }
    if (lane == 63) part[wv] = ws;
    __syncthreads();
    int base = 0;
#pragma unroll
    for (int k = 0; k < 16; k++) base += (k < wv) ? part[k] : 0;
    int incl = base + ws, excl = incl - sum;
    int* ob = offs + b * 4097;
    ob[4 * t] = excl; ob[4 * t + 1] = excl + v.x;
    ob[4 * t + 2] = excl + v.x + v.y; ob[4 * t + 3] = excl + v.x + v.y + v.z;
    if (t == 1023) ob[4096] = incl;
}
__global__ void k_binscatter(const float2* __restrict__ coords, const int* __restrict__ offs,
                             int* __restrict__ fill, float4* __restrict__ srt) {
    int t = blockIdx.x * blockDim.x + threadIdx.x;
    if (t >= B_ * N_) return;
    float2 c = coords[t];
    int b = t >> 13, n = t & 8191;
    int cell = cellof(c.x) * 64 + cellof(c.y);
    int pos = offs[b * 4097 + cell] + atomicAdd(&fill[b * 4096 + cell], 1);
    float s2 = __fadd_rn(__fmul_rn(c.x, c.x), __fmul_rn(c.y, c.y));
    srt[b * N_ + pos] = make_float4(c.x, c.y, s2, __int_as_float(n));
}

// ---------------------------------------------------------------- fused kNN (both directions)
// blocks [0,2048): grid->points search (one wave per grid query, cell expansion)
// blocks [2048,6144): points->grid (one wave per point, fixed 8x8 window + bsort)
// Independent sections; fusing lets knn_out's light waves backfill CUs while
// knn_in's long searches straggle. Bodies verbatim.
__global__ void __launch_bounds__(256) k_knn(
    const float4* __restrict__ gp, const float4* __restrict__ srt,
    const int* __restrict__ offs, const float2* __restrict__ coords,
    int* __restrict__ oidx_in, float* __restrict__ odist_in, float* __restrict__ lastd_in,
    int* __restrict__ oidx_out, float* __restrict__ odist_out, float* __restrict__ lastd_out) {
    int lane = threadIdx.x & 63;
    if (blockIdx.x < 2048) {
        int w = (blockIdx.x * blockDim.x + threadIdx.x) >> 6;
        int b = w >> 12, p = w & 4095;
        float4 q = gp[p];
        float qx = q.x, qy = q.y, q2 = q.z;
        int cqx = cellof(qx), cqy = cellof(qy);
        const float4* S = srt + b * N_;
        const int* OF = offs + b * 4097;

        u64k R = ~0ull;
        u64k pend = ~0ull;
        int fill = 0;

        auto flush = [&]() {
            bsort64(pend, lane);
            bmerge_into(R, pend, lane);
            pend = ~0ull;
            fill = 0;
        };
        auto feed = [&](int s0, int s1) {
            int cnt = s1 - s0;
            while (cnt > 0) {
                int take = min(cnt, 64 - fill);
                int t = lane - fill;
                if (t >= 0 && t < take) {
                    float4 sp = S[s0 + t];
                    float dot = __fadd_rn(__fmul_rn(qx, sp.x), __fmul_rn(qy, sp.y));
                    float d2 = __fsub_rn(__fadd_rn(q2, sp.z), 2.0f * dot);
                    d2 = fmaxf(d2, 0.0f);
                    pend = ((u64k)__float_as_uint(d2) << 32) | (unsigned)__float_as_int(sp.w);
                }
                fill += take; s0 += take; cnt -= take;
                if (fill == 64) flush();
            }
        };

        {
            int xa = max(cqx - 2, 0), xb = min(cqx + 2, 63);
            int ya = max(cqy - 2, 0), yb = min(cqy + 2, 63);
            for (int cx = xa; cx <= xb; cx++) feed(OF[cx * 64 + ya], OF[cx * 64 + yb + 1]);
        }
        int r = 2;
        while (true) {
            if (fill) flush();
            u64k T = (u64k)__shfl((long long)R, 15, 64);
            float d16 = __uint_as_float((unsigned)(T >> 32));
            float bm = (float)r * 0.03125f;
            if (d16 < bm * bm - 1e-5f) break;
            if (cqx - r <= 0 && cqx + r >= 63 && cqy - r <= 0 && cqy + r >= 63) break;
            r++;
            int ya = max(cqy - r, 0), yb = min(cqy + r, 63);
            if (cqx - r >= 0)  { int c0 = (cqx - r) * 64; feed(OF[c0 + ya], OF[c0 + yb + 1]); }
            if (cqx + r <= 63) { int c0 = (cqx + r) * 64; feed(OF[c0 + ya], OF[c0 + yb + 1]); }
            int xa2 = max(cqx - r + 1, 0), xb2 = min(cqx + r - 1, 63);
            for (int cx = xa2; cx <= xb2; cx++) {
                if (cqy - r >= 0)  { int cc = cx * 64 + cqy - r; feed(OF[cc], OF[cc + 1]); }
                if (cqy + r <= 63) { int cc = cx * 64 + cqy + r; feed(OF[cc], OF[cc + 1]); }
            }
        }
        if (lane < 16) {
            float d2 = __uint_as_float((unsigned)(R >> 32));
            float d = sqrtf(d2);
            oidx_in[w * 16 + lane] = (int)(unsigned)(R & 0xffffffffu);
            odist_in[w * 16 + lane] = d;
            if (lane == 15) lastd_in[w] = d;
        }
    } else {
        int w = ((blockIdx.x - 2048) * blockDim.x + threadIdx.x) >> 6;
        float2 c = coords[w];
        float qx = c.x, qy = c.y;
        float q2 = __fadd_rn(__fmul_rn(qx, qx), __fmul_rn(qy, qy));
        int i0 = (int)floorf((qx + 1.0f) * 31.5f);
        int j0 = (int)floorf((qy + 1.0f) * 31.5f);
        int li = min(max(i0 - 3, 0), 56);
        int lj = min(max(j0 - 3, 0), 56);
        int p = (li + (lane >> 3)) * 64 + (lj + (lane & 7));
        float4 sp = gp[p];
        float dot = __fadd_rn(__fmul_rn(qx, sp.x), __fmul_rn(qy, sp.y));
        float d2 = fmaxf(__fsub_rn(__fadd_rn(q2, sp.z), 2.0f * dot), 0.0f);
        u64k key = ((u64k)__float_as_uint(d2) << 32) | (unsigned)p;
        bsort64(key, lane);
        if (lane < 16) {
            float dd = sqrtf(__uint_as_float((unsigned)(key >> 32)));
            oidx_out[w * 16 + lane] = (int)(unsigned)(key & 0xffffffffu);
            odist_out[w * 16 + lane] = dd;
            if (lane == 15) lastd_out[w] = dd;
        }
    }
}

// ---------------------------------------------------------------- both medians, one launch
// block 0: lower-median of lastd_in (n=8192) -> sig_in; block 1: lastd_out
// (n=16384) -> sig_out. The two single-block bisections run CONCURRENTLY
// (wall = max not sum). Body verbatim from k_median_bis.
__global__ void __launch_bounds__(1024) k_median2(
    const float* __restrict__ vin, const float* __restrict__ vout,
    float* __restrict__ sig_in, float* __restrict__ sig_out) {
    const float* vals = blockIdx.x ? vout : vin;
    int n = blockIdx.x ? (B_ * N_) : (B_ * NG);
    float* sig = blockIdx.x ? sig_out : sig_in;
    __shared__ int wred[2][16];
    int tid = threadIdx.x;
    int lane = tid & 63, wv = tid >> 6;
    int cnt_per = n >> 10;           // 8 or 16
    unsigned v[16];
    for (int i = 0; i < cnt_per; i++) v[i] = __float_as_uint(vals[tid + (i << 10)]);
    int r = (n - 1) >> 1;
    unsigned prefix = 0;
    for (int bit = 31; bit >= 0; bit--) {
        unsigned cand = prefix | (1u << bit);
        int c = 0;
        for (int i = 0; i < cnt_per; i++) c += (v[i] < cand) ? 1 : 0;
        for (int o = 32; o >= 1; o >>= 1) c += __shfl_down(c, o, 64);
        int buf = bit & 1;
        if (lane == 0) wred[buf][wv] = c;
        __syncthreads();
        int tot = 0;
#pragma unroll
        for (int k = 0; k < 16; k++) tot += wred[buf][k];
        prefix = (tot <= r) ? cand : prefix;
    }
    if (tid == 0) *sig = fmaxf(__uint_as_float(prefix), 1e-6f);
}

// ---------------------------------------------------------------- edge MLP via split-bf16 MFMA (v5, stable)
// Plateaued at ~43-44us over v3/v4/v5: occupancy pinned at 4 waves/SIMD by the
// unified VGPR+AGPR budget (32-reg acc counts); VALU cuts neutral. Left as-is.
// C/D layout (HW-verified): col = lane&31, row = (reg&3) + 8*(reg>>2) + 4*(lane>>5).
template <int MODE>
__global__ void __launch_bounds__(128, 4) k_edge_mfma(
    const int* __restrict__ idxb, const float* __restrict__ distb,
    const float* __restrict__ sigp,
    const float2* __restrict__ coords, const float4* __restrict__ gp,
    const float* __restrict__ feats, const short* __restrict__ WB,
    const float* __restrict__ b1, const float* __restrict__ b2,
    const float* __restrict__ b3,
    float* __restrict__ outb) {
    constexpr int QSH  = (MODE == 0) ? 12 : 13;     // log2(Nq)
    constexpr int QMSK = (MODE == 0) ? 4095 : 8191;
    constexpr long SR  = (MODE == 0) ? 8192 : 4096; // srcRows
    __shared__ float X[2][2432];           // per wave: 32 rows x 76 floats
    const int tid = threadIdx.x, wv = tid >> 6, lane = tid & 63;
    const int r31 = lane & 31, g = lane >> 5;
    const int qbase = (blockIdx.x * 2 + wv) * 2;
    const float sig = *sigp;
    float* X_ = X[wv];

    // issue first B-fragment load immediately: in flight during staging
    Frag4 cur = ldfrag4(WB, 0, 5, 0, lane);

    // ---- staging: 32 (query,edge) rows by lanes 0..31
    int si = 0; float wt = 0.f;
    if (lane < 32) {
        int q = lane >> 4, e = lane & 15;
        int gq = qbase + q;
        int b = gq >> QSH, p = gq & QMSK;
        si = idxb[gq * 16 + e];
        float d = distb[gq * 16 + e];
        wt = __expf(-d / sig);
        float qx, qy, sx, sy;
        if (MODE == 0) {
            float4 gv = gp[p]; qx = gv.x; qy = gv.y;
            float2 cc = coords[(long)b * SR + si]; sx = cc.x; sy = cc.y;
        } else {
            float2 cc = coords[gq]; qx = cc.x; qy = cc.y;   // b*Nq + p == gq
            float4 gv = gp[si]; sx = gv.x; sy = gv.y;
        }
        float* row = X_ + lane * 76;
        *(float4*)row       = make_float4(qx, qy, sx, sy);
        *(float4*)(row + 4) = make_float4(qx - sx, qy - sy, d, 0.f);
    }
    // per-query weight sums (within each 16-lane group)
    float swt = wt;
#pragma unroll
    for (int m = 1; m < 16; m <<= 1) swt += __shfl_xor(swt, m, 64);
    // ---- feats gather: 32 rows x 16 float4; batch loads -> regs, then write
    {
        float4 fv[8];
#pragma unroll
        for (int it = 0; it < 8; it++) {
            int slot = it * 64 + lane;
            int row = slot >> 4, f4 = slot & 15;
            int gq = qbase + (row >> 4);
            int b = gq >> QSH;
            int sr = __shfl(si, row, 64);
            fv[it] = *(const float4*)&feats[((long)b * SR + sr) * 64 + f4 * 4];
        }
#pragma unroll
        for (int it = 0; it < 8; it++) {
            int slot = it * 64 + lane;
            int row = slot >> 4, f4 = slot & 15;
            *(float4*)&X_[row * 76 + 8 + f4 * 4] = fv[it];
        }
    }

    f32x16 acc0, acc1;
    float4 xa, xb;
    // ---------- layer 1: K = 71 (+pad), kc 0..4; kc=4 upper half is A=0
    {
        float bb0 = b1[r31], bb1 = b1[32 + r31];
#pragma unroll
        for (int i = 0; i < 16; i++) { acc0[i] = bb0; acc1[i] = bb1; }
        {
            const float* xp = &X_[r31 * 76 + g * 8];
            xa = *(const float4*)xp; xb = *(const float4*)(xp + 4);
        }
#pragma unroll
        for (int kc = 0; kc < 5; kc++) {
            Frag4 nxt = (kc < 4) ? ldfrag4(WB, 0, 5, kc + 1, lane)
                                 : ldfrag4(WB, 20, 4, 0, lane);   // layer-2 kc0
            bf16x8 ah, al;
            if (kc == 4 && g) {
#pragma unroll
                for (int i = 0; i < 8; i++) { ah[i] = 0; al[i] = 0; }
            } else {
                cvt8v(xa, xb, ah, al);
            }
            // prefetch next-kc A pair (skip kc=3,g=1: that is the zero pad region)
            if (kc < 4 && (kc != 3 || g == 0)) {
                const float* xp = &X_[r31 * 76 + (kc + 1) * 16 + g * 8];
                xa = *(const float4*)xp; xb = *(const float4*)(xp + 4);
            }
            __builtin_amdgcn_s_setprio(1);
            acc0 = __builtin_amdgcn_mfma_f32_32x32x16_bf16(ah, cur.h0, acc0, 0, 0, 0);
            acc1 = __builtin_amdgcn_mfma_f32_32x32x16_bf16(ah, cur.h1, acc1, 0, 0, 0);
            acc0 = __builtin_amdgcn_mfma_f32_32x32x16_bf16(al, cur.h0, acc0, 0, 0, 0);
            acc1 = __builtin_amdgcn_mfma_f32_32x32x16_bf16(al, cur.h1, acc1, 0, 0, 0);
            acc0 = __builtin_amdgcn_mfma_f32_32x32x16_bf16(ah, cur.l0, acc0, 0, 0, 0);
            acc1 = __builtin_amdgcn_mfma_f32_32x32x16_bf16(ah, cur.l1, acc1, 0, 0, 0);
            __builtin_amdgcn_s_setprio(0);
            cur = nxt;
        }
    }
    // h = gelu(acc) -> LDS (overwrites x slots 0..63; all layer-1 reads done)
#pragma unroll
    for (int reg = 0; reg < 16; reg++) {
        int row = (reg & 3) + 8 * (reg >> 2) + 4 * g;
        X_[row * 76 + r31]      = gelu_f(acc0[reg]);
        X_[row * 76 + 32 + r31] = gelu_f(acc1[reg]);
    }
    // ---------- layer 2
    {
        float bb0 = b2[r31], bb1 = b2[32 + r31];
#pragma unroll
        for (int i = 0; i < 16; i++) { acc0[i] = bb0; acc1[i] = bb1; }
        {
            const float* xp = &X_[r31 * 76 + g * 8];
            xa = *(const float4*)xp; xb = *(const float4*)(xp + 4);
        }
#pragma unroll
        for (int kc = 0; kc < 4; kc++) {
            Frag4 nxt = (kc < 3) ? ldfrag4(WB, 20, 4, kc + 1, lane)
                                 : ldfrag4(WB, 36, 4, 0, lane);   // layer-3 kc0
            bf16x8 ah, al;
            cvt8v(xa, xb, ah, al);
            if (kc < 3) {
                const float* xp = &X_[r31 * 76 + (kc + 1) * 16 + g * 8];
                xa = *(const float4*)xp; xb = *(const float4*)(xp + 4);
            }
            __builtin_amdgcn_s_setprio(1);
            acc0 = __builtin_amdgcn_mfma_f32_32x32x16_bf16(ah, cur.h0, acc0, 0, 0, 0);
            acc1 = __builtin_amdgcn_mfma_f32_32x32x16_bf16(ah, cur.h1, acc1, 0, 0, 0);
            acc0 = __builtin_amdgcn_mfma_f32_32x32x16_bf16(al, cur.h0, acc0, 0, 0, 0);
            acc1 = __builtin_amdgcn_mfma_f32_32x32x16_bf16(al, cur.h1, acc1, 0, 0, 0);
            acc0 = __builtin_amdgcn_mfma_f32_32x32x16_bf16(ah, cur.l0, acc0, 0, 0, 0);
            acc1 = __builtin_amdgcn_mfma_f32_32x32x16_bf16(ah, cur.l1, acc1, 0, 0, 0);
            __builtin_amdgcn_s_setprio(0);
            cur = nxt;
        }
    }
#pragma unroll
    for (int reg = 0; reg < 16; reg++) {
        int row = (reg & 3) + 8 * (reg >> 2) + 4 * g;
        X_[row * 76 + r31]      = gelu_f(acc0[reg]);
        X_[row * 76 + 32 + r31] = gelu_f(acc1[reg]);
    }
    // ---------- layer 3 (no activation)
    {
        float bb0 = b3[r31], bb1 = b3[32 + r31];
#pragma unroll
        for (int i = 0; i < 16; i++) { acc0[i] = bb0; acc1[i] = bb1; }
        {
            const float* xp = &X_[r31 * 76 + g * 8];
            xa = *(const float4*)xp; xb = *(const float4*)(xp + 4);
        }
#pragma unroll
        for (int kc = 0; kc < 4; kc++) {
            Frag4 nxt = cur;
            if (kc < 3) nxt = ldfrag4(WB, 36, 4, kc + 1, lane);
            bf16x8 ah, al;
            cvt8v(xa, xb, ah, al);
            if (kc < 3) {
                const float* xp = &X_[r31 * 76 + (kc + 1) * 16 + g * 8];
                xa = *(const float4*)xp; xb = *(const float4*)(xp + 4);
            }
            __builtin_amdgcn_s_setprio(1);
            acc0 = __builtin_amdgcn_mfma_f32_32x32x16_bf16(ah, cur.h0, acc0, 0, 0, 0);
            acc1 = __builtin_amdgcn_mfma_f32_32x32x16_bf16(ah, cur.h1, acc1, 0, 0, 0);
            acc0 = __builtin_amdgcn_mfma_f32_32x32x16_bf16(al, cur.h0, acc0, 0, 0, 0);
            acc1 = __builtin_amdgcn_mfma_f32_32x32x16_bf16(al, cur.h1, acc1, 0, 0, 0);
            acc0 = __builtin_amdgcn_mfma_f32_32x32x16_bf16(ah, cur.l0, acc0, 0, 0, 0);
            acc1 = __builtin_amdgcn_mfma_f32_32x32x16_bf16(ah, cur.l1, acc1, 0, 0, 0);
            __builtin_amdgcn_s_setprio(0);
            cur = nxt;
        }
    }
    // ---------- weighted aggregation over edges (rows) + output
    float wtv[16];
#pragma unroll
    for (int reg = 0; reg < 16; reg++)
        wtv[reg] = __shfl(wt, (reg & 3) + 8 * (reg >> 2) + 4 * g, 64);
    float s00 = 0.f, s01 = 0.f, s10 = 0.f, s11 = 0.f;   // s<query><ntile>
#pragma unroll
    for (int reg = 0; reg < 16; reg++) {
        if (reg < 8) { s00 = fmaf(wtv[reg], acc0[reg], s00); s01 = fmaf(wtv[reg], acc1[reg], s01); }
        else         { s10 = fmaf(wtv[reg], acc0[reg], s10); s11 = fmaf(wtv[reg], acc1[reg], s11); }
    }
    s00 += __shfl_xor(s00, 32, 64);
    s01 += __shfl_xor(s01, 32, 64);
    s10 += __shfl_xor(s10, 32, 64);
    s11 += __shfl_xor(s11, 32, 64);
    float sw0 = __shfl(swt, 0, 64), sw1 = __shfl(swt, 16, 64);
    if (g == 0) {
        float i0 = 1.0f / fmaxf(sw0, 1e-6f), i1 = 1.0f / fmaxf(sw1, 1e-6f);
        int gq0 = qbase, gq1 = qbase + 1;
        if (MODE == 0) {
            int b0 = gq0 >> QSH, p0 = gq0 & QMSK;
            int b1i = gq1 >> QSH, p1 = gq1 & QMSK;
            outb[((long)b0 * 64 + r31) * 4096 + p0]        = s00 * i0;   // transposed (b, col, p)
            outb[((long)b0 * 64 + 32 + r31) * 4096 + p0]   = s01 * i0;
            outb[((long)b1i * 64 + r31) * 4096 + p1]       = s10 * i1;
            outb[((long)b1i * 64 + 32 + r31) * 4096 + p1]  = s11 * i1;
        } else {
            outb[(long)gq0 * 64 + r31]      = s00 * i0;
            outb[(long)gq0 * 64 + 32 + r31] = s01 * i0;
            outb[(long)gq1 * 64 + r31]      = s10 * i1;
            outb[(long)gq1 * 64 + 32 + r31] = s11 * i1;
        }
    }
}

// ---------------------------------------------------------------- transpose (B,R,C) -> (B,C,R)
__global__ void k_transp(const float* __restrict__ src, float* __restrict__ dst, int R, int C) {
    __shared__ float t[32][33];
    int b = blockIdx.z;
    int c0 = blockIdx.x * 32, r0 = blockIdx.y * 32;
    int tx = threadIdx.x, ty0 = threadIdx.y;    // (32,8)
    for (int yy = ty0; yy < 32; yy += 8) {
        int r = r0 + yy, c = c0 + tx;
        if (r < R && c < C) t[yy][tx] = src[((long)b * R + r) * C + c];
    }
    __syncthreads();
    for (int yy = ty0; yy < 32; yy += 8) {
        int c = c0 + yy, r = r0 + tx;
        if (r < R && c < C) dst[((long)b * C + c) * R + r] = t[tx][yy];
    }
}

// ---------------------------------------------------------------- FNO: truncated forward DFT (v2)
// 2 blocks per (b,ch) image (chalf = 6 of 12 freq cols each) -> 256 blocks.
// Phasor-rotation replaces per-iter trig LDS reads; mid-loop reseed bounds drift.
__global__ void __launch_bounds__(384) k_f1(const float* __restrict__ x, float* __restrict__ Xh) {
    int blk = blockIdx.x >> 1;       // b*64 + ch
    int chalf = blockIdx.x & 1;
    int tid = threadIdx.x;           // 384
    __shared__ __align__(16) float img[4096];
    __shared__ float Tre[64][6], Tim[64][6];
    __shared__ float cs[64], sn[64];
    if (tid < 64) {
        double a = (2.0 * PI_ / 64.0) * (double)tid;
        cs[tid] = (float)cos(a);
        sn[tid] = (float)sin(a);
    }
    for (int t = tid; t < 1024; t += 384)
        ((float4*)img)[t] = ((const float4*)(x + (long)blk * 4096))[t];
    __syncthreads();
    {                                 // (h 64, c 6) = 384 threads, all active
        int h = tid / 6, cl = tid - 6 * h;
        int c = chalf * 6 + cl;
        float cr = cs[c], sr = sn[c];
        float pr = 1.f, pi = 0.f;     // (cos, sin)(2pi c w / 64)
        float re = 0.f, im = 0.f;
#pragma unroll 16
        for (int w = 0; w < 64; w++) {
            if (w == 32) {            // reseed: kill accumulated rotation drift
                int k = (c * 32) & 63;
                pr = cs[k]; pi = sn[k];
            }
            float v = img[h * 64 + w];
            re = fmaf(v, pr, re);
            im = fmaf(-v, pi, im);
            float nr = pr * cr - pi * sr;
            pi = fmaf(pr, sr, pi * cr);
            pr = nr;
        }
        Tre[h][cl] = re; Tim[h][cl] = im;
    }
    __syncthreads();
    if (tid < 144) {                  // (x 24, c 6)
        int xx = tid / 6, cl = tid - 6 * xx;
        int r = (xx < 12) ? xx : (xx + 40);
        float cr = cs[r], sr = sn[r];
        float pr = 1.f, pi = 0.f;     // (cos, sin)(2pi r h / 64)
        float re = 0.f, im = 0.f;
#pragma unroll 16
        for (int h = 0; h < 64; h++) {
            if (h == 32) {
                int k = (r * 32) & 63;
                pr = cs[k]; pi = sn[k];
            }
            float a = Tre[h][cl], bb = Tim[h][cl];
            re += a * pr + bb * pi;
            im += bb * pr - a * pi;
            float nr = pr * cr - pi * sr;
            pi = fmaf(pr, sr, pi * cr);
            pr = nr;
        }
        int m = xx * 12 + chalf * 6 + cl;
        Xh[((long)blk * 288 + m) * 2] = re;
        Xh[((long)blk * 288 + m) * 2 + 1] = im;
    }
}

// ---------------------------------------------------------------- mode-mix (v2, coalesced)
// Yhat[b,o,m] = sum_i Wc[i,o,m] * Xhat[b,i,m].  Block = (b,o); lane = m.
// W offsets xw*24+y*2 are CONTIGUOUS over m -> fully coalesced float2 loads.
__global__ void __launch_bounds__(320) k_f2(const float* __restrict__ Xh, const float* __restrict__ s1,
                                            const float* __restrict__ s2, float* __restrict__ Yh) {
    int bo = blockIdx.x;             // b*64 + o
    int b = bo >> 6, o = bo & 63;
    int m = threadIdx.x;
    if (m >= 288) return;
    int xx = m / 12, y = m - 12 * xx;
    const float* W; int xw;
    if (xx < 12) { W = s1; xw = xx; } else { W = s2; xw = xx - 12; }
    long wbase = (long)o * 288 + xw * 24 + y * 2;
    const float* Xb = Xh + ((long)b * 64) * 576;      // 288 cplx = 576 floats per (b,i)
    float re = 0.f, im = 0.f;
    for (int i = 0; i < 64; i++) {
        float2 wv = *(const float2*)&W[(long)i * 18432 + wbase];
        float2 xv = *(const float2*)&Xb[(long)i * 576 + m * 2];
        re += xv.x * wv.x - xv.y * wv.y;
        im += xv.x * wv.y + xv.y * wv.x;
    }
    float* Yb = Yh + (((long)b * 64 + o) * 288 + m) * 2;
    Yb[0] = re; Yb[1] = im;
}

// inverse DFT + pointwise conv + bias + InstanceNorm + GELU, fused per (b, out-channel)
__global__ void __launch_bounds__(1024) k_f3(const float* __restrict__ Yh, const float* __restrict__ x,
                                             const float* __restrict__ pwW, const float* __restrict__ pwb,
                                             float* __restrict__ xo) {
    int blk = blockIdx.x;
    int b = blk >> 6, o = blk & 63;
    int tid = threadIdx.x;   // 1024; each thread owns 4 consecutive pixels
    __shared__ float yre[288], yim[288];
    __shared__ float Qre[64][12], Qim[64][12];
    __shared__ float cs[64], sn[64];
    __shared__ float red[16];
    if (tid < 64) {
        double a = (2.0 * PI_ / 64.0) * (double)tid;
        cs[tid] = (float)cos(a);
        sn[tid] = (float)sin(a);
    }
    if (tid < 288) {
        yre[tid] = Yh[((long)blk * 288 + tid) * 2];
        yim[tid] = Yh[((long)blk * 288 + tid) * 2 + 1];
    }
    __syncthreads();
    if (tid < 768) {    // (h, c): complex ifft along rows (1/64 scale)
        int h = tid / 12, c = tid - 12 * h;
        float re = 0.f, im = 0.f;
#pragma unroll
        for (int xx = 0; xx < 24; xx++) {
            int r = (xx < 12) ? xx : (xx + 40);
            int k = (r * h) & 63;
            float wr = cs[k], wi = sn[k];
            float a = yre[xx * 12 + c], bb = yim[xx * 12 + c];
            re += a * wr - bb * wi;
            im += a * wi + bb * wr;
        }
        Qre[h][c] = re * (1.0f / 64.0f);
        Qim[h][c] = im * (1.0f / 64.0f);
    }
    __syncthreads();
    float bias = pwb[o];
    int h = tid >> 4;
    int w0 = (tid & 15) * 4;
    float sp0, sp1, sp2, sp3;
    {
        float base = Qre[h][0];
        sp0 = sp1 = sp2 = sp3 = base;
#pragma unroll
        for (int c = 1; c < 12; c++) {
            float qr = Qre[h][c], qi = Qim[h][c];
            int k0 = (c * w0) & 63, k1 = (c * (w0 + 1)) & 63;
            int k2 = (c * (w0 + 2)) & 63, k3 = (c * (w0 + 3)) & 63;
            sp0 += 2.0f * (qr * cs[k0] - qi * sn[k0]);
            sp1 += 2.0f * (qr * cs[k1] - qi * sn[k1]);
            sp2 += 2.0f * (qr * cs[k2] - qi * sn[k2]);
            sp3 += 2.0f * (qr * cs[k3] - qi * sn[k3]);
        }
    }
    float a0 = sp0 * (1.0f / 64.0f) + bias;
    float a1 = sp1 * (1.0f / 64.0f) + bias;
    float a2 = sp2 * (1.0f / 64.0f) + bias;
    float a3 = sp3 * (1.0f / 64.0f) + bias;
    const float* xb = x + ((long)b * 64) * 4096 + tid * 4;
    for (int i = 0; i < 64; i++) {
        float wv = pwW[o * 64 + i];
        const float4 xv = *(const float4*)(xb + (long)i * 4096);
        a0 = fmaf(xv.x, wv, a0);
        a1 = fmaf(xv.y, wv, a1);
        a2 = fmaf(xv.z, wv, a2);
        a3 = fmaf(xv.w, wv, a3);
    }
    // block reduction: wave shfl-reduce + 16-partial sum (3 barriers vs 20)
    float ssum = a0 + a1 + a2 + a3;
#pragma unroll
    for (int m = 1; m < 64; m <<= 1) ssum += __shfl_xor(ssum, m, 64);
    if ((tid & 63) == 0) red[tid >> 6] = ssum;
    __syncthreads();
    float mu = 0.f;
#pragma unroll
    for (int k = 0; k < 16; k++) mu += red[k];
    mu *= (1.0f / 4096.0f);
    __syncthreads();
    float d0 = a0 - mu, d1 = a1 - mu, d2 = a2 - mu, d3 = a3 - mu;
    float sq = d0 * d0 + d1 * d1 + d2 * d2 + d3 * d3;
#pragma unroll
    for (int m = 1; m < 64; m <<= 1) sq += __shfl_xor(sq, m, 64);
    if ((tid & 63) == 0) red[tid >> 6] = sq;
    __syncthreads();
    float var = 0.f;
#pragma unroll
    for (int k = 0; k < 16; k++) var += red[k];
    var *= (1.0f / 4096.0f);
    float inv = 1.0f / sqrtf(var + 1e-5f);
    float4 ov = make_float4(gelu_f(d0 * inv), gelu_f(d1 * inv), gelu_f(d2 * inv), gelu_f(d3 * inv));
    *(float4*)&xo[(long)blk * 4096 + tid * 4] = ov;
}

// ---------------------------------------------------------------- projection MLP (64 -> 64 -> 3)
__global__ void __launch_bounds__(256) k_proj(
    const float* __restrict__ y, const float* __restrict__ W1, const float* __restrict__ b1,
    const float* __restrict__ W2, const float* __restrict__ b2, float* __restrict__ out) {
    __shared__ __align__(16) float yr[4][64];
    __shared__ float h[4][64];
    int ql = threadIdx.x >> 6, j = threadIdx.x & 63;
    long node = (long)blockIdx.x * 4 + ql;
    yr[ql][j] = y[node * 64 + j];
    __syncthreads();
    float a = b1[j];
    for (int k = 0; k < 64; k += 4) {
        float w0 = W1[(k + 0) * 64 + j], w1 = W1[(k + 1) * 64 + j];
        float w2 = W1[(k + 2) * 64 + j], w3 = W1[(k + 3) * 64 + j];
        const float4 hv = *(const float4*)&yr[ql][k];
        a = fmaf(hv.x, w0, fmaf(hv.y, w1, fmaf(hv.z, w2, fmaf(hv.w, w3, a))));
    }
    h[ql][j] = gelu_f(a);
    __syncthreads();
    if (j < 3) {
        float a2 = b2[j];
        for (int k = 0; k < 64; k++) a2 = fmaf(h[ql][k], W2[k * 3 + j], a2);
        out[node * 3 + j] = a2;
    }
}

// ---------------------------------------------------------------- launch
extern "C" void kernel_launch(void* const* d_in, const int* in_sizes, int n_in,
                              void* d_out, int out_size, void* d_ws, size_t ws_size,
                              hipStream_t stream) {
    (void)in_sizes; (void)n_in; (void)out_size; (void)ws_size;
    const float* coords   = (const float*)d_in[0];
    const float* features = (const float*)d_in[1];
    const float* lift_W1 = (const float*)d_in[2];
    const float* lift_b1 = (const float*)d_in[3];
    const float* lift_W2 = (const float*)d_in[4];
    const float* lift_b2 = (const float*)d_in[5];
    const float* gin_W1 = (const float*)d_in[6];
    const float* gin_b1 = (const float*)d_in[7];
    const float* gin_W2 = (const float*)d_in[8];
    const float* gin_b2 = (const float*)d_in[9];
    const float* gin_W3 = (const float*)d_in[10];
    const float* gin_b3 = (const float*)d_in[11];
    const float* spec1 = (const float*)d_in[12];
    const float* spec2 = (const float*)d_in[13];
    const float* pw_W  = (const float*)d_in[14];
    const float* pw_b  = (const float*)d_in[15];
    const float* gout_W1 = (const float*)d_in[16];
    const float* gout_b1 = (const float*)d_in[17];
    const float* gout_W2 = (const float*)d_in[18];
    const float* gout_b2 = (const float*)d_in[19];
    const float* gout_W3 = (const float*)d_in[20];
    const float* gout_b3 = (const float*)d_in[21];
    const float* proj_W1 = (const float*)d_in[22];
    const float* proj_b1 = (const float*)d_in[23];
    const float* proj_W2 = (const float*)d_in[24];
    const float* proj_b2 = (const float*)d_in[25];

    char* ws = (char*)d_ws;
    size_t off = 0;
    auto alloc = [&](size_t bytes) -> char* {
        char* p = ws + off;
        off = (off + bytes + 255) & ~(size_t)255;
        return p;
    };
    float4* grid_pack = (float4*)alloc((size_t)NG * 16);
    float*  feat      = (float*)alloc((size_t)B_ * N_ * 64 * 4);
    int*    bin_cnt   = (int*)alloc((size_t)B_ * 4096 * 4);
    int*    bin_fill  = (int*)alloc((size_t)B_ * 4096 * 4);   // contiguous after bin_cnt
    int*    bin_off   = (int*)alloc((size_t)B_ * 4097 * 4);
    float4* srt       = (float4*)alloc((size_t)B_ * N_ * 16);
    int*    idx_in    = (int*)alloc((size_t)B_ * NG * 16 * 4);
    float*  dist_in   = (float*)alloc((size_t)B_ * NG * 16 * 4);
    float*  lastd_in  = (float*)alloc((size_t)B_ * NG * 4);
    float*  sig_in    = (float*)alloc(256);
    float*  xb0       = (float*)alloc((size_t)B_ * 64 * NG * 4);
    float*  xb1       = (float*)alloc((size_t)B_ * 64 * NG * 4);
    float*  Xh        = (float*)alloc((size_t)B_ * 64 * 288 * 2 * 4);
    float*  Yh        = (float*)alloc((size_t)B_ * 64 * 288 * 2 * 4);
    float*  g2        = (float*)alloc((size_t)B_ * NG * 64 * 4);
    int*    idx_out   = (int*)alloc((size_t)B_ * N_ * 16 * 4);
    float*  dist_out  = (float*)alloc((size_t)B_ * N_ * 16 * 4);
    float*  lastd_out = (float*)alloc((size_t)B_ * N_ * 4);
    float*  sig_out   = (float*)alloc(256);
    float*  ybuf      = (float*)alloc((size_t)B_ * N_ * 64 * 4);
    short*  wb_in     = (short*)alloc((size_t)52 * 1024);   // 52 x 1KB bf16 hi/lo fragments
    short*  wb_out    = (short*)alloc((size_t)52 * 1024);

    // 1: prep (lift + wcvt + grid gen + bin zeroing, fused; no memset dispatch)
    k_prep<<<4202, 256, 0, stream>>>(features, lift_W1, lift_b1, lift_W2, lift_b2, feat,
                                     gin_W1, gin_W2, gin_W3, wb_in,
                                     gout_W1, gout_W2, gout_W3, wb_out,
                                     grid_pack, bin_cnt);
    // 2-4: binning pipeline (serial deps)
    k_bincount<<<(B_ * N_) / 256, 256, 0, stream>>>((const float2*)coords, bin_cnt);
    k_binscan<<<B_, 1024, 0, stream>>>(bin_cnt, bin_off);
    k_binscatter<<<(B_ * N_) / 256, 256, 0, stream>>>((const float2*)coords, bin_off, bin_fill, srt);
    // 5: both kNN directions in one launch
    k_knn<<<2048 + 4096, 256, 0, stream>>>(grid_pack, srt, bin_off, (const float2*)coords,
                                           idx_in, dist_in, lastd_in,
                                           idx_out, dist_out, lastd_out);
    // 6: both medians concurrently (wall = max, not sum)
    k_median2<<<2, 1024, 0, stream>>>(lastd_in, lastd_out, sig_in, sig_out);
    // 7: GNO points -> grid
    k_edge_mfma<0><<<(B_ * NG) / 4, 128, 0, stream>>>(idx_in, dist_in, sig_in,
        (const float2*)coords, grid_pack, feat, wb_in,
        gin_b1, gin_b2, gin_b3, xb0);
    // 8-16: FNO chain
    float* xc = xb0; float* xn = xb1;
    for (int d = 0; d < 3; d++) {
        k_f1<<<B_ * 64 * 2, 384, 0, stream>>>(xc, Xh);
        k_f2<<<B_ * 64, 320, 0, stream>>>(Xh, spec1 + (size_t)d * 1179648, spec2 + (size_t)d * 1179648, Yh);
        k_f3<<<B_ * 64, 1024, 0, stream>>>(Yh, xc, pw_W + (size_t)d * 4096, pw_b + (size_t)d * 64, xn);
        float* tmp = xc; xc = xn; xn = tmp;
    }
    // 17: layout for gather (b,64,NG) -> (b,NG,64)
    {
        dim3 g(NG / 32, 64 / 32, B_); dim3 t(32, 8);
        k_transp<<<g, t, 0, stream>>>(xc, g2, 64, NG);
    }
    // 18: GNO grid -> points (sig/idx/dist computed back at step 5/6)
    k_edge_mfma<1><<<(B_ * N_) / 4, 128, 0, stream>>>(idx_out, dist_out, sig_out,
        (const float2*)coords, grid_pack, g2, wb_out,
        gout_b1, gout_b2, gout_b3, ybuf);
    // 19: projection
    k_proj<<<(B_ * N_) / 4, 256, 0, stream>>>(ybuf, proj_W1, proj_b1, proj_W2, proj_b2, (float*)d_out);
}

// Round 8
// 334.174 us; speedup vs baseline: 1.6500x; 1.0862x over previous
//
#include <hip/hip_runtime.h>
#include <math.h>

#define B_ 2
#define N_ 8192          // points per batch
#define G_ 64
#define NG 4096          // G*G latent grid points
#define WID_ 64
#define K_ 16
#define CIN_ 6
#define COUT_ 3
#define PI_ 3.14159265358979323846

typedef unsigned long long u64k;
typedef __attribute__((ext_vector_type(8))) short bf16x8;   // 8 bf16 bit-patterns (4 VGPR)
typedef __attribute__((ext_vector_type(16))) float f32x16;  // 32x32 MFMA acc

// ---------------------------------------------------------------- helpers
// exact-erf GELU via Abramowitz-Stegun 7.1.26 (|eps_erf| <= 1.5e-7), branchless.
__device__ __forceinline__ float gelu_f(float x) {
    float u = fabsf(x) * 0.70710678118654752440f;
    float t = __builtin_amdgcn_rcpf(fmaf(0.3275911f, u, 1.0f));
    float p = fmaf(fmaf(fmaf(fmaf(1.061405429f, t, -1.453152027f), t, 1.421413741f),
                        t, -0.284496736f), t, 0.254829592f) * t;
    float e = __expf(-u * u);
    float erfc_u = p * e;                               // erfc(u), u >= 0
    float phi = (x >= 0.f) ? fmaf(-0.5f, erfc_u, 1.0f) : (0.5f * erfc_u);
    return x * phi;
}
__device__ __forceinline__ int cellof(float v) {
    int c = (int)floorf((v + 1.0f) * 32.0f);
    return min(63, max(0, c));
}
__device__ __forceinline__ u64k umin64(u64k a, u64k b) { return a < b ? a : b; }
__device__ __forceinline__ u64k umax64(u64k a, u64k b) { return a < b ? b : a; }
__device__ __forceinline__ u64k shflxor64(u64k v, int m) {
    return (u64k)__shfl_xor((long long)v, m, 64);
}
__device__ __forceinline__ void bsort64(u64k& key, int lane) {
#pragma unroll
    for (int sz = 2; sz <= 64; sz <<= 1) {
#pragma unroll
        for (int j = sz >> 1; j >= 1; j >>= 1) {
            u64k o = shflxor64(key, j);
            bool keep_min = ((lane & j) == 0) == ((lane & sz) == 0);
            key = keep_min ? umin64(key, o) : umax64(key, o);
        }
    }
}
__device__ __forceinline__ void bmerge_into(u64k& R, u64k key, int lane) {
    u64k o = shflxor64(key, 63);
    u64k L = umin64(R, o);
#pragma unroll
    for (int j = 32; j >= 1; j >>= 1) {
        u64k t = shflxor64(L, j);
        L = ((lane & j) == 0) ? umin64(L, t) : umax64(L, t);
    }
    R = L;
}
// split fp32 -> bf16 hi (round-half-up, 0.5-ulp) + bf16 lo (truncated residual)
__device__ __forceinline__ void cvt8v(float4 a, float4 b, bf16x8& hv, bf16x8& lv) {
    float v[8] = {a.x, a.y, a.z, a.w, b.x, b.y, b.z, b.w};
#pragma unroll
    for (int i = 0; i < 8; i++) {
        unsigned u = __float_as_uint(v[i]);
        unsigned r = (u + 0x8000u) & 0xffff0000u;
        hv[i] = (short)(r >> 16);
        float lo = v[i] - __uint_as_float(r);
        lv[i] = (short)(__float_as_uint(lo) >> 16);
    }
}
__device__ __forceinline__ bf16x8 ldfrag(const short* __restrict__ WB, int f, int lane) {
    return *(const bf16x8*)(WB + ((long)f * 64 + lane) * 8);
}
struct Frag4 { bf16x8 h0, l0, h1, l1; };
// base/nk select layer: L1 base=0 nk=5, L2 base=20 nk=4, L3 base=36 nk=4
__device__ __forceinline__ Frag4 ldfrag4(const short* __restrict__ WB, int base, int nk,
                                         int kc, int lane) {
    Frag4 f;
    f.h0 = ldfrag(WB, base + (0 * nk + kc) * 2 + 0, lane);
    f.l0 = ldfrag(WB, base + (0 * nk + kc) * 2 + 1, lane);
    f.h1 = ldfrag(WB, base + (1 * nk + kc) * 2 + 0, lane);
    f.l1 = ldfrag(WB, base + (1 * nk + kc) * 2 + 1, lane);
    return f;
}

// ---------------------------------------------------------------- prep mega-kernel
// Fuses 4 independent preprocessing stages by block section:
//   blocks [0,4096)      : lift MLP (features -> feat), 4 nodes/block
//   blocks [4096,4122)   : weight split/pack (both gin & gout sets)
//   blocks [4122,4138)   : latent grid gen (numpy linspace semantics)
//   blocks [4138,4202)   : zero bin_cnt + bin_fill (16384 ints contiguous)
__global__ void __launch_bounds__(256) k_prep(
    const float* __restrict__ fin, const float* __restrict__ lW1,
    const float* __restrict__ lb1, const float* __restrict__ lW2,
    const float* __restrict__ lb2, float* __restrict__ fout,
    const float* __restrict__ W1a, const float* __restrict__ W2a,
    const float* __restrict__ W3a, short* __restrict__ WBa,
    const float* __restrict__ W1b, const float* __restrict__ W2b,
    const float* __restrict__ W3b, short* __restrict__ WBb,
    float4* __restrict__ gp, int* __restrict__ bins) {
    __shared__ float xr[4][8];
    __shared__ __align__(16) float h[4][64];
    int blk = blockIdx.x;
    if (blk < 4096) {                       // ---- lift
        int ql = threadIdx.x >> 6, j = threadIdx.x & 63;
        int node = blk * 4 + ql;
        if (j < CIN_) xr[ql][j] = fin[node * CIN_ + j];
        __syncthreads();
        float a = lb1[j];
#pragma unroll
        for (int i = 0; i < CIN_; i++) a = fmaf(xr[ql][i], lW1[i * 64 + j], a);
        h[ql][j] = gelu_f(a);
        __syncthreads();
        float a2 = lb2[j];
        for (int k = 0; k < 64; k += 4) {
            float w0 = lW2[(k + 0) * 64 + j], w1 = lW2[(k + 1) * 64 + j];
            float w2 = lW2[(k + 2) * 64 + j], w3 = lW2[(k + 3) * 64 + j];
            const float4 hv = *(const float4*)&h[ql][k];
            a2 = fmaf(hv.x, w0, fmaf(hv.y, w1, fmaf(hv.z, w2, fmaf(hv.w, w3, a2))));
        }
        fout[node * 64 + j] = a2;
    } else if (blk < 4122) {                // ---- wcvt (both sets)
        int t = (blk - 4096) * 256 + threadIdx.x;
        if (t >= 6656) return;
        int setb = (t >= 3328);
        int tt = t - (setb ? 3328 : 0);
        const float* W1s = setb ? W1b : W1a;
        const float* W2s = setb ? W2b : W2a;
        const float* W3s = setb ? W3b : W3a;
        short* WB = setb ? WBb : WBa;
        int f = tt >> 6, lane = tt & 63;
        const float* W; int hh, nt, kc, l1 = 0;
        if (f < 20)      { W = W1s; int r = f;      hh = r & 1; r >>= 1; nt = r / 5; kc = r % 5; l1 = 1; }
        else if (f < 36) { W = W2s; int r = f - 20; hh = r & 1; r >>= 1; nt = r / 4; kc = r % 4; }
        else             { W = W3s; int r = f - 36; hh = r & 1; r >>= 1; nt = r / 4; kc = r % 4; }
        int col = nt * 32 + (lane & 31);
        bf16x8 out;
#pragma unroll
        for (int i = 0; i < 8; i++) {
            int k = kc * 16 + (lane >> 5) * 8 + i;
            float w = 0.f;
            if (l1) {
                if (k < 7) w = W[k * 64 + col];
                else if (k >= 8 && k < 72) w = W[(k - 1) * 64 + col];
            } else {
                w = W[k * 64 + col];
            }
            unsigned u = __float_as_uint(w);
            unsigned hi = (u + 0x7fffu + ((u >> 16) & 1u)) & 0xffff0000u;
            float lo = w - __uint_as_float(hi);
            unsigned ul = __float_as_uint(lo);
            unsigned lr = ul + 0x7fffu + ((ul >> 16) & 1u);
            out[i] = hh ? (short)(lr >> 16) : (short)(hi >> 16);
        }
        *(bf16x8*)(WB + ((long)f * 64 + lane) * 8) = out;
    } else if (blk < 4138) {                // ---- grid gen
        int t = (blk - 4122) * 256 + threadIdx.x;    // 0..4095
        int i = t >> 6, j = t & 63;
        double st = 2.0 / 63.0;
        float gx = (i == 63) ? 1.0f : (float)(-1.0 + st * (double)i);
        float gy = (j == 63) ? 1.0f : (float)(-1.0 + st * (double)j);
        float s2 = __fadd_rn(__fmul_rn(gx, gx), __fmul_rn(gy, gy));
        gp[t] = make_float4(gx, gy, s2, 0.f);
    } else {                                // ---- zero bins (cnt+fill contiguous)
        int t = (blk - 4138) * 256 + threadIdx.x;    // 0..16383
        bins[t] = 0;
    }
}

// ---------------------------------------------------------------- binning
__global__ void k_bincount(const float2* __restrict__ coords, int* __restrict__ cnt) {
    int t = blockIdx.x * blockDim.x + threadIdx.x;
    if (t >= B_ * N_) return;
    float2 c = coords[t];
    int b = t >> 13;
    int cell = cellof(c.x) * 64 + cellof(c.y);
    atomicAdd(&cnt[b * 4096 + cell], 1);
}
// wave shfl_up scan + 16-partial combine -> 1 barrier
__global__ void k_binscan(const int* __restrict__ cnt, int* __restrict__ offs) {
    int b = blockIdx.x, t = threadIdx.x;    // 1024 threads
    __shared__ int part[16];
    int4 v = ((const int4*)(cnt + b * 4096))[t];
    int sum = v.x + v.y + v.z + v.w;
    int lane = t & 63, wv = t >> 6;
    int ws = sum;
#pragma unroll
    for (int o = 1; o < 64; o <<= 1) {
        int u = __shfl_up(ws, o, 64);
        if (lane >= o) ws += u;
    }
    if (lane == 63) part[wv] = ws;
    __syncthreads();
    int base = 0;
#pragma unroll
    for (int k = 0; k < 16; k++) base += (k < wv) ? part[k] : 0;
    int incl = base + ws, excl = incl - sum;
    int* ob = offs + b * 4097;
    ob[4 * t] = excl; ob[4 * t + 1] = excl + v.x;
    ob[4 * t + 2] = excl + v.x + v.y; ob[4 * t + 3] = excl + v.x + v.y + v.z;
    if (t == 1023) ob[4096] = incl;
}
__global__ void k_binscatter(const float2* __restrict__ coords, const int* __restrict__ offs,
                             int* __restrict__ fill, float4* __restrict__ srt) {
    int t = blockIdx.x * blockDim.x + threadIdx.x;
    if (t >= B_ * N_) return;
    float2 c = coords[t];
    int b = t >> 13, n = t & 8191;
    int cell = cellof(c.x) * 64 + cellof(c.y);
    int pos = offs[b * 4097 + cell] + atomicAdd(&fill[b * 4096 + cell], 1);
    float s2 = __fadd_rn(__fmul_rn(c.x, c.x), __fmul_rn(c.y, c.y));
    srt[b * N_ + pos] = make_float4(c.x, c.y, s2, __int_as_float(n));
}

// ---------------------------------------------------------------- fused kNN (both directions)
__global__ void __launch_bounds__(256) k_knn(
    const float4* __restrict__ gp, const float4* __restrict__ srt,
    const int* __restrict__ offs, const float2* __restrict__ coords,
    int* __restrict__ oidx_in, float* __restrict__ odist_in, float* __restrict__ lastd_in,
    int* __restrict__ oidx_out, float* __restrict__ odist_out, float* __restrict__ lastd_out) {
    int lane = threadIdx.x & 63;
    if (blockIdx.x < 2048) {
        int w = (blockIdx.x * blockDim.x + threadIdx.x) >> 6;
        int b = w >> 12, p = w & 4095;
        float4 q = gp[p];
        float qx = q.x, qy = q.y, q2 = q.z;
        int cqx = cellof(qx), cqy = cellof(qy);
        const float4* S = srt + b * N_;
        const int* OF = offs + b * 4097;

        u64k R = ~0ull;
        u64k pend = ~0ull;
        int fill = 0;

        auto flush = [&]() {
            bsort64(pend, lane);
            bmerge_into(R, pend, lane);
            pend = ~0ull;
            fill = 0;
        };
        auto feed = [&](int s0, int s1) {
            int cnt = s1 - s0;
            while (cnt > 0) {
                int take = min(cnt, 64 - fill);
                int t = lane - fill;
                if (t >= 0 && t < take) {
                    float4 sp = S[s0 + t];
                    float dot = __fadd_rn(__fmul_rn(qx, sp.x), __fmul_rn(qy, sp.y));
                    float d2 = __fsub_rn(__fadd_rn(q2, sp.z), 2.0f * dot);
                    d2 = fmaxf(d2, 0.0f);
                    pend = ((u64k)__float_as_uint(d2) << 32) | (unsigned)__float_as_int(sp.w);
                }
                fill += take; s0 += take; cnt -= take;
                if (fill == 64) flush();
            }
        };

        {
            int xa = max(cqx - 2, 0), xb = min(cqx + 2, 63);
            int ya = max(cqy - 2, 0), yb = min(cqy + 2, 63);
            for (int cx = xa; cx <= xb; cx++) feed(OF[cx * 64 + ya], OF[cx * 64 + yb + 1]);
        }
        int r = 2;
        while (true) {
            if (fill) flush();
            u64k T = (u64k)__shfl((long long)R, 15, 64);
            float d16 = __uint_as_float((unsigned)(T >> 32));
            float bm = (float)r * 0.03125f;
            if (d16 < bm * bm - 1e-5f) break;
            if (cqx - r <= 0 && cqx + r >= 63 && cqy - r <= 0 && cqy + r >= 63) break;
            r++;
            int ya = max(cqy - r, 0), yb = min(cqy + r, 63);
            if (cqx - r >= 0)  { int c0 = (cqx - r) * 64; feed(OF[c0 + ya], OF[c0 + yb + 1]); }
            if (cqx + r <= 63) { int c0 = (cqx + r) * 64; feed(OF[c0 + ya], OF[c0 + yb + 1]); }
            int xa2 = max(cqx - r + 1, 0), xb2 = min(cqx + r - 1, 63);
            for (int cx = xa2; cx <= xb2; cx++) {
                if (cqy - r >= 0)  { int cc = cx * 64 + cqy - r; feed(OF[cc], OF[cc + 1]); }
                if (cqy + r <= 63) { int cc = cx * 64 + cqy + r; feed(OF[cc], OF[cc + 1]); }
            }
        }
        if (lane < 16) {
            float d2 = __uint_as_float((unsigned)(R >> 32));
            float d = sqrtf(d2);
            oidx_in[w * 16 + lane] = (int)(unsigned)(R & 0xffffffffu);
            odist_in[w * 16 + lane] = d;
            if (lane == 15) lastd_in[w] = d;
        }
    } else {
        int w = ((blockIdx.x - 2048) * blockDim.x + threadIdx.x) >> 6;
        float2 c = coords[w];
        float qx = c.x, qy = c.y;
        float q2 = __fadd_rn(__fmul_rn(qx, qx), __fmul_rn(qy, qy));
        int i0 = (int)floorf((qx + 1.0f) * 31.5f);
        int j0 = (int)floorf((qy + 1.0f) * 31.5f);
        int li = min(max(i0 - 3, 0), 56);
        int lj = min(max(j0 - 3, 0), 56);
        int p = (li + (lane >> 3)) * 64 + (lj + (lane & 7));
        float4 sp = gp[p];
        float dot = __fadd_rn(__fmul_rn(qx, sp.x), __fmul_rn(qy, sp.y));
        float d2 = fmaxf(__fsub_rn(__fadd_rn(q2, sp.z), 2.0f * dot), 0.0f);
        u64k key = ((u64k)__float_as_uint(d2) << 32) | (unsigned)p;
        bsort64(key, lane);
        if (lane < 16) {
            float dd = sqrtf(__uint_as_float((unsigned)(key >> 32)));
            oidx_out[w * 16 + lane] = (int)(unsigned)(key & 0xffffffffu);
            odist_out[w * 16 + lane] = dd;
            if (lane == 15) lastd_out[w] = dd;
        }
    }
}

// ---------------------------------------------------------------- both medians, one launch
__global__ void __launch_bounds__(1024) k_median2(
    const float* __restrict__ vin, const float* __restrict__ vout,
    float* __restrict__ sig_in, float* __restrict__ sig_out) {
    const float* vals = blockIdx.x ? vout : vin;
    int n = blockIdx.x ? (B_ * N_) : (B_ * NG);
    float* sig = blockIdx.x ? sig_out : sig_in;
    __shared__ int wred[2][16];
    int tid = threadIdx.x;
    int lane = tid & 63, wv = tid >> 6;
    int cnt_per = n >> 10;           // 8 or 16
    unsigned v[16];
    for (int i = 0; i < cnt_per; i++) v[i] = __float_as_uint(vals[tid + (i << 10)]);
    int r = (n - 1) >> 1;
    unsigned prefix = 0;
    for (int bit = 31; bit >= 0; bit--) {
        unsigned cand = prefix | (1u << bit);
        int c = 0;
        for (int i = 0; i < cnt_per; i++) c += (v[i] < cand) ? 1 : 0;
        for (int o = 32; o >= 1; o >>= 1) c += __shfl_down(c, o, 64);
        int buf = bit & 1;
        if (lane == 0) wred[buf][wv] = c;
        __syncthreads();
        int tot = 0;
#pragma unroll
        for (int k = 0; k < 16; k++) tot += wred[buf][k];
        prefix = (tot <= r) ? cand : prefix;
    }
    if (tid == 0) *sig = fmaxf(__uint_as_float(prefix), 1e-6f);
}

// ---------------------------------------------------------------- edge MLP via split-bf16 MFMA (v6)
// v6: MODE==1 fuses the projection MLP (64->gelu->64 ->3) into the epilogue:
// after the shfl_xor(.,32) combine ALL lanes hold the y sums; stage y in the
// now-free X_ LDS, lane j computes hidden unit j for both queries (128 fma),
// butterfly-reduce the 3 outputs. Removes k_proj launch + 8MB ybuf round trip.
// C/D layout (HW-verified): col = lane&31, row = (reg&3) + 8*(reg>>2) + 4*(lane>>5).
template <int MODE>
__global__ void __launch_bounds__(128, 4) k_edge_mfma(
    const int* __restrict__ idxb, const float* __restrict__ distb,
    const float* __restrict__ sigp,
    const float2* __restrict__ coords, const float4* __restrict__ gp,
    const float* __restrict__ feats, const short* __restrict__ WB,
    const float* __restrict__ b1, const float* __restrict__ b2,
    const float* __restrict__ b3,
    const float* __restrict__ pW1, const float* __restrict__ pb1,
    const float* __restrict__ pW2, const float* __restrict__ pb2,
    float* __restrict__ outb) {
    constexpr int QSH  = (MODE == 0) ? 12 : 13;     // log2(Nq)
    constexpr int QMSK = (MODE == 0) ? 4095 : 8191;
    constexpr long SR  = (MODE == 0) ? 8192 : 4096; // srcRows
    __shared__ float X[2][2432];           // per wave: 32 rows x 76 floats
    const int tid = threadIdx.x, wv = tid >> 6, lane = tid & 63;
    const int r31 = lane & 31, g = lane >> 5;
    const int qbase = (blockIdx.x * 2 + wv) * 2;
    const float sig = *sigp;
    float* X_ = X[wv];

    // issue first B-fragment load immediately: in flight during staging
    Frag4 cur = ldfrag4(WB, 0, 5, 0, lane);

    // ---- staging: 32 (query,edge) rows by lanes 0..31
    int si = 0; float wt = 0.f;
    if (lane < 32) {
        int q = lane >> 4, e = lane & 15;
        int gq = qbase + q;
        int b = gq >> QSH, p = gq & QMSK;
        si = idxb[gq * 16 + e];
        float d = distb[gq * 16 + e];
        wt = __expf(-d / sig);
        float qx, qy, sx, sy;
        if (MODE == 0) {
            float4 gv = gp[p]; qx = gv.x; qy = gv.y;
            float2 cc = coords[(long)b * SR + si]; sx = cc.x; sy = cc.y;
        } else {
            float2 cc = coords[gq]; qx = cc.x; qy = cc.y;   // b*Nq + p == gq
            float4 gv = gp[si]; sx = gv.x; sy = gv.y;
        }
        float* row = X_ + lane * 76;
        *(float4*)row       = make_float4(qx, qy, sx, sy);
        *(float4*)(row + 4) = make_float4(qx - sx, qy - sy, d, 0.f);
    }
    // per-query weight sums (within each 16-lane group)
    float swt = wt;
#pragma unroll
    for (int m = 1; m < 16; m <<= 1) swt += __shfl_xor(swt, m, 64);
    // ---- feats gather: 32 rows x 16 float4; batch loads -> regs, then write
    {
        float4 fv[8];
#pragma unroll
        for (int it = 0; it < 8; it++) {
            int slot = it * 64 + lane;
            int row = slot >> 4, f4 = slot & 15;
            int gq = qbase + (row >> 4);
            int b = gq >> QSH;
            int sr = __shfl(si, row, 64);
            fv[it] = *(const float4*)&feats[((long)b * SR + sr) * 64 + f4 * 4];
        }
#pragma unroll
        for (int it = 0; it < 8; it++) {
            int slot = it * 64 + lane;
            int row = slot >> 4, f4 = slot & 15;
            *(float4*)&X_[row * 76 + 8 + f4 * 4] = fv[it];
        }
    }

    f32x16 acc0, acc1;
    float4 xa, xb;
    // ---------- layer 1: K = 71 (+pad), kc 0..4; kc=4 upper half is A=0
    {
        float bb0 = b1[r31], bb1 = b1[32 + r31];
#pragma unroll
        for (int i = 0; i < 16; i++) { acc0[i] = bb0; acc1[i] = bb1; }
        {
            const float* xp = &X_[r31 * 76 + g * 8];
            xa = *(const float4*)xp; xb = *(const float4*)(xp + 4);
        }
#pragma unroll
        for (int kc = 0; kc < 5; kc++) {
            Frag4 nxt = (kc < 4) ? ldfrag4(WB, 0, 5, kc + 1, lane)
                                 : ldfrag4(WB, 20, 4, 0, lane);   // layer-2 kc0
            bf16x8 ah, al;
            if (kc == 4 && g) {
#pragma unroll
                for (int i = 0; i < 8; i++) { ah[i] = 0; al[i] = 0; }
            } else {
                cvt8v(xa, xb, ah, al);
            }
            // prefetch next-kc A pair (skip kc=3,g=1: that is the zero pad region)
            if (kc < 4 && (kc != 3 || g == 0)) {
                const float* xp = &X_[r31 * 76 + (kc + 1) * 16 + g * 8];
                xa = *(const float4*)xp; xb = *(const float4*)(xp + 4);
            }
            __builtin_amdgcn_s_setprio(1);
            acc0 = __builtin_amdgcn_mfma_f32_32x32x16_bf16(ah, cur.h0, acc0, 0, 0, 0);
            acc1 = __builtin_amdgcn_mfma_f32_32x32x16_bf16(ah, cur.h1, acc1, 0, 0, 0);
            acc0 = __builtin_amdgcn_mfma_f32_32x32x16_bf16(al, cur.h0, acc0, 0, 0, 0);
            acc1 = __builtin_amdgcn_mfma_f32_32x32x16_bf16(al, cur.h1, acc1, 0, 0, 0);
            acc0 = __builtin_amdgcn_mfma_f32_32x32x16_bf16(ah, cur.l0, acc0, 0, 0, 0);
            acc1 = __builtin_amdgcn_mfma_f32_32x32x16_bf16(ah, cur.l1, acc1, 0, 0, 0);
            __builtin_amdgcn_s_setprio(0);
            cur = nxt;
        }
    }
    // h = gelu(acc) -> LDS (overwrites x slots 0..63; all layer-1 reads done)
#pragma unroll
    for (int reg = 0; reg < 16; reg++) {
        int row = (reg & 3) + 8 * (reg >> 2) + 4 * g;
        X_[row * 76 + r31]      = gelu_f(acc0[reg]);
        X_[row * 76 + 32 + r31] = gelu_f(acc1[reg]);
    }
    // ---------- layer 2
    {
        float bb0 = b2[r31], bb1 = b2[32 + r31];
#pragma unroll
        for (int i = 0; i < 16; i++) { acc0[i] = bb0; acc1[i] = bb1; }
        {
            const float* xp = &X_[r31 * 76 + g * 8];
            xa = *(const float4*)xp; xb = *(const float4*)(xp + 4);
        }
#pragma unroll
        for (int kc = 0; kc < 4; kc++) {
            Frag4 nxt = (kc < 3) ? ldfrag4(WB, 20, 4, kc + 1, lane)
                                 : ldfrag4(WB, 36, 4, 0, lane);   // layer-3 kc0
            bf16x8 ah, al;
            cvt8v(xa, xb, ah, al);
            if (kc < 3) {
                const float* xp = &X_[r31 * 76 + (kc + 1) * 16 + g * 8];
                xa = *(const float4*)xp; xb = *(const float4*)(xp + 4);
            }
            __builtin_amdgcn_s_setprio(1);
            acc0 = __builtin_amdgcn_mfma_f32_32x32x16_bf16(ah, cur.h0, acc0, 0, 0, 0);
            acc1 = __builtin_amdgcn_mfma_f32_32x32x16_bf16(ah, cur.h1, acc1, 0, 0, 0);
            acc0 = __builtin_amdgcn_mfma_f32_32x32x16_bf16(al, cur.h0, acc0, 0, 0, 0);
            acc1 = __builtin_amdgcn_mfma_f32_32x32x16_bf16(al, cur.h1, acc1, 0, 0, 0);
            acc0 = __builtin_amdgcn_mfma_f32_32x32x16_bf16(ah, cur.l0, acc0, 0, 0, 0);
            acc1 = __builtin_amdgcn_mfma_f32_32x32x16_bf16(ah, cur.l1, acc1, 0, 0, 0);
            __builtin_amdgcn_s_setprio(0);
            cur = nxt;
        }
    }
#pragma unroll
    for (int reg = 0; reg < 16; reg++) {
        int row = (reg & 3) + 8 * (reg >> 2) + 4 * g;
        X_[row * 76 + r31]      = gelu_f(acc0[reg]);
        X_[row * 76 + 32 + r31] = gelu_f(acc1[reg]);
    }
    // ---------- layer 3 (no activation)
    {
        float bb0 = b3[r31], bb1 = b3[32 + r31];
#pragma unroll
        for (int i = 0; i < 16; i++) { acc0[i] = bb0; acc1[i] = bb1; }
        {
            const float* xp = &X_[r31 * 76 + g * 8];
            xa = *(const float4*)xp; xb = *(const float4*)(xp + 4);
        }
#pragma unroll
        for (int kc = 0; kc < 4; kc++) {
            Frag4 nxt = cur;
            if (kc < 3) nxt = ldfrag4(WB, 36, 4, kc + 1, lane);
            bf16x8 ah, al;
            cvt8v(xa, xb, ah, al);
            if (kc < 3) {
                const float* xp = &X_[r31 * 76 + (kc + 1) * 16 + g * 8];
                xa = *(const float4*)xp; xb = *(const float4*)(xp + 4);
            }
            __builtin_amdgcn_s_setprio(1);
            acc0 = __builtin_amdgcn_mfma_f32_32x32x16_bf16(ah, cur.h0, acc0, 0, 0, 0);
            acc1 = __builtin_amdgcn_mfma_f32_32x32x16_bf16(ah, cur.h1, acc1, 0, 0, 0);
            acc0 = __builtin_amdgcn_mfma_f32_32x32x16_bf16(al, cur.h0, acc0, 0, 0, 0);
            acc1 = __builtin_amdgcn_mfma_f32_32x32x16_bf16(al, cur.h1, acc1, 0, 0, 0);
            acc0 = __builtin_amdgcn_mfma_f32_32x32x16_bf16(ah, cur.l0, acc0, 0, 0, 0);
            acc1 = __builtin_amdgcn_mfma_f32_32x32x16_bf16(ah, cur.l1, acc1, 0, 0, 0);
            __builtin_amdgcn_s_setprio(0);
            cur = nxt;
        }
    }
    // ---------- weighted aggregation over edges (rows)
    float wtv[16];
#pragma unroll
    for (int reg = 0; reg < 16; reg++)
        wtv[reg] = __shfl(wt, (reg & 3) + 8 * (reg >> 2) + 4 * g, 64);
    float s00 = 0.f, s01 = 0.f, s10 = 0.f, s11 = 0.f;   // s<query><ntile>
#pragma unroll
    for (int reg = 0; reg < 16; reg++) {
        if (reg < 8) { s00 = fmaf(wtv[reg], acc0[reg], s00); s01 = fmaf(wtv[reg], acc1[reg], s01); }
        else         { s10 = fmaf(wtv[reg], acc0[reg], s10); s11 = fmaf(wtv[reg], acc1[reg], s11); }
    }
    s00 += __shfl_xor(s00, 32, 64);     // after these, ALL lanes hold the sums
    s01 += __shfl_xor(s01, 32, 64);
    s10 += __shfl_xor(s10, 32, 64);
    s11 += __shfl_xor(s11, 32, 64);
    float sw0 = __shfl(swt, 0, 64), sw1 = __shfl(swt, 16, 64);
    float i0 = 1.0f / fmaxf(sw0, 1e-6f), i1 = 1.0f / fmaxf(sw1, 1e-6f);
    int gq0 = qbase, gq1 = qbase + 1;
    if (MODE == 0) {
        if (g == 0) {
            int b0 = gq0 >> QSH, p0 = gq0 & QMSK;
            int b1i = gq1 >> QSH, p1 = gq1 & QMSK;
            outb[((long)b0 * 64 + r31) * 4096 + p0]        = s00 * i0;   // transposed (b, col, p)
            outb[((long)b0 * 64 + 32 + r31) * 4096 + p0]   = s01 * i0;
            outb[((long)b1i * 64 + r31) * 4096 + p1]       = s10 * i1;
            outb[((long)b1i * 64 + 32 + r31) * 4096 + p1]  = s11 * i1;
        }
    } else {
        // ---------- fused projection: y(64) -> gelu(yW1+b1) -> W2+b2 -> 3
        if (g == 0) {                       // stage y rows in free X_ LDS
            X_[r31]       = s00 * i0;       // q0 cols [0,32)
            X_[32 + r31]  = s01 * i0;       // q0 cols [32,64)
            X_[64 + r31]  = s10 * i1;       // q1 cols [0,32)
            X_[96 + r31]  = s11 * i1;       // q1 cols [32,64)
        }
        // wave-private LDS write->read: compiler orders via lgkmcnt (same
        // pattern as the staging phase; no barrier needed)
        int j = lane;
        float a0 = pb1[j], a1 = a0;
        for (int k = 0; k < 64; k++) {
            float w = pW1[k * 64 + j];
            a0 = fmaf(X_[k], w, a0);
            a1 = fmaf(X_[64 + k], w, a1);
        }
        float h0 = gelu_f(a0), h1 = gelu_f(a1);
        float w20 = pW2[j * 3 + 0], w21 = pW2[j * 3 + 1], w22 = pW2[j * 3 + 2];
        float p00 = h0 * w20, p01 = h0 * w21, p02 = h0 * w22;
        float p10 = h1 * w20, p11 = h1 * w21, p12 = h1 * w22;
#pragma unroll
        for (int m = 1; m < 64; m <<= 1) {
            p00 += __shfl_xor(p00, m, 64); p01 += __shfl_xor(p01, m, 64);
            p02 += __shfl_xor(p02, m, 64);
            p10 += __shfl_xor(p10, m, 64); p11 += __shfl_xor(p11, m, 64);
            p12 += __shfl_xor(p12, m, 64);
        }
        if (lane == 0) {
            outb[(long)gq0 * 3 + 0] = p00 + pb2[0];
            outb[(long)gq0 * 3 + 1] = p01 + pb2[1];
            outb[(long)gq0 * 3 + 2] = p02 + pb2[2];
            outb[(long)gq1 * 3 + 0] = p10 + pb2[0];
            outb[(long)gq1 * 3 + 1] = p11 + pb2[1];
            outb[(long)gq1 * 3 + 2] = p12 + pb2[2];
        }
    }
}

// ---------------------------------------------------------------- transpose (B,R,C) -> (B,C,R)
__global__ void k_transp(const float* __restrict__ src, float* __restrict__ dst, int R, int C) {
    __shared__ float t[32][33];
    int b = blockIdx.z;
    int c0 = blockIdx.x * 32, r0 = blockIdx.y * 32;
    int tx = threadIdx.x, ty0 = threadIdx.y;    // (32,8)
    for (int yy = ty0; yy < 32; yy += 8) {
        int r = r0 + yy, c = c0 + tx;
        if (r < R && c < C) t[yy][tx] = src[((long)b * R + r) * C + c];
    }
    __syncthreads();
    for (int yy = ty0; yy < 32; yy += 8) {
        int c = c0 + yy, r = r0 + tx;
        if (r < R && c < C) dst[((long)b * C + c) * R + r] = t[tx][yy];
    }
}

// ---------------------------------------------------------------- FNO: truncated forward DFT (depth 0 only)
// 2 blocks per (b,ch) image; phasor rotation with mid-loop reseed.
__global__ void __launch_bounds__(384) k_f1(const float* __restrict__ x, float* __restrict__ Xh) {
    int blk = blockIdx.x >> 1;       // b*64 + ch
    int chalf = blockIdx.x & 1;
    int tid = threadIdx.x;           // 384
    __shared__ __align__(16) float img[4096];
    __shared__ float Tre[64][6], Tim[64][6];
    __shared__ float cs[64], sn[64];
    if (tid < 64) {
        double a = (2.0 * PI_ / 64.0) * (double)tid;
        cs[tid] = (float)cos(a);
        sn[tid] = (float)sin(a);
    }
    for (int t = tid; t < 1024; t += 384)
        ((float4*)img)[t] = ((const float4*)(x + (long)blk * 4096))[t];
    __syncthreads();
    {                                 // (h 64, c 6) = 384 threads, all active
        int h = tid / 6, cl = tid - 6 * h;
        int c = chalf * 6 + cl;
        float cr = cs[c], sr = sn[c];
        float pr = 1.f, pi = 0.f;
        float re = 0.f, im = 0.f;
#pragma unroll 16
        for (int w = 0; w < 64; w++) {
            if (w == 32) {            // reseed: kill accumulated rotation drift
                int k = (c * 32) & 63;
                pr = cs[k]; pi = sn[k];
            }
            float v = img[h * 64 + w];
            re = fmaf(v, pr, re);
            im = fmaf(-v, pi, im);
            float nr = pr * cr - pi * sr;
            pi = fmaf(pr, sr, pi * cr);
            pr = nr;
        }
        Tre[h][cl] = re; Tim[h][cl] = im;
    }
    __syncthreads();
    if (tid < 144) {                  // (x 24, c 6)
        int xx = tid / 6, cl = tid - 6 * xx;
        int r = (xx < 12) ? xx : (xx + 40);
        float cr = cs[r], sr = sn[r];
        float pr = 1.f, pi = 0.f;
        float re = 0.f, im = 0.f;
#pragma unroll 16
        for (int h = 0; h < 64; h++) {
            if (h == 32) {
                int k = (r * 32) & 63;
                pr = cs[k]; pi = sn[k];
            }
            float a = Tre[h][cl], bb = Tim[h][cl];
            re += a * pr + bb * pi;
            im += bb * pr - a * pi;
            float nr = pr * cr - pi * sr;
            pi = fmaf(pr, sr, pi * cr);
            pr = nr;
        }
        int m = xx * 12 + chalf * 6 + cl;
        Xh[((long)blk * 288 + m) * 2] = re;
        Xh[((long)blk * 288 + m) * 2 + 1] = im;
    }
}

// ---------------------------------------------------------------- fused FNO block
// Per (b, out-channel) block (128 blocks x 1024 thr), one launch per depth:
//   A. mode-mix (f2): Yrow(m) = sum_i W[i,o,m]*Xh[b,i,m] -> LDS (no global Yh)
//      i-loop split over 2 groups of 32 (576 threads), combined -> yre/yim
//   B. inverse DFT rows -> Q (768 thr)
//   C. pixel spectral + bias + pointwise conv (global x) + InstanceNorm + GELU
//   D. write xo; if RUN_DFT: forward DFT of the result from LDS -> XhN
// Removes per depth: k_f2 + k_f1 launches, Yh round trip, x re-read by f1.
template <int RUN_DFT>
__global__ void __launch_bounds__(1024) k_f23(
    const float* __restrict__ Xh, const float* __restrict__ s1,
    const float* __restrict__ s2, const float* __restrict__ x,
    const float* __restrict__ pwW, const float* __restrict__ pwb,
    float* __restrict__ xo, float* __restrict__ XhN) {
    int blk = blockIdx.x;
    int b = blk >> 6, o = blk & 63;
    int tid = threadIdx.x;   // 1024
    __shared__ float yre[288], yim[288];
    __shared__ float prr[576], pii[576];
    __shared__ float Qre[64][12], Qim[64][12];
    __shared__ float cs[64], sn[64];
    __shared__ float red[16];
    __shared__ __align__(16) float img[4096];
    __shared__ float Tre[64][12], Tim[64][12];
    if (tid < 64) {
        double a = (2.0 * PI_ / 64.0) * (double)tid;
        cs[tid] = (float)cos(a);
        sn[tid] = (float)sin(a);
    }
    // ---- A: mode-mix, 2 i-groups of 32
    if (tid < 576) {
        int grp = (tid >= 288) ? 1 : 0;
        int m = tid - grp * 288;
        int xx = m / 12, y = m - 12 * xx;
        const float* W; int xw;
        if (xx < 12) { W = s1; xw = xx; } else { W = s2; xw = xx - 12; }
        long wbase = (long)o * 288 + xw * 24 + y * 2;
        const float* Xb = Xh + ((long)b * 64) * 576;
        float re = 0.f, im = 0.f;
        for (int i = grp * 32; i < grp * 32 + 32; i++) {
            float2 wv = *(const float2*)&W[(long)i * 18432 + wbase];
            float2 xv = *(const float2*)&Xb[(long)i * 576 + m * 2];
            re += xv.x * wv.x - xv.y * wv.y;
            im += xv.x * wv.y + xv.y * wv.x;
        }
        prr[tid] = re; pii[tid] = im;
    }
    __syncthreads();
    if (tid < 288) {
        yre[tid] = prr[tid] + prr[tid + 288];
        yim[tid] = pii[tid] + pii[tid + 288];
    }
    __syncthreads();
    // ---- B: inverse DFT rows (1/64 scale)
    if (tid < 768) {
        int h = tid / 12, c = tid - 12 * h;
        float re = 0.f, im = 0.f;
#pragma unroll
        for (int xx = 0; xx < 24; xx++) {
            int r = (xx < 12) ? xx : (xx + 40);
            int k = (r * h) & 63;
            float wr = cs[k], wi = sn[k];
            float a = yre[xx * 12 + c], bb = yim[xx * 12 + c];
            re += a * wr - bb * wi;
            im += a * wi + bb * wr;
        }
        Qre[h][c] = re * (1.0f / 64.0f);
        Qim[h][c] = im * (1.0f / 64.0f);
    }
    __syncthreads();
    // ---- C: pixel spectral + bias + pointwise conv + InstanceNorm + GELU
    float bias = pwb[o];
    int h = tid >> 4;
    int w0 = (tid & 15) * 4;
    float sp0, sp1, sp2, sp3;
    {
        float base = Qre[h][0];
        sp0 = sp1 = sp2 = sp3 = base;
#pragma unroll
        for (int c = 1; c < 12; c++) {
            float qr = Qre[h][c], qi = Qim[h][c];
            int k0 = (c * w0) & 63, k1 = (c * (w0 + 1)) & 63;
            int k2 = (c * (w0 + 2)) & 63, k3 = (c * (w0 + 3)) & 63;
            sp0 += 2.0f * (qr * cs[k0] - qi * sn[k0]);
            sp1 += 2.0f * (qr * cs[k1] - qi * sn[k1]);
            sp2 += 2.0f * (qr * cs[k2] - qi * sn[k2]);
            sp3 += 2.0f * (qr * cs[k3] - qi * sn[k3]);
        }
    }
    float a0 = sp0 * (1.0f / 64.0f) + bias;
    float a1 = sp1 * (1.0f / 64.0f) + bias;
    float a2 = sp2 * (1.0f / 64.0f) + bias;
    float a3 = sp3 * (1.0f / 64.0f) + bias;
    const float* xb = x + ((long)b * 64) * 4096 + tid * 4;
    for (int i = 0; i < 64; i++) {
        float wv = pwW[o * 64 + i];
        const float4 xv = *(const float4*)(xb + (long)i * 4096);
        a0 = fmaf(xv.x, wv, a0);
        a1 = fmaf(xv.y, wv, a1);
        a2 = fmaf(xv.z, wv, a2);
        a3 = fmaf(xv.w, wv, a3);
    }
    float ssum = a0 + a1 + a2 + a3;
#pragma unroll
    for (int m = 1; m < 64; m <<= 1) ssum += __shfl_xor(ssum, m, 64);
    if ((tid & 63) == 0) red[tid >> 6] = ssum;
    __syncthreads();
    float mu = 0.f;
#pragma unroll
    for (int k = 0; k < 16; k++) mu += red[k];
    mu *= (1.0f / 4096.0f);
    __syncthreads();
    float d0 = a0 - mu, d1 = a1 - mu, d2 = a2 - mu, d3 = a3 - mu;
    float sq = d0 * d0 + d1 * d1 + d2 * d2 + d3 * d3;
#pragma unroll
    for (int m = 1; m < 64; m <<= 1) sq += __shfl_xor(sq, m, 64);
    if ((tid & 63) == 0) red[tid >> 6] = sq;
    __syncthreads();
    float var = 0.f;
#pragma unroll
    for (int k = 0; k < 16; k++) var += red[k];
    var *= (1.0f / 4096.0f);
    float inv = 1.0f / sqrtf(var + 1e-5f);
    float4 ov = make_float4(gelu_f(d0 * inv), gelu_f(d1 * inv), gelu_f(d2 * inv), gelu_f(d3 * inv));
    *(float4*)&xo[(long)blk * 4096 + tid * 4] = ov;
    if (RUN_DFT) {
        // ---- D: forward DFT of this block's output image (from LDS)
        *(float4*)&img[tid * 4] = ov;
        __syncthreads();
        if (tid < 768) {              // (h 64, c 12), phasor with reseed
            int hh = tid / 12, c = tid - 12 * hh;
            float cr = cs[c], sr = sn[c];
            float pr = 1.f, pi = 0.f;
            float re = 0.f, im = 0.f;
#pragma unroll 16
            for (int w = 0; w < 64; w++) {
                if (w == 32) {
                    int k = (c * 32) & 63;
                    pr = cs[k]; pi = sn[k];
                }
                float v = img[hh * 64 + w];
                re = fmaf(v, pr, re);
                im = fmaf(-v, pi, im);
                float nr = pr * cr - pi * sr;
                pi = fmaf(pr, sr, pi * cr);
                pr = nr;
            }
            Tre[hh][c] = re; Tim[hh][c] = im;
        }
        __syncthreads();
        if (tid < 288) {              // (x 24, c 12)
            int xx = tid / 12, cl = tid - 12 * xx;
            int r = (xx < 12) ? xx : (xx + 40);
            float cr = cs[r], sr = sn[r];
            float pr = 1.f, pi = 0.f;
            float re = 0.f, im = 0.f;
#pragma unroll 16
            for (int hh = 0; hh < 64; hh++) {
                if (hh == 32) {
                    int k = (r * 32) & 63;
                    pr = cs[k]; pi = sn[k];
                }
                float a = Tre[hh][cl], bb = Tim[hh][cl];
                re += a * pr + bb * pi;
                im += bb * pr - a * pi;
                float nr = pr * cr - pi * sr;
                pi = fmaf(pr, sr, pi * cr);
                pr = nr;
            }
            XhN[((long)blk * 288 + tid) * 2] = re;
            XhN[((long)blk * 288 + tid) * 2 + 1] = im;
        }
    }
}

// ---------------------------------------------------------------- launch
extern "C" void kernel_launch(void* const* d_in, const int* in_sizes, int n_in,
                              void* d_out, int out_size, void* d_ws, size_t ws_size,
                              hipStream_t stream) {
    (void)in_sizes; (void)n_in; (void)out_size; (void)ws_size;
    const float* coords   = (const float*)d_in[0];
    const float* features = (const float*)d_in[1];
    const float* lift_W1 = (const float*)d_in[2];
    const float* lift_b1 = (const float*)d_in[3];
    const float* lift_W2 = (const float*)d_in[4];
    const float* lift_b2 = (const float*)d_in[5];
    const float* gin_W1 = (const float*)d_in[6];
    const float* gin_b1 = (const float*)d_in[7];
    const float* gin_W2 = (const float*)d_in[8];
    const float* gin_b2 = (const float*)d_in[9];
    const float* gin_W3 = (const float*)d_in[10];
    const float* gin_b3 = (const float*)d_in[11];
    const float* spec1 = (const float*)d_in[12];
    const float* spec2 = (const float*)d_in[13];
    const float* pw_W  = (const float*)d_in[14];
    const float* pw_b  = (const float*)d_in[15];
    const float* gout_W1 = (const float*)d_in[16];
    const float* gout_b1 = (const float*)d_in[17];
    const float* gout_W2 = (const float*)d_in[18];
    const float* gout_b2 = (const float*)d_in[19];
    const float* gout_W3 = (const float*)d_in[20];
    const float* gout_b3 = (const float*)d_in[21];
    const float* proj_W1 = (const float*)d_in[22];
    const float* proj_b1 = (const float*)d_in[23];
    const float* proj_W2 = (const float*)d_in[24];
    const float* proj_b2 = (const float*)d_in[25];

    char* ws = (char*)d_ws;
    size_t off = 0;
    auto alloc = [&](size_t bytes) -> char* {
        char* p = ws + off;
        off = (off + bytes + 255) & ~(size_t)255;
        return p;
    };
    float4* grid_pack = (float4*)alloc((size_t)NG * 16);
    float*  feat      = (float*)alloc((size_t)B_ * N_ * 64 * 4);
    int*    bin_cnt   = (int*)alloc((size_t)B_ * 4096 * 4);
    int*    bin_fill  = (int*)alloc((size_t)B_ * 4096 * 4);   // contiguous after bin_cnt
    int*    bin_off   = (int*)alloc((size_t)B_ * 4097 * 4);
    float4* srt       = (float4*)alloc((size_t)B_ * N_ * 16);
    int*    idx_in    = (int*)alloc((size_t)B_ * NG * 16 * 4);
    float*  dist_in   = (float*)alloc((size_t)B_ * NG * 16 * 4);
    float*  lastd_in  = (float*)alloc((size_t)B_ * NG * 4);
    float*  sig_in    = (float*)alloc(256);
    float*  xb0       = (float*)alloc((size_t)B_ * 64 * NG * 4);
    float*  xb1       = (float*)alloc((size_t)B_ * 64 * NG * 4);
    float*  Xh        = (float*)alloc((size_t)B_ * 64 * 288 * 2 * 4);
    float*  Xh2       = (float*)alloc((size_t)B_ * 64 * 288 * 2 * 4);
    float*  g2        = (float*)alloc((size_t)B_ * NG * 64 * 4);
    int*    idx_out   = (int*)alloc((size_t)B_ * N_ * 16 * 4);
    float*  dist_out  = (float*)alloc((size_t)B_ * N_ * 16 * 4);
    float*  lastd_out = (float*)alloc((size_t)B_ * N_ * 4);
    float*  sig_out   = (float*)alloc(256);
    short*  wb_in     = (short*)alloc((size_t)52 * 1024);   // 52 x 1KB bf16 hi/lo fragments
    short*  wb_out    = (short*)alloc((size_t)52 * 1024);

    // 1: prep (lift + wcvt + grid gen + bin zeroing)
    k_prep<<<4202, 256, 0, stream>>>(features, lift_W1, lift_b1, lift_W2, lift_b2, feat,
                                     gin_W1, gin_W2, gin_W3, wb_in,
                                     gout_W1, gout_W2, gout_W3, wb_out,
                                     grid_pack, bin_cnt);
    // 2-4: binning pipeline (serial deps)
    k_bincount<<<(B_ * N_) / 256, 256, 0, stream>>>((const float2*)coords, bin_cnt);
    k_binscan<<<B_, 1024, 0, stream>>>(bin_cnt, bin_off);
    k_binscatter<<<(B_ * N_) / 256, 256, 0, stream>>>((const float2*)coords, bin_off, bin_fill, srt);
    // 5: both kNN directions in one launch
    k_knn<<<2048 + 4096, 256, 0, stream>>>(grid_pack, srt, bin_off, (const float2*)coords,
                                           idx_in, dist_in, lastd_in,
                                           idx_out, dist_out, lastd_out);
    // 6: both medians concurrently
    k_median2<<<2, 1024, 0, stream>>>(lastd_in, lastd_out, sig_in, sig_out);
    // 7: GNO points -> grid
    k_edge_mfma<0><<<(B_ * NG) / 4, 128, 0, stream>>>(idx_in, dist_in, sig_in,
        (const float2*)coords, grid_pack, feat, wb_in,
        gin_b1, gin_b2, gin_b3, nullptr, nullptr, nullptr, nullptr, xb0);
    // 8: forward DFT of depth-0 input
    k_f1<<<B_ * 64 * 2, 384, 0, stream>>>(xb0, Xh);
    // 9-11: fused FNO blocks (f2 + f3 + next-depth f1)
    k_f23<1><<<B_ * 64, 1024, 0, stream>>>(Xh,  spec1,           spec2,           xb0,
        pw_W,            pw_b,        xb1, Xh2);
    k_f23<1><<<B_ * 64, 1024, 0, stream>>>(Xh2, spec1 + 1179648, spec2 + 1179648, xb1,
        pw_W + 4096,     pw_b + 64,   xb0, Xh);
    k_f23<0><<<B_ * 64, 1024, 0, stream>>>(Xh,  spec1 + 2359296, spec2 + 2359296, xb0,
        pw_W + 8192,     pw_b + 128,  xb1, Xh2);
    // 12: layout for gather (b,64,NG) -> (b,NG,64)
    {
        dim3 g(NG / 32, 64 / 32, B_); dim3 t(32, 8);
        k_transp<<<g, t, 0, stream>>>(xb1, g2, 64, NG);
    }
    // 13: GNO grid -> points with fused projection MLP -> final output
    k_edge_mfma<1><<<(B_ * N_) / 4, 128, 0, stream>>>(idx_out, dist_out, sig_out,
        (const float2*)coords, grid_pack, g2, wb_out,
        gout_b1, gout_b2, gout_b3, proj_W1, proj_b1, proj_W2, proj_b2, (float*)d_out);
}